// Round 7
// baseline (1381.346 us; speedup 1.0000x reference)
//
#include <hip/hip_runtime.h>
#include <math.h>

typedef unsigned short u16;
typedef unsigned int   u32;
typedef unsigned long long u64;
typedef __attribute__((ext_vector_type(8))) short short8;   // 8 bf16 (4 VGPR)
typedef __attribute__((ext_vector_type(4))) float f32x4;    // MFMA acc

// ---------- dtype helpers ----------
__device__ __forceinline__ float b2f(u16 v) { return __uint_as_float(((u32)v) << 16); }
__device__ __forceinline__ u16 f2b(float f) {
    u32 u = __float_as_uint(f);
    u32 r = (u + 0x7FFFu + ((u >> 16) & 1u)) >> 16;   // RNE
    return (u16)r;
}
__device__ __forceinline__ float gload(const void* p, long i, int bf) {
    return bf ? b2f(((const u16*)p)[i]) : ((const float*)p)[i];
}
__device__ __forceinline__ void gstore(void* p, long i, float v, int bf) {
    if (bf) ((u16*)p)[i] = f2b(v);
    else    ((float*)p)[i] = v;
}

// top-k key: smallest key = (largest value, then smallest index)
__device__ __forceinline__ u64 packKey(float v, int idx) {
    u32 u = __float_as_uint(v);
    u32 m = (u & 0x80000000u) ? ~u : (u | 0x80000000u);   // monotone float->uint
    return ((u64)(~m) << 32) | (u32)idx;
}

// ---------- problem constants ----------
#define BATCH 8
#define CIN   64
#define FH    96
#define FW    320
#define KDET  50
#define NROI  400
#define CROI  69
#define HW    (FH*FW)
#define CHUNK 1920
#define NCHUNK 16

// ---------- workspace layout (float offsets) ----------
#define WS_HEAT 0L
#define WS_OFF2 737280L
#define WS_SIZ2 1228800L
#define WS_NH   1720320L
#define WS_S1S  2457600L
#define WS_S1I  2458800L
#define WS_CLS  2460000L
#define WS_BOX  2460400L
#define WS_ROI  2462400L
#define WS_HOUT 3814800L
#define WS_W1T  3827600L     // 147456 f32: hm conv1 [k=576][c=256] (exact strip)
#define WS_WB16 3975056L     // u16: 3 branches * [9][256][64] bf16
#define WS_W1H  4269968L     // u16: 4 heads * [9][3][256][32] bf16
#define WS_PAR  4905872L     // packed f32 params
#define WS_FLAG 4938960L     // int dtype flag

// param block sub-offsets
#define PB_CAL 0
#define PB_CRN 96
#define PB_MSZ 128
#define PB_BR0 144          // stride 1040: b1@0, w2@256 ([k][n]), b2@256+OC*256
#define PB_HD0 3264         // stride 7456

// ---------- output layout (element offsets) ----------
#define O_HEAT 0L
#define O_OFF2 737280L
#define O_SIZ2 1228800L
#define O_HEAD 1720320L
#define O_DEP  1729920L
#define O_OFF3 1730720L
#define O_S3D  1731520L
#define O_H3D  1732720L

// =====================================================================
// dtype detection
// =====================================================================
__global__ void kDetect(const void* __restrict__ feat, int* __restrict__ flag) {
    __shared__ int cnt;
    if (threadIdx.x == 0) cnt = 0;
    __syncthreads();
    u16 v = ((const u16*)feat)[threadIdx.x];     // 512 threads
    float f = b2f(v);
    u32 e = (v >> 7) & 0xFF;
    float a = fabsf(f);
    int sane = (e != 0xFF) && (f == 0.f || (a >= 1e-8f && a <= 1e4f));
    atomicAdd(&cnt, sane);
    __syncthreads();
    if (threadIdx.x == 0) *flag = (cnt >= 480) ? 1 : 0;
}

// =====================================================================
// Prep: weights
// =====================================================================
struct WPtrs { const void* bw[3]; const void* hw[4]; };

__global__ void kPrepW(WPtrs P, const int* __restrict__ flag,
                       float* __restrict__ w1t, u16* __restrict__ wb16,
                       u16* __restrict__ whb) {
    const int bf = *flag;
    int idx = blockIdx.x * 256 + threadIdx.x;
    if (idx < 147456) {
        int k = idx >> 8, c = idx & 255;
        w1t[idx] = gload(P.bw[0], (long)c * 576 + k, bf);
    } else if (idx < 589824) {
        int j = idx - 147456;
        int br = j / 147456, rem = j % 147456;
        int tap = rem / 16384, n = (rem >> 6) & 255, ci = rem & 63;
        wb16[j] = f2b(gload(P.bw[br], (long)n * 576 + ci * 9 + tap, bf));
    } else {
        int j = idx - 589824;               // < 884736
        int h = j / 221184, rem = j % 221184;
        int tap = rem / 24576, rem2 = rem % 24576;
        int cs = rem2 / 8192, rem3 = rem2 % 8192;
        int oc = rem3 >> 5, jj = rem3 & 31;
        int ci = cs * 32 + jj;
        u16 val = 0;
        if (ci < CROI) val = f2b(gload(P.hw[h], (long)oc * 621 + ci * 9 + tap, bf));
        whb[j] = val;
    }
}

// Prep: pack all small params to f32
struct Seg { const void* src; int n; int dst; };
struct Segs { Seg s[40]; };

__global__ void kPrepP(Segs S, const int* __restrict__ flag, float* __restrict__ par) {
    const int bf = *flag;
    Seg sg = S.s[blockIdx.x];
    for (int i = threadIdx.x; i < sg.n; i += 256)
        par[sg.dst + i] = gload(sg.src, i, bf);
}

// =====================================================================
// Merged MFMA branch conv: all 3 branches, 512 thr, M=128 (2 rows x 64 x)
// conv3x3(64->256) as 9 shifted GEMMs + b1 + ReLU + 1x1(->oc) + b2
// grid (5, 48, 24); z = br*8 + b. Wave owns 32 n; 8 M-tiles x 2 N-tiles.
// Weight tile for tap t+1 is prefetched into VGPRs while computing tap t.
// =====================================================================
union B3U {
    u16   a[4][68][72];       // input rows y0-1..y0+2, x0-1..x0+64, 64ci (pad 72)
    float red[8][128][3];     // 1x1 partials per wave
};

__global__ __launch_bounds__(512, 4)
void kBranch3(const void* __restrict__ feat, const int* __restrict__ flag,
              const u16* __restrict__ wbAll,   // 3 * [9][256][64] bf16
              const float* __restrict__ bpAll, // par + PB_BR0, stride 1040
              void* __restrict__ outb, float* __restrict__ wsbase) {
    __shared__ __align__(16) B3U u;
    __shared__ __align__(16) u16 w_lds[256][72];

    const long obase[3] = {O_HEAT, O_OFF2, O_SIZ2};
    const long wfs[3]   = {WS_HEAT, WS_OFF2, WS_SIZ2};

    const int bfl = *flag;
    const int tid = threadIdx.x;
    const int wave = tid >> 6, lane = tid & 63;
    const int q = lane >> 4, n15 = lane & 15;
    const int x0 = blockIdx.x * 64, y0 = blockIdx.y * 2;
    const int br = blockIdx.z >> 3, b = blockIdx.z & 7;
    const int oc = (br == 0) ? 3 : 2;
    const u16* wb = wbAll + br * 147456;
    const float* bp = bpAll + br * 1040;

    // ---- stage input tile: rows y0-1..y0+2, x0-1..x0+64, 64 ci ----
    if (tid < 256) {
        const int ci = tid & 63, rr = tid >> 6;
        const int gy = y0 - 1 + rr;
        if (gy < 0 || gy >= FH) {
            for (int xi = 0; xi < 66; ++xi) u.a[rr][xi][ci] = 0;
        } else if (bfl) {
            const u16* rp = (const u16*)feat + ((long)((b << 6) | ci) * FH + gy) * FW;
            for (int j = 0; j < 10; ++j) {
                int xs0 = x0 - 8 + j * 8;
                u16 tmp[8];
                if (xs0 >= 0 && xs0 <= FW - 8)
                    *(uint4*)tmp = *(const uint4*)(rp + xs0);
                else
                    for (int e = 0; e < 8; ++e) {
                        int gx = xs0 + e;
                        tmp[e] = (gx >= 0 && gx < FW) ? rp[gx] : (u16)0;
                    }
                for (int e = 0; e < 8; ++e) {
                    int xi = xs0 + e - x0 + 1;
                    if (xi >= 0 && xi < 66) u.a[rr][xi][ci] = tmp[e];
                }
            }
        } else {
            const float* rp = (const float*)feat + ((long)((b << 6) | ci) * FH + gy) * FW;
            for (int j = 0; j < 18; ++j) {
                int xs0 = x0 - 4 + j * 4;
                float tmp[4];
                if (xs0 >= 0 && xs0 <= FW - 4)
                    *(float4*)tmp = *(const float4*)(rp + xs0);
                else
                    for (int e = 0; e < 4; ++e) {
                        int gx = xs0 + e;
                        tmp[e] = (gx >= 0 && gx < FW) ? rp[gx] : 0.f;
                    }
                for (int e = 0; e < 4; ++e) {
                    int xi = xs0 + e - x0 + 1;
                    if (xi >= 0 && xi < 66) u.a[rr][xi][ci] = f2b(tmp[e]);
                }
            }
        }
    }

    f32x4 acc[8][2];
#pragma unroll
    for (int i = 0; i < 8; ++i)
#pragma unroll
        for (int t = 0; t < 2; ++t) acc[i][t] = (f32x4){0.f, 0.f, 0.f, 0.f};

    // ---- prologue: prefetch tap 0 weights into regs (64 B / thread) ----
    uint4 wreg[4];
#pragma unroll
    for (int j = 0; j < 4; ++j)
        wreg[j] = *(const uint4*)(wb + tid * 32 + j * 8);

    // ---- K-loop: 9 taps x 2 k-steps (32 ci each), reg-prefetch pipeline ----
    for (int tap = 0; tap < 9; ++tap) {
        __syncthreads();   // prior tap readers done (first iter: a_lds fill fence)
        // regs -> LDS (thread owns 4 consecutive 16B chunks of row tid>>1)
#pragma unroll
        for (int j = 0; j < 4; ++j) {
            int i = tid * 4 + j, n = i >> 3, c8 = i & 7;
            *(uint4*)&w_lds[n][c8 * 8] = wreg[j];
        }
        __syncthreads();
        // issue next tap's global loads; they complete during the MFMA phase
        if (tap < 8) {
            const u16* wt = wb + (tap + 1) * 16384;
#pragma unroll
            for (int j = 0; j < 4; ++j)
                wreg[j] = *(const uint4*)(wt + tid * 32 + j * 8);
        }
        const int ky = tap / 3, kx = tap % 3;
#pragma unroll
        for (int s = 0; s < 2; ++s) {
            short8 bfr[2];
#pragma unroll
            for (int t = 0; t < 2; ++t)
                bfr[t] = *(const short8*)&w_lds[wave * 32 + t * 16 + n15][s * 32 + q * 8];
#pragma unroll
            for (int ig = 0; ig < 2; ++ig) {
                short8 afr[4];
#pragma unroll
                for (int i = 0; i < 4; ++i) {
                    int it = ig * 4 + i;
                    int r = it >> 2, xb = (it & 3) * 16;
                    afr[i] = *(const short8*)&u.a[r + ky][xb + n15 + kx][s * 32 + q * 8];
                }
#pragma unroll
                for (int i = 0; i < 4; ++i)
#pragma unroll
                    for (int t = 0; t < 2; ++t)
                        acc[ig * 4 + i][t] = __builtin_amdgcn_mfma_f32_16x16x32_bf16(
                            afr[i], bfr[t], acc[ig * 4 + i][t], 0, 0, 0);
            }
        }
    }

    // ---- epilogue: b1 + relu + 1x1 partials ----
    float b1v[2], w2v[3][2];
#pragma unroll
    for (int t = 0; t < 2; ++t) {
        int n = wave * 32 + t * 16 + n15;
        b1v[t] = bp[n];
#pragma unroll
        for (int k = 0; k < 3; ++k) w2v[k][t] = bp[256 + k * 256 + n];
    }
    __syncthreads();   // done reading u.a; reuse as red
#pragma unroll
    for (int i = 0; i < 8; ++i) {
#pragma unroll
        for (int r = 0; r < 4; ++r) {
            float pk[3];
#pragma unroll
            for (int k = 0; k < 3; ++k) pk[k] = 0.f;
#pragma unroll
            for (int t = 0; t < 2; ++t) {
                float h = fmaxf(acc[i][t][r] + b1v[t], 0.f);
#pragma unroll
                for (int k = 0; k < 3; ++k) pk[k] = fmaf(h, w2v[k][t], pk[k]);
            }
#pragma unroll
            for (int k = 0; k < 3; ++k) {
                pk[k] += __shfl_xor(pk[k], 1);
                pk[k] += __shfl_xor(pk[k], 2);
                pk[k] += __shfl_xor(pk[k], 4);
                pk[k] += __shfl_xor(pk[k], 8);
            }
            if (n15 == 0) {
                int m = i * 16 + q * 4 + r;
#pragma unroll
                for (int k = 0; k < 3; ++k) u.red[wave][m][k] = pk[k];
            }
        }
    }
    __syncthreads();
    float* outf = wsbase + wfs[br];
    for (int t2 = tid; t2 < oc * 128; t2 += 512) {
        int k = t2 >> 7, m = t2 & 127;
        int row = m >> 6, x = m & 63;
        float s = bp[256 + oc * 256 + k];
#pragma unroll
        for (int w = 0; w < 8; ++w) s += u.red[w][m][k];
        long o = (((long)b * oc + k) * FH + (y0 + row)) * FW + x0 + x;
        gstore(outb, obase[br] + o, s, bfl);
        outf[o] = s;
    }
}

// =====================================================================
// Exact f32 strip (rows 0..4 of heat): NMS/topk decisions bit-match f32
// =====================================================================
union BrLds {
    float w[36 * 256];
    float part[32 * 3 * 64];
};

__global__ __launch_bounds__(256)
void kBranchX(const void* __restrict__ feat, const int* __restrict__ flag,
              const float* __restrict__ w1t, const float* __restrict__ bp,
              void* __restrict__ outb, long obase, float* __restrict__ outf) {
    __shared__ float in_lds[4][3][68];
    __shared__ BrLds u;
    const int bf = *flag;
    const int OC = 3;

    const int tid = threadIdx.x;
    const int xg = tid & 7, cg = tid >> 3;
    const int x0 = blockIdx.x * 64, y = blockIdx.y, b = blockIdx.z;
    const int c0 = cg * 8;

    float acc[8][8];
#pragma unroll
    for (int i = 0; i < 8; ++i)
#pragma unroll
        for (int j = 0; j < 8; ++j) acc[i][j] = 0.f;

    for (int chunk = 0; chunk < 16; ++chunk) {
        const int ci0 = chunk * 4;
        __syncthreads();
        for (int i = tid; i < 4 * 3 * 68; i += 256) {
            int xx = i % 68, t2 = i / 68;
            int r = t2 % 3, ci = t2 / 3;
            int gx = x0 - 1 + xx, gy = y - 1 + r;
            float v = 0.f;
            if (gx >= 0 && gx < FW && gy >= 0 && gy < FH)
                v = gload(feat, ((long)(b * CIN + ci0 + ci) * FH + gy) * FW + gx, bf);
            in_lds[ci][r][xx] = v;
        }
        {
            const float4* src = (const float4*)(w1t + (long)ci0 * 9 * 256);
            float4* dst = (float4*)u.w;
            for (int i = tid; i < 36 * 256 / 4; i += 256) dst[i] = src[i];
        }
        __syncthreads();
#pragma unroll
        for (int ci = 0; ci < 4; ++ci) {
#pragma unroll
            for (int ky = 0; ky < 3; ++ky) {
                const float* rowp = &in_lds[ci][ky][xg * 8];
                float inv[10];
                *(float4*)&inv[0] = *(const float4*)&rowp[0];
                *(float4*)&inv[4] = *(const float4*)&rowp[4];
                *(float2*)&inv[8] = *(const float2*)&rowp[8];
#pragma unroll
                for (int kx = 0; kx < 3; ++kx) {
                    const float* wp = &u.w[(ci * 9 + ky * 3 + kx) * 256 + c0];
                    float wv[8];
                    *(float4*)&wv[0] = *(const float4*)&wp[0];
                    *(float4*)&wv[4] = *(const float4*)&wp[4];
#pragma unroll
                    for (int cc = 0; cc < 8; ++cc)
#pragma unroll
                        for (int xx = 0; xx < 8; ++xx)
                            acc[cc][xx] = fmaf(wv[cc], inv[xx + kx], acc[cc][xx]);
                }
            }
        }
    }

#pragma unroll
    for (int cc = 0; cc < 8; ++cc) {
        float b1v = bp[c0 + cc];
#pragma unroll
        for (int xx = 0; xx < 8; ++xx)
            acc[cc][xx] = fmaxf(acc[cc][xx] + b1v, 0.f);
    }

    __syncthreads();
#pragma unroll
    for (int k = 0; k < OC; ++k) {
        float p[8];
#pragma unroll
        for (int xx = 0; xx < 8; ++xx) p[xx] = 0.f;
#pragma unroll
        for (int cc = 0; cc < 8; ++cc) {
            float wv = bp[256 + k * 256 + c0 + cc];
#pragma unroll
            for (int xx = 0; xx < 8; ++xx) p[xx] = fmaf(acc[cc][xx], wv, p[xx]);
        }
#pragma unroll
        for (int xx = 0; xx < 8; ++xx)
            u.part[(cg * OC + k) * 64 + xg * 8 + xx] = p[xx];
    }
    __syncthreads();
    for (int t = tid; t < OC * 64; t += 256) {
        int k = t >> 6, xx = t & 63;
        float s = bp[256 + OC * 256 + k];
#pragma unroll 8
        for (int g = 0; g < 32; ++g) s += u.part[(g * OC + k) * 64 + xx];
        long o = (((long)b * OC + k) * FH + y) * FW + x0 + xx;
        gstore(outb, obase + o, s, bf);
        outf[o] = s;
    }
}

// =====================================================================
// NMS
// =====================================================================
__global__ void kNms(const float* __restrict__ heat, float* __restrict__ nh) {
    int idx = blockIdx.x * 256 + threadIdx.x;
    if (idx >= 737280) return;
    int x = idx % FW, t = idx / FW;
    int yy = t % FH, bc = t / FH;
    const float* p = heat + (long)bc * HW;
    float v = p[yy * FW + x];
    float m = v;
    for (int dy = -1; dy <= 1; ++dy) {
        int ny = yy + dy;
        if (ny < 0 || ny >= FH) continue;
        for (int dx = -1; dx <= 1; ++dx) {
            int nx = x + dx;
            if (nx < 0 || nx >= FW) continue;
            m = fmaxf(m, p[ny * FW + nx]);
        }
    }
    nh[idx] = (v == m) ? v : 0.f;
}

// =====================================================================
// top-k stage A: per (bc, chunk) local top-50 via single-wave extraction.
// =====================================================================
__global__ __launch_bounds__(256)
void kTopA(float* __restrict__ nh) {
    __shared__ u64 keys[CHUNK];
    const int bc = blockIdx.x, ch = blockIdx.y;
    const int tid = threadIdx.x;
    const long base = (long)bc * HW + (long)ch * CHUNK;
    for (int i = tid; i < CHUNK; i += 256)
        keys[i] = packKey(nh[base + i], ch * CHUNK + i);
    __syncthreads();
    if (tid < 64) {
        const int lane = tid;
        u64* outp = (u64*)(nh + base);
        for (int it = 0; it < KDET; ++it) {
            u64 bk = ~0ULL; int bp = 0;
            for (int i = lane; i < CHUNK; i += 64) {
                u64 k = keys[i];
                if (k < bk) { bk = k; bp = i; }
            }
#pragma unroll
            for (int s = 32; s > 0; s >>= 1) {
                u64 k2 = __shfl_down(bk, s);
                int p2 = __shfl_down(bp, s);
                if (k2 < bk) { bk = k2; bp = p2; }
            }
            bk = __shfl(bk, 0);
            bp = __shfl(bp, 0);
            if (lane == 0) {
                outp[it] = bk;
                keys[bp] = ~0ULL;
            }
        }
    }
}

// =====================================================================
// top-k stage B: merge 16x50 chunk keys -> sorted per-(b,c) top-50
// =====================================================================
__global__ __launch_bounds__(64)
void kTopB(const float* __restrict__ nh, float* __restrict__ s1s,
           int* __restrict__ s1i) {
    __shared__ u64 keys[NCHUNK * KDET];
    const int bc = blockIdx.x, lane = threadIdx.x;
    for (int ch = 0; ch < NCHUNK; ++ch) {
        const u64* src = (const u64*)(nh + (long)bc * HW + (long)ch * CHUNK);
        if (lane < KDET) keys[ch * KDET + lane] = src[lane];
    }
    __syncthreads();
    for (int it = 0; it < KDET; ++it) {
        u64 bk = ~0ULL; int bp = 0;
        for (int i = lane; i < NCHUNK * KDET; i += 64) {
            u64 k = keys[i];
            if (k < bk) { bk = k; bp = i; }
        }
#pragma unroll
        for (int s = 32; s > 0; s >>= 1) {
            u64 k2 = __shfl_down(bk, s);
            int p2 = __shfl_down(bp, s);
            if (k2 < bk) { bk = k2; bp = p2; }
        }
        bk = __shfl(bk, 0);
        bp = __shfl(bp, 0);
        if (lane == 0) {
            u32 hm = ~(u32)(bk >> 32);
            u32 u = (hm & 0x80000000u) ? (hm & 0x7fffffffu) : ~hm;
            s1s[bc * KDET + it] = __uint_as_float(u);
            s1i[bc * KDET + it] = (int)(bk & 0xFFFFFFFFu);
            keys[bp] = ~0ULL;
        }
    }
}

// =====================================================================
// top-50 stage 2 + boxes
// =====================================================================
__global__ void kTop2(const float* __restrict__ s1s, const int* __restrict__ s1i,
                      const float* __restrict__ off2, const float* __restrict__ siz2,
                      float* __restrict__ boxes, int* __restrict__ clsArr) {
    const int b = blockIdx.x, t = threadIdx.x;    // 64 threads
    __shared__ float sc[150];
    for (int i = t; i < 150; i += 64) sc[i] = s1s[b * 150 + i];
    __syncthreads();
    for (int r = 0; r < KDET; ++r) {
        float bv = -INFINITY; int bp = 0x7fffffff;
        for (int i = t; i < 150; i += 64) {
            float v = sc[i];
            if (v > bv) { bv = v; bp = i; }
        }
        for (int s = 32; s > 0; s >>= 1) {
            float v2 = __shfl_down(bv, s);
            int   p2 = __shfl_down(bp, s);
            if (v2 > bv || (v2 == bv && p2 < bp)) { bv = v2; bp = p2; }
        }
        if (t == 0) {
            int cls = bp / KDET;
            int ind = s1i[b * 150 + bp];
            int n = b * KDET + r;
            clsArr[n] = cls;
            int x = ind % FW, yy = ind / FW;
            float cx = (float)x  + off2[(((long)b * 2 + 0) * FH + yy) * FW + x];
            float cy = (float)yy + off2[(((long)b * 2 + 1) * FH + yy) * FW + x];
            float w  = siz2[(((long)b * 2 + 0) * FH + yy) * FW + x];
            float h  = siz2[(((long)b * 2 + 1) * FH + yy) * FW + x];
            boxes[n * 5 + 0] = (float)b;
            boxes[n * 5 + 1] = cx - w * 0.5f;
            boxes[n * 5 + 2] = cy - h * 0.5f;
            boxes[n * 5 + 3] = cx + w * 0.5f;
            boxes[n * 5 + 4] = cy + h * 0.5f;
            sc[bp] = -INFINITY;
        }
        __syncthreads();
    }
}

// =====================================================================
// ROI align 7x7 (sr=2) + coord maps + one-hot -> roi_in f32
// =====================================================================
__global__ __launch_bounds__(256)
void kRoi(const void* __restrict__ feat, const int* __restrict__ flag,
          const float* __restrict__ boxes, const int* __restrict__ clsArr,
          const float* __restrict__ par, float* __restrict__ roi_in) {
    const int n = blockIdx.x, tid = threadIdx.x;
    const int bf = *flag;
    __shared__ int   x0s[14], x1s[14], y0s[14], y1s[14], vxs[14], vys[14];
    __shared__ float lxs[14], lys[14], cxs[7], cys[7];

    const float bx1 = boxes[n * 5 + 1], by1 = boxes[n * 5 + 2];
    const float bx2 = boxes[n * 5 + 3], by2 = boxes[n * 5 + 4];
    const int b = (int)boxes[n * 5 + 0];

    if (tid < 14) {
        float roi_w = fmaxf(bx2 - bx1, 1.f);
        float X = bx1 + (roi_w / 7.f) * ((tid + 0.5f) * 0.5f);
        vxs[tid] = (X > -1.f) && (X < (float)FW);
        float Xc = fminf(fmaxf(X, 0.f), (float)(FW - 1));
        int xi = (int)floorf(Xc);
        x0s[tid] = xi; x1s[tid] = min(xi + 1, FW - 1); lxs[tid] = Xc - (float)xi;
    } else if (tid >= 16 && tid < 30) {
        int i = tid - 16;
        float roi_h = fmaxf(by2 - by1, 1.f);
        float Y = by1 + (roi_h / 7.f) * ((i + 0.5f) * 0.5f);
        vys[i] = (Y > -1.f) && (Y < (float)FH);
        float Yc = fminf(fmaxf(Y, 0.f), (float)(FH - 1));
        int yi = (int)floorf(Yc);
        y0s[i] = yi; y1s[i] = min(yi + 1, FH - 1); lys[i] = Yc - (float)yi;
    } else if (tid >= 32 && tid < 46) {
        int j = tid - 32;
        const float* cal = par + PB_CAL + b * 12;
        float f_u = cal[0], c_u = cal[2], t03 = cal[3];
        float f_v = cal[5], c_v = cal[6], t13 = cal[7];
        float bxc = t03 / (-f_u), byc = t13 / (-f_v);
        const float* cr = par + PB_CRN + b * 4;
        float crx0 = cr[0], cry0 = cr[1], crx1 = cr[2], cry1 = cr[3];
        float sx = crx1 - crx0, sy = cry1 - cry0;
        float u1 = bx1 / (float)FW * sx + crx0, v1 = by1 / (float)FH * sy + cry0;
        float u2 = bx2 / (float)FW * sx + crx0, v2 = by2 / (float)FH * sy + cry0;
        float p1x = (u1 - c_u) / f_u + bxc, p1y = (v1 - c_v) / f_v + byc;
        float p2x = (u2 - c_u) / f_u + bxc, p2y = (v2 - c_v) / f_v + byc;
        if (j < 7) cxs[j] = p1x + ((float)j / 6.f) * (p2x - p1x);
        else       cys[j - 7] = p1y + ((float)(j - 7) / 6.f) * (p2y - p1y);
    }
    __syncthreads();

    for (int t = tid; t < CIN * 49; t += 256) {
        int c = t / 49, p = t % 49, oy = p / 7, ox = p % 7;
        long fb = ((long)b * CIN + c) * HW;
        float acc = 0.f;
#pragma unroll
        for (int dy = 0; dy < 2; ++dy) {
            int sy = oy * 2 + dy;
            float ly = lys[sy]; int yA = y0s[sy], yB = y1s[sy], vy = vys[sy];
#pragma unroll
            for (int dx = 0; dx < 2; ++dx) {
                int sx = ox * 2 + dx;
                float lx = lxs[sx]; int xA = x0s[sx], xB = x1s[sx];
                float v = (1.f - ly) * (1.f - lx) * gload(feat, fb + yA * FW + xA, bf)
                        + (1.f - ly) * lx         * gload(feat, fb + yA * FW + xB, bf)
                        + ly * (1.f - lx)         * gload(feat, fb + yB * FW + xA, bf)
                        + ly * lx                 * gload(feat, fb + yB * FW + xB, bf);
                if (!(vy && vxs[sx])) v = 0.f;
                acc += v;
            }
        }
        roi_in[((long)n * CROI + c) * 49 + p] = acc * 0.25f;
    }
    int cls = clsArr[n];
    for (int t = tid; t < 5 * 49; t += 256) {
        int ch = t / 49, p = t % 49, i = p / 7, j = p % 7;
        float v;
        if (ch == 0)      v = cxs[j];
        else if (ch == 1) v = cys[i];
        else              v = (cls == ch - 2) ? 1.f : 0.f;
        roi_in[((long)n * CROI + 64 + ch) * 49 + p] = v;
    }
}

// =====================================================================
// MFMA ROI head: conv3x3(69->256,pad1) as 9 taps x 3 k-steps GEMM
// rows padded to 104 elems (52 banks, gcd(20,32)=4 -> 2-way = free)
// =====================================================================
__global__ __launch_bounds__(256, 2)
void kHeadM(const float* __restrict__ roi_in, const u16* __restrict__ whb,
            const float* __restrict__ par, float* __restrict__ head_out) {
    const int h = blockIdx.x, n = blockIdx.y, tid = threadIdx.x;
    const int wave = tid >> 6, lane = tid & 63;
    const int q = lane >> 4, n15 = lane & 15;
    const int ocArr[4] = {2, 2, 4, 24};
    const int offArr[4] = {0, 2, 4, 8};
    __shared__ __align__(16) u16 r_lds[9][9][104];   // padded roi, ci-contig
    __shared__ __align__(16) u16 w_lds[256][104];    // per-tap weights [oc][ci]
    __shared__ float means[256];

    for (int i = tid; i < 9 * 9 * 104 / 8; i += 256)
        ((uint4*)r_lds)[i] = (uint4){0, 0, 0, 0};
    __syncthreads();
    const float* rp = roi_in + (long)n * CROI * 49;
    for (int i = tid; i < CROI * 49; i += 256) {
        int c = i / 49, p = i % 49;
        r_lds[p / 7 + 1][p % 7 + 1][c] = f2b(rp[i]);
    }

    int oyA[4], oxA[4];
#pragma unroll
    for (int i = 0; i < 4; ++i) {
        int pos = i * 16 + n15; if (pos > 48) pos = 48;
        oyA[i] = pos / 7; oxA[i] = pos % 7;
    }

    f32x4 acc[4][4];
#pragma unroll
    for (int i = 0; i < 4; ++i)
#pragma unroll
        for (int t = 0; t < 4; ++t) acc[i][t] = (f32x4){0.f, 0.f, 0.f, 0.f};

    for (int tap = 0; tap < 9; ++tap) {
        __syncthreads();
        const u16* wt = whb + ((long)h * 9 + tap) * 24576;   // [3][256][32]
        for (int i = tid; i < 3072; i += 256) {
            int cs = i >> 10, oc = (i & 1023) >> 2, seg = i & 3;
            *(uint4*)&w_lds[oc][cs * 32 + seg * 8] =
                *(const uint4*)(wt + ((cs << 8) + oc) * 32 + seg * 8);
        }
        __syncthreads();
        const int ky = tap / 3, kx = tap % 3;
#pragma unroll
        for (int cs = 0; cs < 3; ++cs) {
            short8 afr[4], bfr[4];
#pragma unroll
            for (int i = 0; i < 4; ++i)
                afr[i] = *(const short8*)&r_lds[oyA[i] + ky][oxA[i] + kx][cs * 32 + q * 8];
#pragma unroll
            for (int t = 0; t < 4; ++t)
                bfr[t] = *(const short8*)&w_lds[wave * 64 + t * 16 + n15][cs * 32 + q * 8];
#pragma unroll
            for (int i = 0; i < 4; ++i)
#pragma unroll
                for (int t = 0; t < 4; ++t)
                    acc[i][t] = __builtin_amdgcn_mfma_f32_16x16x32_bf16(
                        afr[i], bfr[t], acc[i][t], 0, 0, 0);
        }
    }

    const float* hb = par + PB_HD0 + h * 7456;
#pragma unroll
    for (int t = 0; t < 4; ++t) {
        int oc = wave * 64 + t * 16 + n15;
        float b1 = hb[oc], g = hb[256 + oc], be = hb[512 + oc];
        float m = hb[768 + oc], v = hb[1024 + oc];
        float scale = g / sqrtf(v + 1e-5f);
        float s = 0.f;
#pragma unroll
        for (int i = 0; i < 4; ++i)
#pragma unroll
            for (int r = 0; r < 4; ++r) {
                int pos = i * 16 + q * 4 + r;
                if (pos < 49)
                    s += fmaxf((acc[i][t][r] + b1 - m) * scale + be, 0.f);
            }
        s += __shfl_xor(s, 16);
        s += __shfl_xor(s, 32);
        if (q == 0) means[oc] = s / 49.f;
    }
    __syncthreads();

    int oc_out = ocArr[h];
    const float* w2 = hb + 1280;
    for (int k = wave; k < oc_out; k += 4) {
        float s = 0.f;
        for (int c = lane; c < 256; c += 64) s += means[c] * w2[k * 256 + c];
#pragma unroll
        for (int off = 32; off > 0; off >>= 1) s += __shfl_down(s, off);
        if (lane == 0)
            head_out[(long)n * 32 + offArr[h] + k] = s + w2[oc_out * 256 + k];
    }
}

// =====================================================================
// Final scalar math + small outputs
// =====================================================================
__global__ void kFinal(const float* __restrict__ head_out, const float* __restrict__ boxes,
                       const int* __restrict__ clsArr, const float* __restrict__ par,
                       void* __restrict__ out, const int* __restrict__ flag) {
    int n = blockIdx.x * 256 + threadIdx.x;
    if (n >= NROI) return;
    const int bf = *flag;
    const float* ho = head_out + (long)n * 32;
    float dep0 = ho[0], dep1 = ho[1];
    int b = (int)boxes[n * 5 + 0];
    int cls = clsArr[n];

    for (int j = 0; j < 24; ++j) gstore(out, O_HEAD + n * 24 + j, ho[8 + j], bf);
    gstore(out, O_OFF3 + n * 2 + 0, ho[2], bf);
    gstore(out, O_OFF3 + n * 2 + 1, ho[3], bf);
    gstore(out, O_S3D + n * 3 + 0, ho[4], bf);
    gstore(out, O_S3D + n * 3 + 1, ho[5], bf);
    gstore(out, O_S3D + n * 3 + 2, ho[6], bf);
    gstore(out, O_H3D + n, ho[7], bf);

    float cry0 = par[PB_CRN + b * 4 + 1], cry1 = par[PB_CRN + b * 4 + 3];
    float sy = cry1 - cry0;
    float bi2 = boxes[n * 5 + 2] / (float)FH * sy + cry0;
    float bi4 = boxes[n * 5 + 4] / (float)FH * sy + cry0;
    float box_h = fmaxf(bi4 - bi2, 1.f);
    float f_u = par[PB_CAL + b * 12 + 0];
    float size3d0 = par[PB_MSZ + cls * 3 + 0] + ho[4];
    float depth_geo = size3d0 / box_h * f_u;
    float sig = 1.f / (1.f + expf(-dep0));
    float d0 = 1.f / (sig + 1e-6f) - 1.f + depth_geo;
    float dgls = ho[7] + 2.f * (logf(f_u) - logf(box_h));
    float mx = fmaxf(dep1, dgls);
    float lse = mx + logf(expf(dep1 - mx) + expf(dgls - mx));
    gstore(out, O_DEP + n * 2 + 0, d0, bf);
    gstore(out, O_DEP + n * 2 + 1, lse, bf);
}

// =====================================================================
extern "C" void kernel_launch(void* const* d_in, const int* in_sizes, int n_in,
                              void* d_out, int out_size, void* d_ws, size_t ws_size,
                              hipStream_t stream) {
    (void)in_sizes; (void)n_in; (void)out_size; (void)ws_size;
    float* ws = (float*)d_ws;
    float* par = ws + WS_PAR;
    int* flag = (int*)(ws + WS_FLAG);
    u16* wb16 = (u16*)(ws + WS_WB16);
    u16* whb  = (u16*)(ws + WS_W1H);
    const void* feat = d_in[0];

    kDetect<<<1, 512, 0, stream>>>(feat, flag);

    WPtrs WP;
    WP.bw[0] = d_in[4]; WP.bw[1] = d_in[8]; WP.bw[2] = d_in[12];
    WP.hw[0] = d_in[16]; WP.hw[1] = d_in[24]; WP.hw[2] = d_in[32]; WP.hw[3] = d_in[40];
    kPrepW<<<5760, 256, 0, stream>>>(WP, flag, ws + WS_W1T, wb16, whb);

    Segs SG; int si = 0;
    auto add = [&](const void* s, int n, int dst) {
        SG.s[si].src = s; SG.s[si].n = n; SG.s[si].dst = dst; ++si;
    };
    add(d_in[1], 96, PB_CAL); add(d_in[2], 32, PB_CRN); add(d_in[3], 9, PB_MSZ);
    const int ocb[3] = {3, 2, 2};
    for (int b = 0; b < 3; ++b) {
        int base = PB_BR0 + b * 1040;
        int i0 = 4 + 4 * b;
        add(d_in[i0 + 1], 256, base);
        add(d_in[i0 + 2], ocb[b] * 256, base + 256);
        add(d_in[i0 + 3], ocb[b], base + 256 + ocb[b] * 256);
    }
    const int och[4] = {2, 2, 4, 24};
    for (int h = 0; h < 4; ++h) {
        int base = PB_HD0 + h * 7456;
        int i0 = 16 + 8 * h;
        add(d_in[i0 + 1], 256, base);
        add(d_in[i0 + 2], 256, base + 256);
        add(d_in[i0 + 3], 256, base + 512);
        add(d_in[i0 + 4], 256, base + 768);
        add(d_in[i0 + 5], 256, base + 1024);
        add(d_in[i0 + 6], och[h] * 256, base + 1280);
        add(d_in[i0 + 7], och[h], base + 1280 + och[h] * 256);
    }
    kPrepP<<<si, 256, 0, stream>>>(SG, flag, par);

    // merged MFMA branches (all 3 in one dispatch, reg-prefetch pipelined)
    kBranch3<<<dim3(5, 48, 24), 512, 0, stream>>>(
        feat, flag, wb16, par + PB_BR0, d_out, ws);

    // exact f32 strip for NMS/topk decision region (rows 0..4 of heat)
    kBranchX<<<dim3(5, 5, 8), 256, 0, stream>>>(
        feat, flag, ws + WS_W1T, par + PB_BR0, d_out, O_HEAT, ws + WS_HEAT);

    kNms<<<2880, 256, 0, stream>>>(ws + WS_HEAT, ws + WS_NH);
    kTopA<<<dim3(24, NCHUNK), 256, 0, stream>>>(ws + WS_NH);
    kTopB<<<24, 64, 0, stream>>>(ws + WS_NH, ws + WS_S1S, (int*)(ws + WS_S1I));
    kTop2<<<8, 64, 0, stream>>>(ws + WS_S1S, (int*)(ws + WS_S1I), ws + WS_OFF2,
                                ws + WS_SIZ2, ws + WS_BOX, (int*)(ws + WS_CLS));
    kRoi<<<400, 256, 0, stream>>>(feat, flag, ws + WS_BOX, (int*)(ws + WS_CLS),
                                  par, ws + WS_ROI);
    kHeadM<<<dim3(4, NROI), 256, 0, stream>>>(ws + WS_ROI, whb, par, ws + WS_HOUT);
    kFinal<<<2, 256, 0, stream>>>(ws + WS_HOUT, ws + WS_BOX, (int*)(ws + WS_CLS),
                                  par, d_out, flag);
}

// Round 8
// 1340.466 us; speedup vs baseline: 1.0305x; 1.0305x over previous
//
#include <hip/hip_runtime.h>
#include <math.h>

typedef unsigned short u16;
typedef unsigned int   u32;
typedef unsigned long long u64;
typedef __attribute__((ext_vector_type(8))) short short8;   // 8 bf16 (4 VGPR)
typedef __attribute__((ext_vector_type(4))) float f32x4;    // MFMA acc

// ---------- dtype helpers ----------
__device__ __forceinline__ float b2f(u16 v) { return __uint_as_float(((u32)v) << 16); }
__device__ __forceinline__ u16 f2b(float f) {
    u32 u = __float_as_uint(f);
    u32 r = (u + 0x7FFFu + ((u >> 16) & 1u)) >> 16;   // RNE
    return (u16)r;
}
__device__ __forceinline__ float gload(const void* p, long i, int bf) {
    return bf ? b2f(((const u16*)p)[i]) : ((const float*)p)[i];
}
__device__ __forceinline__ void gstore(void* p, long i, float v, int bf) {
    if (bf) ((u16*)p)[i] = f2b(v);
    else    ((float*)p)[i] = v;
}

// top-k key: smallest key = (largest value, then smallest index)
__device__ __forceinline__ u64 packKey(float v, int idx) {
    u32 u = __float_as_uint(v);
    u32 m = (u & 0x80000000u) ? ~u : (u | 0x80000000u);   // monotone float->uint
    return ((u64)(~m) << 32) | (u32)idx;
}

// ---------- problem constants ----------
#define BATCH 8
#define CIN   64
#define FH    96
#define FW    320
#define KDET  50
#define NROI  400
#define CROI  69
#define HW    (FH*FW)
#define CHUNK 1920
#define NCHUNK 16

// ---------- workspace layout (float offsets) ----------
#define WS_HEAT 0L
#define WS_OFF2 737280L
#define WS_SIZ2 1228800L
#define WS_NH   1720320L
#define WS_S1S  2457600L
#define WS_S1I  2458800L
#define WS_CLS  2460000L
#define WS_BOX  2460400L
#define WS_ROI  2462400L
#define WS_HOUT 3814800L
#define WS_W1T  3827600L     // 147456 f32: hm conv1 [k=576][c=256] (exact strip)
#define WS_WB16 3975056L     // u16: 3 branches * [9][2][256][32] bf16 (lane-coalesced)
#define WS_W1H  4269968L     // u16: 4 heads * [9][3][256][32] bf16
#define WS_PAR  4905872L     // packed f32 params
#define WS_FLAG 4938960L     // int dtype flag

// param block sub-offsets
#define PB_CAL 0
#define PB_CRN 96
#define PB_MSZ 128
#define PB_BR0 144          // stride 1040: b1@0, w2@256 ([k][n]), b2@256+OC*256
#define PB_HD0 3264         // stride 7456

// ---------- output layout (element offsets) ----------
#define O_HEAT 0L
#define O_OFF2 737280L
#define O_SIZ2 1228800L
#define O_HEAD 1720320L
#define O_DEP  1729920L
#define O_OFF3 1730720L
#define O_S3D  1731520L
#define O_H3D  1732720L

// =====================================================================
// dtype detection
// =====================================================================
__global__ void kDetect(const void* __restrict__ feat, int* __restrict__ flag) {
    __shared__ int cnt;
    if (threadIdx.x == 0) cnt = 0;
    __syncthreads();
    u16 v = ((const u16*)feat)[threadIdx.x];     // 512 threads
    float f = b2f(v);
    u32 e = (v >> 7) & 0xFF;
    float a = fabsf(f);
    int sane = (e != 0xFF) && (f == 0.f || (a >= 1e-8f && a <= 1e4f));
    atomicAdd(&cnt, sane);
    __syncthreads();
    if (threadIdx.x == 0) *flag = (cnt >= 480) ? 1 : 0;
}

// =====================================================================
// Prep: weights
//  region 1: hm conv1 f32 [k=576][c=256]              (exact strip)
//  region 2: 3 branches bf16 [tap][s][n=256][32]      (direct B-frag loads)
//  region 3: 4 heads bf16 [tap][cs=3][oc=256][32]     (direct B-frag loads)
// =====================================================================
struct WPtrs { const void* bw[3]; const void* hw[4]; };

__global__ void kPrepW(WPtrs P, const int* __restrict__ flag,
                       float* __restrict__ w1t, u16* __restrict__ wb16,
                       u16* __restrict__ whb) {
    const int bf = *flag;
    int idx = blockIdx.x * 256 + threadIdx.x;
    if (idx < 147456) {
        int k = idx >> 8, c = idx & 255;
        w1t[idx] = gload(P.bw[0], (long)c * 576 + k, bf);
    } else if (idx < 589824) {
        int j = idx - 147456;
        int br = j / 147456, rem = j % 147456;
        int tap = rem / 16384;
        int r2 = rem & 16383;
        int s = r2 >> 13;
        int n = (r2 >> 5) & 255;
        int c5 = r2 & 31;
        int ci = s * 32 + c5;
        wb16[j] = f2b(gload(P.bw[br], (long)n * 576 + ci * 9 + tap, bf));
    } else {
        int j = idx - 589824;               // < 884736
        int h = j / 221184, rem = j % 221184;
        int tap = rem / 24576, rem2 = rem % 24576;
        int cs = rem2 / 8192, rem3 = rem2 % 8192;
        int oc = rem3 >> 5, jj = rem3 & 31;
        int ci = cs * 32 + jj;
        u16 val = 0;
        if (ci < CROI) val = f2b(gload(P.hw[h], (long)oc * 621 + ci * 9 + tap, bf));
        whb[j] = val;
    }
}

// Prep: pack all small params to f32
struct Seg { const void* src; int n; int dst; };
struct Segs { Seg s[40]; };

__global__ void kPrepP(Segs S, const int* __restrict__ flag, float* __restrict__ par) {
    const int bf = *flag;
    Seg sg = S.s[blockIdx.x];
    for (int i = threadIdx.x; i < sg.n; i += 256)
        par[sg.dst + i] = gload(sg.src, i, bf);
}

// =====================================================================
// Merged MFMA branch conv: all 3 branches, 512 thr, M=128 (2 rows x 64 x)
// conv3x3(64->256) as 9 shifted GEMMs + b1 + ReLU + 1x1(->oc) + b2
// grid (5, 48, 24); z = br*8 + b. Wave owns 32 n; 8 M-tiles x 2 N-tiles.
// B-fragments load DIRECTLY from global (per-wave slices, coalesced 16B);
// K-loop is barrier-free.
// =====================================================================
union B3U {
    u16   a[4][68][72];       // input rows y0-1..y0+2, x0-1..x0+64, 64ci (pad 72)
    float red[8][128][3];     // 1x1 partials per wave
};

__global__ __launch_bounds__(512, 4)
void kBranch3(const void* __restrict__ feat, const int* __restrict__ flag,
              const u16* __restrict__ wbAll,   // 3 * [9][2][256][32] bf16
              const float* __restrict__ bpAll, // par + PB_BR0, stride 1040
              void* __restrict__ outb, float* __restrict__ wsbase) {
    __shared__ __align__(16) B3U u;

    const long obase[3] = {O_HEAT, O_OFF2, O_SIZ2};
    const long wfs[3]   = {WS_HEAT, WS_OFF2, WS_SIZ2};

    const int bfl = *flag;
    const int tid = threadIdx.x;
    const int wave = tid >> 6, lane = tid & 63;
    const int q = lane >> 4, n15 = lane & 15;
    const int x0 = blockIdx.x * 64, y0 = blockIdx.y * 2;
    const int br = blockIdx.z >> 3, b = blockIdx.z & 7;
    const int oc = (br == 0) ? 3 : 2;
    const u16* wpt = wbAll + br * 147456;
    const float* bp = bpAll + br * 1040;

    // ---- stage input tile: rows y0-1..y0+2, x0-1..x0+64, 64 ci ----
    if (tid < 256) {
        const int ci = tid & 63, rr = tid >> 6;
        const int gy = y0 - 1 + rr;
        if (gy < 0 || gy >= FH) {
            for (int xi = 0; xi < 66; ++xi) u.a[rr][xi][ci] = 0;
        } else if (bfl) {
            const u16* rp = (const u16*)feat + ((long)((b << 6) | ci) * FH + gy) * FW;
            for (int j = 0; j < 10; ++j) {
                int xs0 = x0 - 8 + j * 8;
                u16 tmp[8];
                if (xs0 >= 0 && xs0 <= FW - 8)
                    *(uint4*)tmp = *(const uint4*)(rp + xs0);
                else
                    for (int e = 0; e < 8; ++e) {
                        int gx = xs0 + e;
                        tmp[e] = (gx >= 0 && gx < FW) ? rp[gx] : (u16)0;
                    }
                for (int e = 0; e < 8; ++e) {
                    int xi = xs0 + e - x0 + 1;
                    if (xi >= 0 && xi < 66) u.a[rr][xi][ci] = tmp[e];
                }
            }
        } else {
            const float* rp = (const float*)feat + ((long)((b << 6) | ci) * FH + gy) * FW;
            for (int j = 0; j < 18; ++j) {
                int xs0 = x0 - 4 + j * 4;
                float tmp[4];
                if (xs0 >= 0 && xs0 <= FW - 4)
                    *(float4*)tmp = *(const float4*)(rp + xs0);
                else
                    for (int e = 0; e < 4; ++e) {
                        int gx = xs0 + e;
                        tmp[e] = (gx >= 0 && gx < FW) ? rp[gx] : 0.f;
                    }
                for (int e = 0; e < 4; ++e) {
                    int xi = xs0 + e - x0 + 1;
                    if (xi >= 0 && xi < 66) u.a[rr][xi][ci] = f2b(tmp[e]);
                }
            }
        }
    }
    __syncthreads();   // a_lds visible to all waves; no more barriers in K-loop

    f32x4 acc[8][2];
#pragma unroll
    for (int i = 0; i < 8; ++i)
#pragma unroll
        for (int t = 0; t < 2; ++t) acc[i][t] = (f32x4){0.f, 0.f, 0.f, 0.f};

    // ---- K-loop: 9 taps x 2 k-steps (32 ci each), barrier-free ----
#pragma unroll
    for (int tap = 0; tap < 9; ++tap) {
        const int ky = tap / 3, kx = tap % 3;
#pragma unroll
        for (int s = 0; s < 2; ++s) {
            const u16* wks = wpt + (tap * 2 + s) * 8192;
            short8 bfr[2];
#pragma unroll
            for (int t = 0; t < 2; ++t)
                bfr[t] = *(const short8*)(wks + (wave * 32 + t * 16 + n15) * 32 + q * 8);
#pragma unroll
            for (int ig = 0; ig < 2; ++ig) {
                short8 afr[4];
#pragma unroll
                for (int i = 0; i < 4; ++i) {
                    int it = ig * 4 + i;
                    int r = it >> 2, xb = (it & 3) * 16;
                    afr[i] = *(const short8*)&u.a[r + ky][xb + n15 + kx][s * 32 + q * 8];
                }
#pragma unroll
                for (int i = 0; i < 4; ++i)
#pragma unroll
                    for (int t = 0; t < 2; ++t)
                        acc[ig * 4 + i][t] = __builtin_amdgcn_mfma_f32_16x16x32_bf16(
                            afr[i], bfr[t], acc[ig * 4 + i][t], 0, 0, 0);
            }
        }
    }

    // ---- epilogue: b1 + relu + 1x1 partials ----
    float b1v[2], w2v[3][2];
#pragma unroll
    for (int t = 0; t < 2; ++t) {
        int n = wave * 32 + t * 16 + n15;
        b1v[t] = bp[n];
#pragma unroll
        for (int k = 0; k < 3; ++k) w2v[k][t] = bp[256 + k * 256 + n];
    }
    __syncthreads();   // done reading u.a; reuse as red
#pragma unroll
    for (int i = 0; i < 8; ++i) {
#pragma unroll
        for (int r = 0; r < 4; ++r) {
            float pk[3];
#pragma unroll
            for (int k = 0; k < 3; ++k) pk[k] = 0.f;
#pragma unroll
            for (int t = 0; t < 2; ++t) {
                float h = fmaxf(acc[i][t][r] + b1v[t], 0.f);
#pragma unroll
                for (int k = 0; k < 3; ++k) pk[k] = fmaf(h, w2v[k][t], pk[k]);
            }
#pragma unroll
            for (int k = 0; k < 3; ++k) {
                pk[k] += __shfl_xor(pk[k], 1);
                pk[k] += __shfl_xor(pk[k], 2);
                pk[k] += __shfl_xor(pk[k], 4);
                pk[k] += __shfl_xor(pk[k], 8);
            }
            if (n15 == 0) {
                int m = i * 16 + q * 4 + r;
#pragma unroll
                for (int k = 0; k < 3; ++k) u.red[wave][m][k] = pk[k];
            }
        }
    }
    __syncthreads();
    float* outf = wsbase + wfs[br];
    for (int t2 = tid; t2 < oc * 128; t2 += 512) {
        int k = t2 >> 7, m = t2 & 127;
        int row = m >> 6, x = m & 63;
        float s = bp[256 + oc * 256 + k];
#pragma unroll
        for (int w = 0; w < 8; ++w) s += u.red[w][m][k];
        long o = (((long)b * oc + k) * FH + (y0 + row)) * FW + x0 + x;
        gstore(outb, obase[br] + o, s, bfl);
        outf[o] = s;
    }
}

// =====================================================================
// Exact f32 strip (rows 0..4 of heat): NMS/topk decisions bit-match f32
// =====================================================================
union BrLds {
    float w[36 * 256];
    float part[32 * 3 * 64];
};

__global__ __launch_bounds__(256)
void kBranchX(const void* __restrict__ feat, const int* __restrict__ flag,
              const float* __restrict__ w1t, const float* __restrict__ bp,
              void* __restrict__ outb, long obase, float* __restrict__ outf) {
    __shared__ float in_lds[4][3][68];
    __shared__ BrLds u;
    const int bf = *flag;
    const int OC = 3;

    const int tid = threadIdx.x;
    const int xg = tid & 7, cg = tid >> 3;
    const int x0 = blockIdx.x * 64, y = blockIdx.y, b = blockIdx.z;
    const int c0 = cg * 8;

    float acc[8][8];
#pragma unroll
    for (int i = 0; i < 8; ++i)
#pragma unroll
        for (int j = 0; j < 8; ++j) acc[i][j] = 0.f;

    for (int chunk = 0; chunk < 16; ++chunk) {
        const int ci0 = chunk * 4;
        __syncthreads();
        for (int i = tid; i < 4 * 3 * 68; i += 256) {
            int xx = i % 68, t2 = i / 68;
            int r = t2 % 3, ci = t2 / 3;
            int gx = x0 - 1 + xx, gy = y - 1 + r;
            float v = 0.f;
            if (gx >= 0 && gx < FW && gy >= 0 && gy < FH)
                v = gload(feat, ((long)(b * CIN + ci0 + ci) * FH + gy) * FW + gx, bf);
            in_lds[ci][r][xx] = v;
        }
        {
            const float4* src = (const float4*)(w1t + (long)ci0 * 9 * 256);
            float4* dst = (float4*)u.w;
            for (int i = tid; i < 36 * 256 / 4; i += 256) dst[i] = src[i];
        }
        __syncthreads();
#pragma unroll
        for (int ci = 0; ci < 4; ++ci) {
#pragma unroll
            for (int ky = 0; ky < 3; ++ky) {
                const float* rowp = &in_lds[ci][ky][xg * 8];
                float inv[10];
                *(float4*)&inv[0] = *(const float4*)&rowp[0];
                *(float4*)&inv[4] = *(const float4*)&rowp[4];
                *(float2*)&inv[8] = *(const float2*)&rowp[8];
#pragma unroll
                for (int kx = 0; kx < 3; ++kx) {
                    const float* wp = &u.w[(ci * 9 + ky * 3 + kx) * 256 + c0];
                    float wv[8];
                    *(float4*)&wv[0] = *(const float4*)&wp[0];
                    *(float4*)&wv[4] = *(const float4*)&wp[4];
#pragma unroll
                    for (int cc = 0; cc < 8; ++cc)
#pragma unroll
                        for (int xx = 0; xx < 8; ++xx)
                            acc[cc][xx] = fmaf(wv[cc], inv[xx + kx], acc[cc][xx]);
                }
            }
        }
    }

#pragma unroll
    for (int cc = 0; cc < 8; ++cc) {
        float b1v = bp[c0 + cc];
#pragma unroll
        for (int xx = 0; xx < 8; ++xx)
            acc[cc][xx] = fmaxf(acc[cc][xx] + b1v, 0.f);
    }

    __syncthreads();
#pragma unroll
    for (int k = 0; k < OC; ++k) {
        float p[8];
#pragma unroll
        for (int xx = 0; xx < 8; ++xx) p[xx] = 0.f;
#pragma unroll
        for (int cc = 0; cc < 8; ++cc) {
            float wv = bp[256 + k * 256 + c0 + cc];
#pragma unroll
            for (int xx = 0; xx < 8; ++xx) p[xx] = fmaf(acc[cc][xx], wv, p[xx]);
        }
#pragma unroll
        for (int xx = 0; xx < 8; ++xx)
            u.part[(cg * OC + k) * 64 + xg * 8 + xx] = p[xx];
    }
    __syncthreads();
    for (int t = tid; t < OC * 64; t += 256) {
        int k = t >> 6, xx = t & 63;
        float s = bp[256 + OC * 256 + k];
#pragma unroll 8
        for (int g = 0; g < 32; ++g) s += u.part[(g * OC + k) * 64 + xx];
        long o = (((long)b * OC + k) * FH + y) * FW + x0 + xx;
        gstore(outb, obase + o, s, bf);
        outf[o] = s;
    }
}

// =====================================================================
// NMS
// =====================================================================
__global__ void kNms(const float* __restrict__ heat, float* __restrict__ nh) {
    int idx = blockIdx.x * 256 + threadIdx.x;
    if (idx >= 737280) return;
    int x = idx % FW, t = idx / FW;
    int yy = t % FH, bc = t / FH;
    const float* p = heat + (long)bc * HW;
    float v = p[yy * FW + x];
    float m = v;
    for (int dy = -1; dy <= 1; ++dy) {
        int ny = yy + dy;
        if (ny < 0 || ny >= FH) continue;
        for (int dx = -1; dx <= 1; ++dx) {
            int nx = x + dx;
            if (nx < 0 || nx >= FW) continue;
            m = fmaxf(m, p[ny * FW + nx]);
        }
    }
    nh[idx] = (v == m) ? v : 0.f;
}

// =====================================================================
// top-k stage A: per (bc, chunk) local top-50 via single-wave extraction.
// =====================================================================
__global__ __launch_bounds__(256)
void kTopA(float* __restrict__ nh) {
    __shared__ u64 keys[CHUNK];
    const int bc = blockIdx.x, ch = blockIdx.y;
    const int tid = threadIdx.x;
    const long base = (long)bc * HW + (long)ch * CHUNK;
    for (int i = tid; i < CHUNK; i += 256)
        keys[i] = packKey(nh[base + i], ch * CHUNK + i);
    __syncthreads();
    if (tid < 64) {
        const int lane = tid;
        u64* outp = (u64*)(nh + base);
        for (int it = 0; it < KDET; ++it) {
            u64 bk = ~0ULL; int bp = 0;
            for (int i = lane; i < CHUNK; i += 64) {
                u64 k = keys[i];
                if (k < bk) { bk = k; bp = i; }
            }
#pragma unroll
            for (int s = 32; s > 0; s >>= 1) {
                u64 k2 = __shfl_down(bk, s);
                int p2 = __shfl_down(bp, s);
                if (k2 < bk) { bk = k2; bp = p2; }
            }
            bk = __shfl(bk, 0);
            bp = __shfl(bp, 0);
            if (lane == 0) {
                outp[it] = bk;
                keys[bp] = ~0ULL;
            }
        }
    }
}

// =====================================================================
// top-k stage B: merge 16x50 chunk keys -> sorted per-(b,c) top-50
// =====================================================================
__global__ __launch_bounds__(64)
void kTopB(const float* __restrict__ nh, float* __restrict__ s1s,
           int* __restrict__ s1i) {
    __shared__ u64 keys[NCHUNK * KDET];
    const int bc = blockIdx.x, lane = threadIdx.x;
    for (int ch = 0; ch < NCHUNK; ++ch) {
        const u64* src = (const u64*)(nh + (long)bc * HW + (long)ch * CHUNK);
        if (lane < KDET) keys[ch * KDET + lane] = src[lane];
    }
    __syncthreads();
    for (int it = 0; it < KDET; ++it) {
        u64 bk = ~0ULL; int bp = 0;
        for (int i = lane; i < NCHUNK * KDET; i += 64) {
            u64 k = keys[i];
            if (k < bk) { bk = k; bp = i; }
        }
#pragma unroll
        for (int s = 32; s > 0; s >>= 1) {
            u64 k2 = __shfl_down(bk, s);
            int p2 = __shfl_down(bp, s);
            if (k2 < bk) { bk = k2; bp = p2; }
        }
        bk = __shfl(bk, 0);
        bp = __shfl(bp, 0);
        if (lane == 0) {
            u32 hm = ~(u32)(bk >> 32);
            u32 u = (hm & 0x80000000u) ? (hm & 0x7fffffffu) : ~hm;
            s1s[bc * KDET + it] = __uint_as_float(u);
            s1i[bc * KDET + it] = (int)(bk & 0xFFFFFFFFu);
            keys[bp] = ~0ULL;
        }
    }
}

// =====================================================================
// top-50 stage 2 + boxes
// =====================================================================
__global__ void kTop2(const float* __restrict__ s1s, const int* __restrict__ s1i,
                      const float* __restrict__ off2, const float* __restrict__ siz2,
                      float* __restrict__ boxes, int* __restrict__ clsArr) {
    const int b = blockIdx.x, t = threadIdx.x;    // 64 threads
    __shared__ float sc[150];
    for (int i = t; i < 150; i += 64) sc[i] = s1s[b * 150 + i];
    __syncthreads();
    for (int r = 0; r < KDET; ++r) {
        float bv = -INFINITY; int bp = 0x7fffffff;
        for (int i = t; i < 150; i += 64) {
            float v = sc[i];
            if (v > bv) { bv = v; bp = i; }
        }
        for (int s = 32; s > 0; s >>= 1) {
            float v2 = __shfl_down(bv, s);
            int   p2 = __shfl_down(bp, s);
            if (v2 > bv || (v2 == bv && p2 < bp)) { bv = v2; bp = p2; }
        }
        if (t == 0) {
            int cls = bp / KDET;
            int ind = s1i[b * 150 + bp];
            int n = b * KDET + r;
            clsArr[n] = cls;
            int x = ind % FW, yy = ind / FW;
            float cx = (float)x  + off2[(((long)b * 2 + 0) * FH + yy) * FW + x];
            float cy = (float)yy + off2[(((long)b * 2 + 1) * FH + yy) * FW + x];
            float w  = siz2[(((long)b * 2 + 0) * FH + yy) * FW + x];
            float h  = siz2[(((long)b * 2 + 1) * FH + yy) * FW + x];
            boxes[n * 5 + 0] = (float)b;
            boxes[n * 5 + 1] = cx - w * 0.5f;
            boxes[n * 5 + 2] = cy - h * 0.5f;
            boxes[n * 5 + 3] = cx + w * 0.5f;
            boxes[n * 5 + 4] = cy + h * 0.5f;
            sc[bp] = -INFINITY;
        }
        __syncthreads();
    }
}

// =====================================================================
// ROI align 7x7 (sr=2) + coord maps + one-hot -> roi_in f32
// =====================================================================
__global__ __launch_bounds__(256)
void kRoi(const void* __restrict__ feat, const int* __restrict__ flag,
          const float* __restrict__ boxes, const int* __restrict__ clsArr,
          const float* __restrict__ par, float* __restrict__ roi_in) {
    const int n = blockIdx.x, tid = threadIdx.x;
    const int bf = *flag;
    __shared__ int   x0s[14], x1s[14], y0s[14], y1s[14], vxs[14], vys[14];
    __shared__ float lxs[14], lys[14], cxs[7], cys[7];

    const float bx1 = boxes[n * 5 + 1], by1 = boxes[n * 5 + 2];
    const float bx2 = boxes[n * 5 + 3], by2 = boxes[n * 5 + 4];
    const int b = (int)boxes[n * 5 + 0];

    if (tid < 14) {
        float roi_w = fmaxf(bx2 - bx1, 1.f);
        float X = bx1 + (roi_w / 7.f) * ((tid + 0.5f) * 0.5f);
        vxs[tid] = (X > -1.f) && (X < (float)FW);
        float Xc = fminf(fmaxf(X, 0.f), (float)(FW - 1));
        int xi = (int)floorf(Xc);
        x0s[tid] = xi; x1s[tid] = min(xi + 1, FW - 1); lxs[tid] = Xc - (float)xi;
    } else if (tid >= 16 && tid < 30) {
        int i = tid - 16;
        float roi_h = fmaxf(by2 - by1, 1.f);
        float Y = by1 + (roi_h / 7.f) * ((i + 0.5f) * 0.5f);
        vys[i] = (Y > -1.f) && (Y < (float)FH);
        float Yc = fminf(fmaxf(Y, 0.f), (float)(FH - 1));
        int yi = (int)floorf(Yc);
        y0s[i] = yi; y1s[i] = min(yi + 1, FH - 1); lys[i] = Yc - (float)yi;
    } else if (tid >= 32 && tid < 46) {
        int j = tid - 32;
        const float* cal = par + PB_CAL + b * 12;
        float f_u = cal[0], c_u = cal[2], t03 = cal[3];
        float f_v = cal[5], c_v = cal[6], t13 = cal[7];
        float bxc = t03 / (-f_u), byc = t13 / (-f_v);
        const float* cr = par + PB_CRN + b * 4;
        float crx0 = cr[0], cry0 = cr[1], crx1 = cr[2], cry1 = cr[3];
        float sx = crx1 - crx0, sy = cry1 - cry0;
        float u1 = bx1 / (float)FW * sx + crx0, v1 = by1 / (float)FH * sy + cry0;
        float u2 = bx2 / (float)FW * sx + crx0, v2 = by2 / (float)FH * sy + cry0;
        float p1x = (u1 - c_u) / f_u + bxc, p1y = (v1 - c_v) / f_v + byc;
        float p2x = (u2 - c_u) / f_u + bxc, p2y = (v2 - c_v) / f_v + byc;
        if (j < 7) cxs[j] = p1x + ((float)j / 6.f) * (p2x - p1x);
        else       cys[j - 7] = p1y + ((float)(j - 7) / 6.f) * (p2y - p1y);
    }
    __syncthreads();

    for (int t = tid; t < CIN * 49; t += 256) {
        int c = t / 49, p = t % 49, oy = p / 7, ox = p % 7;
        long fb = ((long)b * CIN + c) * HW;
        float acc = 0.f;
#pragma unroll
        for (int dy = 0; dy < 2; ++dy) {
            int sy = oy * 2 + dy;
            float ly = lys[sy]; int yA = y0s[sy], yB = y1s[sy], vy = vys[sy];
#pragma unroll
            for (int dx = 0; dx < 2; ++dx) {
                int sx = ox * 2 + dx;
                float lx = lxs[sx]; int xA = x0s[sx], xB = x1s[sx];
                float v = (1.f - ly) * (1.f - lx) * gload(feat, fb + yA * FW + xA, bf)
                        + (1.f - ly) * lx         * gload(feat, fb + yA * FW + xB, bf)
                        + ly * (1.f - lx)         * gload(feat, fb + yB * FW + xA, bf)
                        + ly * lx                 * gload(feat, fb + yB * FW + xB, bf);
                if (!(vy && vxs[sx])) v = 0.f;
                acc += v;
            }
        }
        roi_in[((long)n * CROI + c) * 49 + p] = acc * 0.25f;
    }
    int cls = clsArr[n];
    for (int t = tid; t < 5 * 49; t += 256) {
        int ch = t / 49, p = t % 49, i = p / 7, j = p % 7;
        float v;
        if (ch == 0)      v = cxs[j];
        else if (ch == 1) v = cys[i];
        else              v = (cls == ch - 2) ? 1.f : 0.f;
        roi_in[((long)n * CROI + 64 + ch) * 49 + p] = v;
    }
}

// =====================================================================
// MFMA ROI head: conv3x3(69->256,pad1) as 9 taps x 3 k-steps GEMM
// B-frags load directly from global (whb layout is lane-coalesced);
// K-loop barrier-free. r_lds rows padded to 104 (2-way = free).
// =====================================================================
__global__ __launch_bounds__(256, 4)
void kHeadM(const float* __restrict__ roi_in, const u16* __restrict__ whb,
            const float* __restrict__ par, float* __restrict__ head_out) {
    const int h = blockIdx.x, n = blockIdx.y, tid = threadIdx.x;
    const int wave = tid >> 6, lane = tid & 63;
    const int q = lane >> 4, n15 = lane & 15;
    const int ocArr[4] = {2, 2, 4, 24};
    const int offArr[4] = {0, 2, 4, 8};
    __shared__ __align__(16) u16 r_lds[9][9][104];   // padded roi, ci-contig
    __shared__ float means[256];

    for (int i = tid; i < 9 * 9 * 104 / 8; i += 256)
        ((uint4*)r_lds)[i] = (uint4){0, 0, 0, 0};
    __syncthreads();
    const float* rp = roi_in + (long)n * CROI * 49;
    for (int i = tid; i < CROI * 49; i += 256) {
        int c = i / 49, p = i % 49;
        r_lds[p / 7 + 1][p % 7 + 1][c] = f2b(rp[i]);
    }
    __syncthreads();

    int oyA[4], oxA[4];
#pragma unroll
    for (int i = 0; i < 4; ++i) {
        int pos = i * 16 + n15; if (pos > 48) pos = 48;
        oyA[i] = pos / 7; oxA[i] = pos % 7;
    }

    f32x4 acc[4][4];
#pragma unroll
    for (int i = 0; i < 4; ++i)
#pragma unroll
        for (int t = 0; t < 4; ++t) acc[i][t] = (f32x4){0.f, 0.f, 0.f, 0.f};

#pragma unroll
    for (int tap = 0; tap < 9; ++tap) {
        const int ky = tap / 3, kx = tap % 3;
        const u16* wt = whb + ((long)h * 9 + tap) * 24576;   // [3][256][32]
#pragma unroll
        for (int cs = 0; cs < 3; ++cs) {
            short8 afr[4], bfr[4];
#pragma unroll
            for (int i = 0; i < 4; ++i)
                afr[i] = *(const short8*)&r_lds[oyA[i] + ky][oxA[i] + kx][cs * 32 + q * 8];
#pragma unroll
            for (int t = 0; t < 4; ++t)
                bfr[t] = *(const short8*)(wt + ((cs << 8) + wave * 64 + t * 16 + n15) * 32 + q * 8);
#pragma unroll
            for (int i = 0; i < 4; ++i)
#pragma unroll
                for (int t = 0; t < 4; ++t)
                    acc[i][t] = __builtin_amdgcn_mfma_f32_16x16x32_bf16(
                        afr[i], bfr[t], acc[i][t], 0, 0, 0);
        }
    }

    const float* hb = par + PB_HD0 + h * 7456;
#pragma unroll
    for (int t = 0; t < 4; ++t) {
        int oc = wave * 64 + t * 16 + n15;
        float b1 = hb[oc], g = hb[256 + oc], be = hb[512 + oc];
        float m = hb[768 + oc], v = hb[1024 + oc];
        float scale = g / sqrtf(v + 1e-5f);
        float s = 0.f;
#pragma unroll
        for (int i = 0; i < 4; ++i)
#pragma unroll
            for (int r = 0; r < 4; ++r) {
                int pos = i * 16 + q * 4 + r;
                if (pos < 49)
                    s += fmaxf((acc[i][t][r] + b1 - m) * scale + be, 0.f);
            }
        s += __shfl_xor(s, 16);
        s += __shfl_xor(s, 32);
        if (q == 0) means[oc] = s / 49.f;
    }
    __syncthreads();

    int oc_out = ocArr[h];
    const float* w2 = hb + 1280;
    for (int k = wave; k < oc_out; k += 4) {
        float s = 0.f;
        for (int c = lane; c < 256; c += 64) s += means[c] * w2[k * 256 + c];
#pragma unroll
        for (int off = 32; off > 0; off >>= 1) s += __shfl_down(s, off);
        if (lane == 0)
            head_out[(long)n * 32 + offArr[h] + k] = s + w2[oc_out * 256 + k];
    }
}

// =====================================================================
// Final scalar math + small outputs
// =====================================================================
__global__ void kFinal(const float* __restrict__ head_out, const float* __restrict__ boxes,
                       const int* __restrict__ clsArr, const float* __restrict__ par,
                       void* __restrict__ out, const int* __restrict__ flag) {
    int n = blockIdx.x * 256 + threadIdx.x;
    if (n >= NROI) return;
    const int bf = *flag;
    const float* ho = head_out + (long)n * 32;
    float dep0 = ho[0], dep1 = ho[1];
    int b = (int)boxes[n * 5 + 0];
    int cls = clsArr[n];

    for (int j = 0; j < 24; ++j) gstore(out, O_HEAD + n * 24 + j, ho[8 + j], bf);
    gstore(out, O_OFF3 + n * 2 + 0, ho[2], bf);
    gstore(out, O_OFF3 + n * 2 + 1, ho[3], bf);
    gstore(out, O_S3D + n * 3 + 0, ho[4], bf);
    gstore(out, O_S3D + n * 3 + 1, ho[5], bf);
    gstore(out, O_S3D + n * 3 + 2, ho[6], bf);
    gstore(out, O_H3D + n, ho[7], bf);

    float cry0 = par[PB_CRN + b * 4 + 1], cry1 = par[PB_CRN + b * 4 + 3];
    float sy = cry1 - cry0;
    float bi2 = boxes[n * 5 + 2] / (float)FH * sy + cry0;
    float bi4 = boxes[n * 5 + 4] / (float)FH * sy + cry0;
    float box_h = fmaxf(bi4 - bi2, 1.f);
    float f_u = par[PB_CAL + b * 12 + 0];
    float size3d0 = par[PB_MSZ + cls * 3 + 0] + ho[4];
    float depth_geo = size3d0 / box_h * f_u;
    float sig = 1.f / (1.f + expf(-dep0));
    float d0 = 1.f / (sig + 1e-6f) - 1.f + depth_geo;
    float dgls = ho[7] + 2.f * (logf(f_u) - logf(box_h));
    float mx = fmaxf(dep1, dgls);
    float lse = mx + logf(expf(dep1 - mx) + expf(dgls - mx));
    gstore(out, O_DEP + n * 2 + 0, d0, bf);
    gstore(out, O_DEP + n * 2 + 1, lse, bf);
}

// =====================================================================
extern "C" void kernel_launch(void* const* d_in, const int* in_sizes, int n_in,
                              void* d_out, int out_size, void* d_ws, size_t ws_size,
                              hipStream_t stream) {
    (void)in_sizes; (void)n_in; (void)out_size; (void)ws_size;
    float* ws = (float*)d_ws;
    float* par = ws + WS_PAR;
    int* flag = (int*)(ws + WS_FLAG);
    u16* wb16 = (u16*)(ws + WS_WB16);
    u16* whb  = (u16*)(ws + WS_W1H);
    const void* feat = d_in[0];

    kDetect<<<1, 512, 0, stream>>>(feat, flag);

    WPtrs WP;
    WP.bw[0] = d_in[4]; WP.bw[1] = d_in[8]; WP.bw[2] = d_in[12];
    WP.hw[0] = d_in[16]; WP.hw[1] = d_in[24]; WP.hw[2] = d_in[32]; WP.hw[3] = d_in[40];
    kPrepW<<<5760, 256, 0, stream>>>(WP, flag, ws + WS_W1T, wb16, whb);

    Segs SG; int si = 0;
    auto add = [&](const void* s, int n, int dst) {
        SG.s[si].src = s; SG.s[si].n = n; SG.s[si].dst = dst; ++si;
    };
    add(d_in[1], 96, PB_CAL); add(d_in[2], 32, PB_CRN); add(d_in[3], 9, PB_MSZ);
    const int ocb[3] = {3, 2, 2};
    for (int b = 0; b < 3; ++b) {
        int base = PB_BR0 + b * 1040;
        int i0 = 4 + 4 * b;
        add(d_in[i0 + 1], 256, base);
        add(d_in[i0 + 2], ocb[b] * 256, base + 256);
        add(d_in[i0 + 3], ocb[b], base + 256 + ocb[b] * 256);
    }
    const int och[4] = {2, 2, 4, 24};
    for (int h = 0; h < 4; ++h) {
        int base = PB_HD0 + h * 7456;
        int i0 = 16 + 8 * h;
        add(d_in[i0 + 1], 256, base);
        add(d_in[i0 + 2], 256, base + 256);
        add(d_in[i0 + 3], 256, base + 512);
        add(d_in[i0 + 4], 256, base + 768);
        add(d_in[i0 + 5], 256, base + 1024);
        add(d_in[i0 + 6], och[h] * 256, base + 1280);
        add(d_in[i0 + 7], och[h], base + 1280 + och[h] * 256);
    }
    kPrepP<<<si, 256, 0, stream>>>(SG, flag, par);

    // merged MFMA branches (one dispatch, barrier-free K-loop)
    kBranch3<<<dim3(5, 48, 24), 512, 0, stream>>>(
        feat, flag, wb16, par + PB_BR0, d_out, ws);

    // exact f32 strip for NMS/topk decision region (rows 0..4 of heat)
    kBranchX<<<dim3(5, 5, 8), 256, 0, stream>>>(
        feat, flag, ws + WS_W1T, par + PB_BR0, d_out, O_HEAT, ws + WS_HEAT);

    kNms<<<2880, 256, 0, stream>>>(ws + WS_HEAT, ws + WS_NH);
    kTopA<<<dim3(24, NCHUNK), 256, 0, stream>>>(ws + WS_NH);
    kTopB<<<24, 64, 0, stream>>>(ws + WS_NH, ws + WS_S1S, (int*)(ws + WS_S1I));
    kTop2<<<8, 64, 0, stream>>>(ws + WS_S1S, (int*)(ws + WS_S1I), ws + WS_OFF2,
                                ws + WS_SIZ2, ws + WS_BOX, (int*)(ws + WS_CLS));
    kRoi<<<400, 256, 0, stream>>>(feat, flag, ws + WS_BOX, (int*)(ws + WS_CLS),
                                  par, ws + WS_ROI);
    kHeadM<<<dim3(4, NROI), 256, 0, stream>>>(ws + WS_ROI, whb, par, ws + WS_HOUT);
    kFinal<<<2, 256, 0, stream>>>(ws + WS_HOUT, ws + WS_BOX, (int*)(ws + WS_CLS),
                                  par, d_out, flag);
}

// Round 9
// 975.500 us; speedup vs baseline: 1.4160x; 1.3741x over previous
//
#include <hip/hip_runtime.h>
#include <math.h>

typedef unsigned short u16;
typedef unsigned int   u32;
typedef unsigned long long u64;
typedef __attribute__((ext_vector_type(8))) short short8;   // 8 bf16 (4 VGPR)
typedef __attribute__((ext_vector_type(4))) float f32x4;    // MFMA acc

// ---------- dtype helpers ----------
__device__ __forceinline__ float b2f(u16 v) { return __uint_as_float(((u32)v) << 16); }
__device__ __forceinline__ u16 f2b(float f) {
    u32 u = __float_as_uint(f);
    u32 r = (u + 0x7FFFu + ((u >> 16) & 1u)) >> 16;   // RNE
    return (u16)r;
}
__device__ __forceinline__ float gload(const void* p, long i, int bf) {
    return bf ? b2f(((const u16*)p)[i]) : ((const float*)p)[i];
}
__device__ __forceinline__ void gstore(void* p, long i, float v, int bf) {
    if (bf) ((u16*)p)[i] = f2b(v);
    else    ((float*)p)[i] = v;
}

// top-k key: smallest key = (largest value, then smallest index)
__device__ __forceinline__ u64 packKey(float v, int idx) {
    u32 u = __float_as_uint(v);
    u32 m = (u & 0x80000000u) ? ~u : (u | 0x80000000u);   // monotone float->uint
    return ((u64)(~m) << 32) | (u32)idx;
}

// ---------- problem constants ----------
#define BATCH 8
#define CIN   64
#define FH    96
#define FW    320
#define KDET  50
#define NROI  400
#define CROI  69
#define HW    (FH*FW)
#define CHUNK 1920
#define NCHUNK 16

// ---------- workspace layout (float offsets) ----------
#define WS_HEAT 0L
#define WS_OFF2 737280L
#define WS_SIZ2 1228800L
#define WS_NH   1720320L
#define WS_S1S  2457600L
#define WS_S1I  2458800L
#define WS_CLS  2460000L
#define WS_BOX  2460400L
#define WS_ROI  2462400L
#define WS_HOUT 3814800L
#define WS_W1T  3827600L     // 147456 f32: hm conv1 [k=576][c=256] (exact strip)
#define WS_WB16 3975056L     // u16: 3 branches * [9][2][256][32] bf16 (lane-coalesced)
#define WS_W1H  4269968L     // u16: 4 heads * [9][3][256][32] bf16
#define WS_PAR  4905872L     // packed f32 params
#define WS_FLAG 4938960L     // int dtype flag

// param block sub-offsets
#define PB_CAL 0
#define PB_CRN 96
#define PB_MSZ 128
#define PB_BR0 144          // stride 1040: b1@0, w2@256 ([k][n]), b2@256+OC*256
#define PB_HD0 3264         // stride 7456

// ---------- output layout (element offsets) ----------
#define O_HEAT 0L
#define O_OFF2 737280L
#define O_SIZ2 1228800L
#define O_HEAD 1720320L
#define O_DEP  1729920L
#define O_OFF3 1730720L
#define O_S3D  1731520L
#define O_H3D  1732720L

// =====================================================================
// dtype detection
// =====================================================================
__global__ void kDetect(const void* __restrict__ feat, int* __restrict__ flag) {
    __shared__ int cnt;
    if (threadIdx.x == 0) cnt = 0;
    __syncthreads();
    u16 v = ((const u16*)feat)[threadIdx.x];     // 512 threads
    float f = b2f(v);
    u32 e = (v >> 7) & 0xFF;
    float a = fabsf(f);
    int sane = (e != 0xFF) && (f == 0.f || (a >= 1e-8f && a <= 1e4f));
    atomicAdd(&cnt, sane);
    __syncthreads();
    if (threadIdx.x == 0) *flag = (cnt >= 480) ? 1 : 0;
}

// =====================================================================
// Prep: weights
//  region 1: hm conv1 f32 [k=576][c=256]              (exact strip)
//  region 2: 3 branches bf16 [tap][s][n=256][32]      (direct B-frag loads)
//  region 3: 4 heads bf16 [tap][cs=3][oc=256][32]     (direct B-frag loads)
// =====================================================================
struct WPtrs { const void* bw[3]; const void* hw[4]; };

__global__ void kPrepW(WPtrs P, const int* __restrict__ flag,
                       float* __restrict__ w1t, u16* __restrict__ wb16,
                       u16* __restrict__ whb) {
    const int bf = *flag;
    int idx = blockIdx.x * 256 + threadIdx.x;
    if (idx < 147456) {
        int k = idx >> 8, c = idx & 255;
        w1t[idx] = gload(P.bw[0], (long)c * 576 + k, bf);
    } else if (idx < 589824) {
        int j = idx - 147456;
        int br = j / 147456, rem = j % 147456;
        int tap = rem / 16384;
        int r2 = rem & 16383;
        int s = r2 >> 13;
        int n = (r2 >> 5) & 255;
        int c5 = r2 & 31;
        int ci = s * 32 + c5;
        wb16[j] = f2b(gload(P.bw[br], (long)n * 576 + ci * 9 + tap, bf));
    } else {
        int j = idx - 589824;               // < 884736
        int h = j / 221184, rem = j % 221184;
        int tap = rem / 24576, rem2 = rem % 24576;
        int cs = rem2 / 8192, rem3 = rem2 % 8192;
        int oc = rem3 >> 5, jj = rem3 & 31;
        int ci = cs * 32 + jj;
        u16 val = 0;
        if (ci < CROI) val = f2b(gload(P.hw[h], (long)oc * 621 + ci * 9 + tap, bf));
        whb[j] = val;
    }
}

// Prep: pack all small params to f32
struct Seg { const void* src; int n; int dst; };
struct Segs { Seg s[40]; };

__global__ void kPrepP(Segs S, const int* __restrict__ flag, float* __restrict__ par) {
    const int bf = *flag;
    Seg sg = S.s[blockIdx.x];
    for (int i = threadIdx.x; i < sg.n; i += 256)
        par[sg.dst + i] = gload(sg.src, i, bf);
}

// =====================================================================
// Merged MFMA branch conv: all 3 branches, 512 thr, M=128 (2 rows x 64 x)
// conv3x3(64->256) as 9 shifted GEMMs + b1 + ReLU + 1x1(->oc) + b2
// grid (5, 48, 24); z = br*8 + b. Wave owns 32 n; 8 M-tiles x 2 N-tiles.
// B-fragments load DIRECTLY from global (per-wave slices, coalesced 16B);
// K-loop barrier-free; tap loop pinned to unroll 1 (reg-budget discipline).
// =====================================================================
union B3U {
    u16   a[4][68][72];       // input rows y0-1..y0+2, x0-1..x0+64, 64ci (pad 72)
    float red[8][128][3];     // 1x1 partials per wave
};

__global__ __launch_bounds__(512, 4)
void kBranch3(const void* __restrict__ feat, const int* __restrict__ flag,
              const u16* __restrict__ wbAll,   // 3 * [9][2][256][32] bf16
              const float* __restrict__ bpAll, // par + PB_BR0, stride 1040
              void* __restrict__ outb, float* __restrict__ wsbase) {
    __shared__ __align__(16) B3U u;

    const long obase[3] = {O_HEAT, O_OFF2, O_SIZ2};
    const long wfs[3]   = {WS_HEAT, WS_OFF2, WS_SIZ2};

    const int bfl = *flag;
    const int tid = threadIdx.x;
    const int wave = tid >> 6, lane = tid & 63;
    const int q = lane >> 4, n15 = lane & 15;
    const int x0 = blockIdx.x * 64, y0 = blockIdx.y * 2;
    const int br = blockIdx.z >> 3, b = blockIdx.z & 7;
    const int oc = (br == 0) ? 3 : 2;
    const u16* wpt = wbAll + br * 147456;
    const float* bp = bpAll + br * 1040;

    // ---- stage input tile: rows y0-1..y0+2, x0-1..x0+64, 64 ci ----
    if (tid < 256) {
        const int ci = tid & 63, rr = tid >> 6;
        const int gy = y0 - 1 + rr;
        if (gy < 0 || gy >= FH) {
            for (int xi = 0; xi < 66; ++xi) u.a[rr][xi][ci] = 0;
        } else if (bfl) {
            const u16* rp = (const u16*)feat + ((long)((b << 6) | ci) * FH + gy) * FW;
            for (int j = 0; j < 10; ++j) {
                int xs0 = x0 - 8 + j * 8;
                u16 tmp[8];
                if (xs0 >= 0 && xs0 <= FW - 8)
                    *(uint4*)tmp = *(const uint4*)(rp + xs0);
                else
                    for (int e = 0; e < 8; ++e) {
                        int gx = xs0 + e;
                        tmp[e] = (gx >= 0 && gx < FW) ? rp[gx] : (u16)0;
                    }
                for (int e = 0; e < 8; ++e) {
                    int xi = xs0 + e - x0 + 1;
                    if (xi >= 0 && xi < 66) u.a[rr][xi][ci] = tmp[e];
                }
            }
        } else {
            const float* rp = (const float*)feat + ((long)((b << 6) | ci) * FH + gy) * FW;
            for (int j = 0; j < 18; ++j) {
                int xs0 = x0 - 4 + j * 4;
                float tmp[4];
                if (xs0 >= 0 && xs0 <= FW - 4)
                    *(float4*)tmp = *(const float4*)(rp + xs0);
                else
                    for (int e = 0; e < 4; ++e) {
                        int gx = xs0 + e;
                        tmp[e] = (gx >= 0 && gx < FW) ? rp[gx] : 0.f;
                    }
                for (int e = 0; e < 4; ++e) {
                    int xi = xs0 + e - x0 + 1;
                    if (xi >= 0 && xi < 66) u.a[rr][xi][ci] = f2b(tmp[e]);
                }
            }
        }
    }
    __syncthreads();   // a_lds visible to all waves; no more barriers in K-loop

    f32x4 acc[8][2];
#pragma unroll
    for (int i = 0; i < 8; ++i)
#pragma unroll
        for (int t = 0; t < 2; ++t) acc[i][t] = (f32x4){0.f, 0.f, 0.f, 0.f};

    // ---- K-loop: 9 taps x 2 k-steps (32 ci each), barrier-free ----
#pragma unroll 1
    for (int tap = 0; tap < 9; ++tap) {
        const int ky = tap / 3, kx = tap % 3;
#pragma unroll
        for (int s = 0; s < 2; ++s) {
            const u16* wks = wpt + (tap * 2 + s) * 8192;
            short8 bfr[2];
#pragma unroll
            for (int t = 0; t < 2; ++t)
                bfr[t] = *(const short8*)(wks + (wave * 32 + t * 16 + n15) * 32 + q * 8);
#pragma unroll
            for (int ig = 0; ig < 2; ++ig) {
                short8 afr[4];
#pragma unroll
                for (int i = 0; i < 4; ++i) {
                    int it = ig * 4 + i;
                    int r = it >> 2, xb = (it & 3) * 16;
                    afr[i] = *(const short8*)&u.a[r + ky][xb + n15 + kx][s * 32 + q * 8];
                }
#pragma unroll
                for (int i = 0; i < 4; ++i)
#pragma unroll
                    for (int t = 0; t < 2; ++t)
                        acc[ig * 4 + i][t] = __builtin_amdgcn_mfma_f32_16x16x32_bf16(
                            afr[i], bfr[t], acc[ig * 4 + i][t], 0, 0, 0);
            }
        }
    }

    // ---- epilogue: b1 + relu + 1x1 partials ----
    float b1v[2], w2v[3][2];
#pragma unroll
    for (int t = 0; t < 2; ++t) {
        int n = wave * 32 + t * 16 + n15;
        b1v[t] = bp[n];
#pragma unroll
        for (int k = 0; k < 3; ++k) w2v[k][t] = bp[256 + k * 256 + n];
    }
    __syncthreads();   // done reading u.a; reuse as red
#pragma unroll
    for (int i = 0; i < 8; ++i) {
#pragma unroll
        for (int r = 0; r < 4; ++r) {
            float pk[3];
#pragma unroll
            for (int k = 0; k < 3; ++k) pk[k] = 0.f;
#pragma unroll
            for (int t = 0; t < 2; ++t) {
                float h = fmaxf(acc[i][t][r] + b1v[t], 0.f);
#pragma unroll
                for (int k = 0; k < 3; ++k) pk[k] = fmaf(h, w2v[k][t], pk[k]);
            }
#pragma unroll
            for (int k = 0; k < 3; ++k) {
                pk[k] += __shfl_xor(pk[k], 1);
                pk[k] += __shfl_xor(pk[k], 2);
                pk[k] += __shfl_xor(pk[k], 4);
                pk[k] += __shfl_xor(pk[k], 8);
            }
            if (n15 == 0) {
                int m = i * 16 + q * 4 + r;
#pragma unroll
                for (int k = 0; k < 3; ++k) u.red[wave][m][k] = pk[k];
            }
        }
    }
    __syncthreads();
    float* outf = wsbase + wfs[br];
    for (int t2 = tid; t2 < oc * 128; t2 += 512) {
        int k = t2 >> 7, m = t2 & 127;
        int row = m >> 6, x = m & 63;
        float s = bp[256 + oc * 256 + k];
#pragma unroll
        for (int w = 0; w < 8; ++w) s += u.red[w][m][k];
        long o = (((long)b * oc + k) * FH + (y0 + row)) * FW + x0 + x;
        gstore(outb, obase[br] + o, s, bfl);
        outf[o] = s;
    }
}

// =====================================================================
// Exact f32 strip (rows 0..4 of heat): NMS/topk decisions bit-match f32
// =====================================================================
union BrLds {
    float w[36 * 256];
    float part[32 * 3 * 64];
};

__global__ __launch_bounds__(256)
void kBranchX(const void* __restrict__ feat, const int* __restrict__ flag,
              const float* __restrict__ w1t, const float* __restrict__ bp,
              void* __restrict__ outb, long obase, float* __restrict__ outf) {
    __shared__ float in_lds[4][3][68];
    __shared__ BrLds u;
    const int bf = *flag;
    const int OC = 3;

    const int tid = threadIdx.x;
    const int xg = tid & 7, cg = tid >> 3;
    const int x0 = blockIdx.x * 64, y = blockIdx.y, b = blockIdx.z;
    const int c0 = cg * 8;

    float acc[8][8];
#pragma unroll
    for (int i = 0; i < 8; ++i)
#pragma unroll
        for (int j = 0; j < 8; ++j) acc[i][j] = 0.f;

    for (int chunk = 0; chunk < 16; ++chunk) {
        const int ci0 = chunk * 4;
        __syncthreads();
        for (int i = tid; i < 4 * 3 * 68; i += 256) {
            int xx = i % 68, t2 = i / 68;
            int r = t2 % 3, ci = t2 / 3;
            int gx = x0 - 1 + xx, gy = y - 1 + r;
            float v = 0.f;
            if (gx >= 0 && gx < FW && gy >= 0 && gy < FH)
                v = gload(feat, ((long)(b * CIN + ci0 + ci) * FH + gy) * FW + gx, bf);
            in_lds[ci][r][xx] = v;
        }
        {
            const float4* src = (const float4*)(w1t + (long)ci0 * 9 * 256);
            float4* dst = (float4*)u.w;
            for (int i = tid; i < 36 * 256 / 4; i += 256) dst[i] = src[i];
        }
        __syncthreads();
#pragma unroll
        for (int ci = 0; ci < 4; ++ci) {
#pragma unroll
            for (int ky = 0; ky < 3; ++ky) {
                const float* rowp = &in_lds[ci][ky][xg * 8];
                float inv[10];
                *(float4*)&inv[0] = *(const float4*)&rowp[0];
                *(float4*)&inv[4] = *(const float4*)&rowp[4];
                *(float2*)&inv[8] = *(const float2*)&rowp[8];
#pragma unroll
                for (int kx = 0; kx < 3; ++kx) {
                    const float* wp = &u.w[(ci * 9 + ky * 3 + kx) * 256 + c0];
                    float wv[8];
                    *(float4*)&wv[0] = *(const float4*)&wp[0];
                    *(float4*)&wv[4] = *(const float4*)&wp[4];
#pragma unroll
                    for (int cc = 0; cc < 8; ++cc)
#pragma unroll
                        for (int xx = 0; xx < 8; ++xx)
                            acc[cc][xx] = fmaf(wv[cc], inv[xx + kx], acc[cc][xx]);
                }
            }
        }
    }

#pragma unroll
    for (int cc = 0; cc < 8; ++cc) {
        float b1v = bp[c0 + cc];
#pragma unroll
        for (int xx = 0; xx < 8; ++xx)
            acc[cc][xx] = fmaxf(acc[cc][xx] + b1v, 0.f);
    }

    __syncthreads();
#pragma unroll
    for (int k = 0; k < OC; ++k) {
        float p[8];
#pragma unroll
        for (int xx = 0; xx < 8; ++xx) p[xx] = 0.f;
#pragma unroll
        for (int cc = 0; cc < 8; ++cc) {
            float wv = bp[256 + k * 256 + c0 + cc];
#pragma unroll
            for (int xx = 0; xx < 8; ++xx) p[xx] = fmaf(acc[cc][xx], wv, p[xx]);
        }
#pragma unroll
        for (int xx = 0; xx < 8; ++xx)
            u.part[(cg * OC + k) * 64 + xg * 8 + xx] = p[xx];
    }
    __syncthreads();
    for (int t = tid; t < OC * 64; t += 256) {
        int k = t >> 6, xx = t & 63;
        float s = bp[256 + OC * 256 + k];
#pragma unroll 8
        for (int g = 0; g < 32; ++g) s += u.part[(g * OC + k) * 64 + xx];
        long o = (((long)b * OC + k) * FH + y) * FW + x0 + xx;
        gstore(outb, obase + o, s, bf);
        outf[o] = s;
    }
}

// =====================================================================
// NMS
// =====================================================================
__global__ void kNms(const float* __restrict__ heat, float* __restrict__ nh) {
    int idx = blockIdx.x * 256 + threadIdx.x;
    if (idx >= 737280) return;
    int x = idx % FW, t = idx / FW;
    int yy = t % FH, bc = t / FH;
    const float* p = heat + (long)bc * HW;
    float v = p[yy * FW + x];
    float m = v;
    for (int dy = -1; dy <= 1; ++dy) {
        int ny = yy + dy;
        if (ny < 0 || ny >= FH) continue;
        for (int dx = -1; dx <= 1; ++dx) {
            int nx = x + dx;
            if (nx < 0 || nx >= FW) continue;
            m = fmaxf(m, p[ny * FW + nx]);
        }
    }
    nh[idx] = (v == m) ? v : 0.f;
}

// =====================================================================
// top-k stage A: per (bc, chunk) local top-50 via single-wave extraction.
// =====================================================================
__global__ __launch_bounds__(256)
void kTopA(float* __restrict__ nh) {
    __shared__ u64 keys[CHUNK];
    const int bc = blockIdx.x, ch = blockIdx.y;
    const int tid = threadIdx.x;
    const long base = (long)bc * HW + (long)ch * CHUNK;
    for (int i = tid; i < CHUNK; i += 256)
        keys[i] = packKey(nh[base + i], ch * CHUNK + i);
    __syncthreads();
    if (tid < 64) {
        const int lane = tid;
        u64* outp = (u64*)(nh + base);
        for (int it = 0; it < KDET; ++it) {
            u64 bk = ~0ULL; int bp = 0;
            for (int i = lane; i < CHUNK; i += 64) {
                u64 k = keys[i];
                if (k < bk) { bk = k; bp = i; }
            }
#pragma unroll
            for (int s = 32; s > 0; s >>= 1) {
                u64 k2 = __shfl_down(bk, s);
                int p2 = __shfl_down(bp, s);
                if (k2 < bk) { bk = k2; bp = p2; }
            }
            bk = __shfl(bk, 0);
            bp = __shfl(bp, 0);
            if (lane == 0) {
                outp[it] = bk;
                keys[bp] = ~0ULL;
            }
        }
    }
}

// =====================================================================
// top-k stage B: merge 16x50 chunk keys -> sorted per-(b,c) top-50
// =====================================================================
__global__ __launch_bounds__(64)
void kTopB(const float* __restrict__ nh, float* __restrict__ s1s,
           int* __restrict__ s1i) {
    __shared__ u64 keys[NCHUNK * KDET];
    const int bc = blockIdx.x, lane = threadIdx.x;
    for (int ch = 0; ch < NCHUNK; ++ch) {
        const u64* src = (const u64*)(nh + (long)bc * HW + (long)ch * CHUNK);
        if (lane < KDET) keys[ch * KDET + lane] = src[lane];
    }
    __syncthreads();
    for (int it = 0; it < KDET; ++it) {
        u64 bk = ~0ULL; int bp = 0;
        for (int i = lane; i < NCHUNK * KDET; i += 64) {
            u64 k = keys[i];
            if (k < bk) { bk = k; bp = i; }
        }
#pragma unroll
        for (int s = 32; s > 0; s >>= 1) {
            u64 k2 = __shfl_down(bk, s);
            int p2 = __shfl_down(bp, s);
            if (k2 < bk) { bk = k2; bp = p2; }
        }
        bk = __shfl(bk, 0);
        bp = __shfl(bp, 0);
        if (lane == 0) {
            u32 hm = ~(u32)(bk >> 32);
            u32 u = (hm & 0x80000000u) ? (hm & 0x7fffffffu) : ~hm;
            s1s[bc * KDET + it] = __uint_as_float(u);
            s1i[bc * KDET + it] = (int)(bk & 0xFFFFFFFFu);
            keys[bp] = ~0ULL;
        }
    }
}

// =====================================================================
// top-50 stage 2 + boxes
// =====================================================================
__global__ void kTop2(const float* __restrict__ s1s, const int* __restrict__ s1i,
                      const float* __restrict__ off2, const float* __restrict__ siz2,
                      float* __restrict__ boxes, int* __restrict__ clsArr) {
    const int b = blockIdx.x, t = threadIdx.x;    // 64 threads
    __shared__ float sc[150];
    for (int i = t; i < 150; i += 64) sc[i] = s1s[b * 150 + i];
    __syncthreads();
    for (int r = 0; r < KDET; ++r) {
        float bv = -INFINITY; int bp = 0x7fffffff;
        for (int i = t; i < 150; i += 64) {
            float v = sc[i];
            if (v > bv) { bv = v; bp = i; }
        }
        for (int s = 32; s > 0; s >>= 1) {
            float v2 = __shfl_down(bv, s);
            int   p2 = __shfl_down(bp, s);
            if (v2 > bv || (v2 == bv && p2 < bp)) { bv = v2; bp = p2; }
        }
        if (t == 0) {
            int cls = bp / KDET;
            int ind = s1i[b * 150 + bp];
            int n = b * KDET + r;
            clsArr[n] = cls;
            int x = ind % FW, yy = ind / FW;
            float cx = (float)x  + off2[(((long)b * 2 + 0) * FH + yy) * FW + x];
            float cy = (float)yy + off2[(((long)b * 2 + 1) * FH + yy) * FW + x];
            float w  = siz2[(((long)b * 2 + 0) * FH + yy) * FW + x];
            float h  = siz2[(((long)b * 2 + 1) * FH + yy) * FW + x];
            boxes[n * 5 + 0] = (float)b;
            boxes[n * 5 + 1] = cx - w * 0.5f;
            boxes[n * 5 + 2] = cy - h * 0.5f;
            boxes[n * 5 + 3] = cx + w * 0.5f;
            boxes[n * 5 + 4] = cy + h * 0.5f;
            sc[bp] = -INFINITY;
        }
        __syncthreads();
    }
}

// =====================================================================
// ROI align 7x7 (sr=2) + coord maps + one-hot -> roi_in f32
// =====================================================================
__global__ __launch_bounds__(256)
void kRoi(const void* __restrict__ feat, const int* __restrict__ flag,
          const float* __restrict__ boxes, const int* __restrict__ clsArr,
          const float* __restrict__ par, float* __restrict__ roi_in) {
    const int n = blockIdx.x, tid = threadIdx.x;
    const int bf = *flag;
    __shared__ int   x0s[14], x1s[14], y0s[14], y1s[14], vxs[14], vys[14];
    __shared__ float lxs[14], lys[14], cxs[7], cys[7];

    const float bx1 = boxes[n * 5 + 1], by1 = boxes[n * 5 + 2];
    const float bx2 = boxes[n * 5 + 3], by2 = boxes[n * 5 + 4];
    const int b = (int)boxes[n * 5 + 0];

    if (tid < 14) {
        float roi_w = fmaxf(bx2 - bx1, 1.f);
        float X = bx1 + (roi_w / 7.f) * ((tid + 0.5f) * 0.5f);
        vxs[tid] = (X > -1.f) && (X < (float)FW);
        float Xc = fminf(fmaxf(X, 0.f), (float)(FW - 1));
        int xi = (int)floorf(Xc);
        x0s[tid] = xi; x1s[tid] = min(xi + 1, FW - 1); lxs[tid] = Xc - (float)xi;
    } else if (tid >= 16 && tid < 30) {
        int i = tid - 16;
        float roi_h = fmaxf(by2 - by1, 1.f);
        float Y = by1 + (roi_h / 7.f) * ((i + 0.5f) * 0.5f);
        vys[i] = (Y > -1.f) && (Y < (float)FH);
        float Yc = fminf(fmaxf(Y, 0.f), (float)(FH - 1));
        int yi = (int)floorf(Yc);
        y0s[i] = yi; y1s[i] = min(yi + 1, FH - 1); lys[i] = Yc - (float)yi;
    } else if (tid >= 32 && tid < 46) {
        int j = tid - 32;
        const float* cal = par + PB_CAL + b * 12;
        float f_u = cal[0], c_u = cal[2], t03 = cal[3];
        float f_v = cal[5], c_v = cal[6], t13 = cal[7];
        float bxc = t03 / (-f_u), byc = t13 / (-f_v);
        const float* cr = par + PB_CRN + b * 4;
        float crx0 = cr[0], cry0 = cr[1], crx1 = cr[2], cry1 = cr[3];
        float sx = crx1 - crx0, sy = cry1 - cry0;
        float u1 = bx1 / (float)FW * sx + crx0, v1 = by1 / (float)FH * sy + cry0;
        float u2 = bx2 / (float)FW * sx + crx0, v2 = by2 / (float)FH * sy + cry0;
        float p1x = (u1 - c_u) / f_u + bxc, p1y = (v1 - c_v) / f_v + byc;
        float p2x = (u2 - c_u) / f_u + bxc, p2y = (v2 - c_v) / f_v + byc;
        if (j < 7) cxs[j] = p1x + ((float)j / 6.f) * (p2x - p1x);
        else       cys[j - 7] = p1y + ((float)(j - 7) / 6.f) * (p2y - p1y);
    }
    __syncthreads();

    for (int t = tid; t < CIN * 49; t += 256) {
        int c = t / 49, p = t % 49, oy = p / 7, ox = p % 7;
        long fb = ((long)b * CIN + c) * HW;
        float acc = 0.f;
#pragma unroll
        for (int dy = 0; dy < 2; ++dy) {
            int sy = oy * 2 + dy;
            float ly = lys[sy]; int yA = y0s[sy], yB = y1s[sy], vy = vys[sy];
#pragma unroll
            for (int dx = 0; dx < 2; ++dx) {
                int sx = ox * 2 + dx;
                float lx = lxs[sx]; int xA = x0s[sx], xB = x1s[sx];
                float v = (1.f - ly) * (1.f - lx) * gload(feat, fb + yA * FW + xA, bf)
                        + (1.f - ly) * lx         * gload(feat, fb + yA * FW + xB, bf)
                        + ly * (1.f - lx)         * gload(feat, fb + yB * FW + xA, bf)
                        + ly * lx                 * gload(feat, fb + yB * FW + xB, bf);
                if (!(vy && vxs[sx])) v = 0.f;
                acc += v;
            }
        }
        roi_in[((long)n * CROI + c) * 49 + p] = acc * 0.25f;
    }
    int cls = clsArr[n];
    for (int t = tid; t < 5 * 49; t += 256) {
        int ch = t / 49, p = t % 49, i = p / 7, j = p % 7;
        float v;
        if (ch == 0)      v = cxs[j];
        else if (ch == 1) v = cys[i];
        else              v = (cls == ch - 2) ? 1.f : 0.f;
        roi_in[((long)n * CROI + 64 + ch) * 49 + p] = v;
    }
}

// =====================================================================
// MFMA ROI head: conv3x3(69->256,pad1) as 9 taps x 3 k-steps GEMM
// B-frags load directly from global; K-loop barrier-free; tap loop unroll 1.
// =====================================================================
__global__ __launch_bounds__(256, 4)
void kHeadM(const float* __restrict__ roi_in, const u16* __restrict__ whb,
            const float* __restrict__ par, float* __restrict__ head_out) {
    const int h = blockIdx.x, n = blockIdx.y, tid = threadIdx.x;
    const int wave = tid >> 6, lane = tid & 63;
    const int q = lane >> 4, n15 = lane & 15;
    const int ocArr[4] = {2, 2, 4, 24};
    const int offArr[4] = {0, 2, 4, 8};
    __shared__ __align__(16) u16 r_lds[9][9][104];   // padded roi, ci-contig
    __shared__ float means[256];

    for (int i = tid; i < 9 * 9 * 104 / 8; i += 256)
        ((uint4*)r_lds)[i] = (uint4){0, 0, 0, 0};
    __syncthreads();
    const float* rp = roi_in + (long)n * CROI * 49;
    for (int i = tid; i < CROI * 49; i += 256) {
        int c = i / 49, p = i % 49;
        r_lds[p / 7 + 1][p % 7 + 1][c] = f2b(rp[i]);
    }
    __syncthreads();

    int oyA[4], oxA[4];
#pragma unroll
    for (int i = 0; i < 4; ++i) {
        int pos = i * 16 + n15; if (pos > 48) pos = 48;
        oyA[i] = pos / 7; oxA[i] = pos % 7;
    }

    f32x4 acc[4][4];
#pragma unroll
    for (int i = 0; i < 4; ++i)
#pragma unroll
        for (int t = 0; t < 4; ++t) acc[i][t] = (f32x4){0.f, 0.f, 0.f, 0.f};

#pragma unroll 1
    for (int tap = 0; tap < 9; ++tap) {
        const int ky = tap / 3, kx = tap % 3;
        const u16* wt = whb + ((long)h * 9 + tap) * 24576;   // [3][256][32]
#pragma unroll
        for (int cs = 0; cs < 3; ++cs) {
            short8 afr[4], bfr[4];
#pragma unroll
            for (int i = 0; i < 4; ++i)
                afr[i] = *(const short8*)&r_lds[oyA[i] + ky][oxA[i] + kx][cs * 32 + q * 8];
#pragma unroll
            for (int t = 0; t < 4; ++t)
                bfr[t] = *(const short8*)(wt + ((cs << 8) + wave * 64 + t * 16 + n15) * 32 + q * 8);
#pragma unroll
            for (int i = 0; i < 4; ++i)
#pragma unroll
                for (int t = 0; t < 4; ++t)
                    acc[i][t] = __builtin_amdgcn_mfma_f32_16x16x32_bf16(
                        afr[i], bfr[t], acc[i][t], 0, 0, 0);
        }
    }

    const float* hb = par + PB_HD0 + h * 7456;
#pragma unroll
    for (int t = 0; t < 4; ++t) {
        int oc = wave * 64 + t * 16 + n15;
        float b1 = hb[oc], g = hb[256 + oc], be = hb[512 + oc];
        float m = hb[768 + oc], v = hb[1024 + oc];
        float scale = g / sqrtf(v + 1e-5f);
        float s = 0.f;
#pragma unroll
        for (int i = 0; i < 4; ++i)
#pragma unroll
            for (int r = 0; r < 4; ++r) {
                int pos = i * 16 + q * 4 + r;
                if (pos < 49)
                    s += fmaxf((acc[i][t][r] + b1 - m) * scale + be, 0.f);
            }
        s += __shfl_xor(s, 16);
        s += __shfl_xor(s, 32);
        if (q == 0) means[oc] = s / 49.f;
    }
    __syncthreads();

    int oc_out = ocArr[h];
    const float* w2 = hb + 1280;
    for (int k = wave; k < oc_out; k += 4) {
        float s = 0.f;
        for (int c = lane; c < 256; c += 64) s += means[c] * w2[k * 256 + c];
#pragma unroll
        for (int off = 32; off > 0; off >>= 1) s += __shfl_down(s, off);
        if (lane == 0)
            head_out[(long)n * 32 + offArr[h] + k] = s + w2[oc_out * 256 + k];
    }
}

// =====================================================================
// Final scalar math + small outputs
// =====================================================================
__global__ void kFinal(const float* __restrict__ head_out, const float* __restrict__ boxes,
                       const int* __restrict__ clsArr, const float* __restrict__ par,
                       void* __restrict__ out, const int* __restrict__ flag) {
    int n = blockIdx.x * 256 + threadIdx.x;
    if (n >= NROI) return;
    const int bf = *flag;
    const float* ho = head_out + (long)n * 32;
    float dep0 = ho[0], dep1 = ho[1];
    int b = (int)boxes[n * 5 + 0];
    int cls = clsArr[n];

    for (int j = 0; j < 24; ++j) gstore(out, O_HEAD + n * 24 + j, ho[8 + j], bf);
    gstore(out, O_OFF3 + n * 2 + 0, ho[2], bf);
    gstore(out, O_OFF3 + n * 2 + 1, ho[3], bf);
    gstore(out, O_S3D + n * 3 + 0, ho[4], bf);
    gstore(out, O_S3D + n * 3 + 1, ho[5], bf);
    gstore(out, O_S3D + n * 3 + 2, ho[6], bf);
    gstore(out, O_H3D + n, ho[7], bf);

    float cry0 = par[PB_CRN + b * 4 + 1], cry1 = par[PB_CRN + b * 4 + 3];
    float sy = cry1 - cry0;
    float bi2 = boxes[n * 5 + 2] / (float)FH * sy + cry0;
    float bi4 = boxes[n * 5 + 4] / (float)FH * sy + cry0;
    float box_h = fmaxf(bi4 - bi2, 1.f);
    float f_u = par[PB_CAL + b * 12 + 0];
    float size3d0 = par[PB_MSZ + cls * 3 + 0] + ho[4];
    float depth_geo = size3d0 / box_h * f_u;
    float sig = 1.f / (1.f + expf(-dep0));
    float d0 = 1.f / (sig + 1e-6f) - 1.f + depth_geo;
    float dgls = ho[7] + 2.f * (logf(f_u) - logf(box_h));
    float mx = fmaxf(dep1, dgls);
    float lse = mx + logf(expf(dep1 - mx) + expf(dgls - mx));
    gstore(out, O_DEP + n * 2 + 0, d0, bf);
    gstore(out, O_DEP + n * 2 + 1, lse, bf);
}

// =====================================================================
extern "C" void kernel_launch(void* const* d_in, const int* in_sizes, int n_in,
                              void* d_out, int out_size, void* d_ws, size_t ws_size,
                              hipStream_t stream) {
    (void)in_sizes; (void)n_in; (void)out_size; (void)ws_size;
    float* ws = (float*)d_ws;
    float* par = ws + WS_PAR;
    int* flag = (int*)(ws + WS_FLAG);
    u16* wb16 = (u16*)(ws + WS_WB16);
    u16* whb  = (u16*)(ws + WS_W1H);
    const void* feat = d_in[0];

    kDetect<<<1, 512, 0, stream>>>(feat, flag);

    WPtrs WP;
    WP.bw[0] = d_in[4]; WP.bw[1] = d_in[8]; WP.bw[2] = d_in[12];
    WP.hw[0] = d_in[16]; WP.hw[1] = d_in[24]; WP.hw[2] = d_in[32]; WP.hw[3] = d_in[40];
    kPrepW<<<5760, 256, 0, stream>>>(WP, flag, ws + WS_W1T, wb16, whb);

    Segs SG; int si = 0;
    auto add = [&](const void* s, int n, int dst) {
        SG.s[si].src = s; SG.s[si].n = n; SG.s[si].dst = dst; ++si;
    };
    add(d_in[1], 96, PB_CAL); add(d_in[2], 32, PB_CRN); add(d_in[3], 9, PB_MSZ);
    const int ocb[3] = {3, 2, 2};
    for (int b = 0; b < 3; ++b) {
        int base = PB_BR0 + b * 1040;
        int i0 = 4 + 4 * b;
        add(d_in[i0 + 1], 256, base);
        add(d_in[i0 + 2], ocb[b] * 256, base + 256);
        add(d_in[i0 + 3], ocb[b], base + 256 + ocb[b] * 256);
    }
    const int och[4] = {2, 2, 4, 24};
    for (int h = 0; h < 4; ++h) {
        int base = PB_HD0 + h * 7456;
        int i0 = 16 + 8 * h;
        add(d_in[i0 + 1], 256, base);
        add(d_in[i0 + 2], 256, base + 256);
        add(d_in[i0 + 3], 256, base + 512);
        add(d_in[i0 + 4], 256, base + 768);
        add(d_in[i0 + 5], 256, base + 1024);
        add(d_in[i0 + 6], och[h] * 256, base + 1280);
        add(d_in[i0 + 7], och[h], base + 1280 + och[h] * 256);
    }
    kPrepP<<<si, 256, 0, stream>>>(SG, flag, par);

    // merged MFMA branches (one dispatch, barrier-free K-loop)
    kBranch3<<<dim3(5, 48, 24), 512, 0, stream>>>(
        feat, flag, wb16, par + PB_BR0, d_out, ws);

    // exact f32 strip for NMS/topk decision region (rows 0..4 of heat)
    kBranchX<<<dim3(5, 5, 8), 256, 0, stream>>>(
        feat, flag, ws + WS_W1T, par + PB_BR0, d_out, O_HEAT, ws + WS_HEAT);

    kNms<<<2880, 256, 0, stream>>>(ws + WS_HEAT, ws + WS_NH);
    kTopA<<<dim3(24, NCHUNK), 256, 0, stream>>>(ws + WS_NH);
    kTopB<<<24, 64, 0, stream>>>(ws + WS_NH, ws + WS_S1S, (int*)(ws + WS_S1I));
    kTop2<<<8, 64, 0, stream>>>(ws + WS_S1S, (int*)(ws + WS_S1I), ws + WS_OFF2,
                                ws + WS_SIZ2, ws + WS_BOX, (int*)(ws + WS_CLS));
    kRoi<<<400, 256, 0, stream>>>(feat, flag, ws + WS_BOX, (int*)(ws + WS_CLS),
                                  par, ws + WS_ROI);
    kHeadM<<<dim3(4, NROI), 256, 0, stream>>>(ws + WS_ROI, whb, par, ws + WS_HOUT);
    kFinal<<<2, 256, 0, stream>>>(ws + WS_HOUT, ws + WS_BOX, (int*)(ws + WS_CLS),
                                  par, d_out, flag);
}

// Round 10
// 914.221 us; speedup vs baseline: 1.5110x; 1.0670x over previous
//
#include <hip/hip_runtime.h>
#include <math.h>

typedef unsigned short u16;
typedef unsigned int   u32;
typedef unsigned long long u64;
typedef __attribute__((ext_vector_type(8))) short short8;   // 8 bf16 (4 VGPR)
typedef __attribute__((ext_vector_type(4))) float f32x4;    // MFMA acc

// ---------- dtype helpers ----------
__device__ __forceinline__ float b2f(u16 v) { return __uint_as_float(((u32)v) << 16); }
__device__ __forceinline__ u16 f2b(float f) {
    u32 u = __float_as_uint(f);
    u32 r = (u + 0x7FFFu + ((u >> 16) & 1u)) >> 16;   // RNE
    return (u16)r;
}
__device__ __forceinline__ float gload(const void* p, long i, int bf) {
    return bf ? b2f(((const u16*)p)[i]) : ((const float*)p)[i];
}
__device__ __forceinline__ void gstore(void* p, long i, float v, int bf) {
    if (bf) ((u16*)p)[i] = f2b(v);
    else    ((float*)p)[i] = v;
}

// top-k key: smallest key = (largest value, then smallest index)
__device__ __forceinline__ u64 packKey(float v, int idx) {
    u32 u = __float_as_uint(v);
    u32 m = (u & 0x80000000u) ? ~u : (u | 0x80000000u);   // monotone float->uint
    return ((u64)(~m) << 32) | (u32)idx;
}

// ---------- problem constants ----------
#define BATCH 8
#define CIN   64
#define FH    96
#define FW    320
#define KDET  50
#define NROI  400
#define CROI  69
#define HW    (FH*FW)
#define CHUNK 1920
#define NCHUNK 16

// ---------- workspace layout (float offsets) ----------
#define WS_HEAT 0L
#define WS_OFF2 737280L
#define WS_SIZ2 1228800L
#define WS_NH   1720320L
#define WS_S1S  2457600L
#define WS_S1I  2458800L
#define WS_CLS  2460000L
#define WS_BOX  2460400L
#define WS_ROI  2462400L
#define WS_HOUT 3814800L
#define WS_W1T  3827600L     // 147456 f32: hm conv1 [k=576][c=256] (exact strip)
#define WS_WB16 3975056L     // u16: 3 branches * [9][2][256][32] bf16 (lane-coalesced)
#define WS_W1H  4269968L     // u16: 4 heads * [9][3][256][32] bf16
#define WS_PAR  4905872L     // packed f32 params
#define WS_FLAG 4938960L     // int dtype flag

// param block sub-offsets
#define PB_CAL 0
#define PB_CRN 96
#define PB_MSZ 128
#define PB_BR0 144          // stride 1040: b1@0, w2@256 ([k][n]), b2@256+OC*256
#define PB_HD0 3264         // stride 7456

// ---------- output layout (element offsets) ----------
#define O_HEAT 0L
#define O_OFF2 737280L
#define O_SIZ2 1228800L
#define O_HEAD 1720320L
#define O_DEP  1729920L
#define O_OFF3 1730720L
#define O_S3D  1731520L
#define O_H3D  1732720L

// =====================================================================
// dtype detection
// =====================================================================
__global__ void kDetect(const void* __restrict__ feat, int* __restrict__ flag) {
    __shared__ int cnt;
    if (threadIdx.x == 0) cnt = 0;
    __syncthreads();
    u16 v = ((const u16*)feat)[threadIdx.x];     // 512 threads
    float f = b2f(v);
    u32 e = (v >> 7) & 0xFF;
    float a = fabsf(f);
    int sane = (e != 0xFF) && (f == 0.f || (a >= 1e-8f && a <= 1e4f));
    atomicAdd(&cnt, sane);
    __syncthreads();
    if (threadIdx.x == 0) *flag = (cnt >= 480) ? 1 : 0;
}

// =====================================================================
// Prep: weights
// =====================================================================
struct WPtrs { const void* bw[3]; const void* hw[4]; };

__global__ void kPrepW(WPtrs P, const int* __restrict__ flag,
                       float* __restrict__ w1t, u16* __restrict__ wb16,
                       u16* __restrict__ whb) {
    const int bf = *flag;
    int idx = blockIdx.x * 256 + threadIdx.x;
    if (idx < 147456) {
        int k = idx >> 8, c = idx & 255;
        w1t[idx] = gload(P.bw[0], (long)c * 576 + k, bf);
    } else if (idx < 589824) {
        int j = idx - 147456;
        int br = j / 147456, rem = j % 147456;
        int tap = rem / 16384;
        int r2 = rem & 16383;
        int s = r2 >> 13;
        int n = (r2 >> 5) & 255;
        int c5 = r2 & 31;
        int ci = s * 32 + c5;
        wb16[j] = f2b(gload(P.bw[br], (long)n * 576 + ci * 9 + tap, bf));
    } else {
        int j = idx - 589824;               // < 884736
        int h = j / 221184, rem = j % 221184;
        int tap = rem / 24576, rem2 = rem % 24576;
        int cs = rem2 / 8192, rem3 = rem2 % 8192;
        int oc = rem3 >> 5, jj = rem3 & 31;
        int ci = cs * 32 + jj;
        u16 val = 0;
        if (ci < CROI) val = f2b(gload(P.hw[h], (long)oc * 621 + ci * 9 + tap, bf));
        whb[j] = val;
    }
}

// Prep: pack all small params to f32
struct Seg { const void* src; int n; int dst; };
struct Segs { Seg s[40]; };

__global__ void kPrepP(Segs S, const int* __restrict__ flag, float* __restrict__ par) {
    const int bf = *flag;
    Seg sg = S.s[blockIdx.x];
    for (int i = threadIdx.x; i < sg.n; i += 256)
        par[sg.dst + i] = gload(sg.src, i, bf);
}

// =====================================================================
// Merged MFMA branch conv: all 3 branches, 512 thr, M=128 (2 rows x 64 x)
// Wave tile 64M x 64N: mg=wave>>2 (M half), ng=wave&3 (N quarter).
// A LDS reads: 4 b128/k-step (halved); B direct from global (4/k-step).
// K-loop barrier-free; tap loop unroll 1 (reg-budget discipline).
// =====================================================================
union B3U {
    u16   a[4][68][72];       // input rows y0-1..y0+2, x0-1..x0+64, 64ci (pad 72)
    float red[8][64][3];      // 1x1 partials per wave (wave-local 64 m)
};

__global__ __launch_bounds__(512, 4)
void kBranch3(const void* __restrict__ feat, const int* __restrict__ flag,
              const u16* __restrict__ wbAll,   // 3 * [9][2][256][32] bf16
              const float* __restrict__ bpAll, // par + PB_BR0, stride 1040
              void* __restrict__ outb, float* __restrict__ wsbase) {
    __shared__ __align__(16) B3U u;

    const long obase[3] = {O_HEAT, O_OFF2, O_SIZ2};
    const long wfs[3]   = {WS_HEAT, WS_OFF2, WS_SIZ2};

    const int bfl = *flag;
    const int tid = threadIdx.x;
    const int wave = tid >> 6, lane = tid & 63;
    const int q = lane >> 4, n15 = lane & 15;
    const int mg = wave >> 2, ng = wave & 3;
    const int x0 = blockIdx.x * 64, y0 = blockIdx.y * 2;
    const int br = blockIdx.z >> 3, b = blockIdx.z & 7;
    const int oc = (br == 0) ? 3 : 2;
    const u16* wpt = wbAll + br * 147456;
    const float* bp = bpAll + br * 1040;

    // ---- stage input tile: rows y0-1..y0+2, x0-1..x0+64, 64 ci ----
    if (tid < 256) {
        const int ci = tid & 63, rr = tid >> 6;
        const int gy = y0 - 1 + rr;
        if (gy < 0 || gy >= FH) {
            for (int xi = 0; xi < 66; ++xi) u.a[rr][xi][ci] = 0;
        } else if (bfl) {
            const u16* rp = (const u16*)feat + ((long)((b << 6) | ci) * FH + gy) * FW;
            for (int j = 0; j < 10; ++j) {
                int xs0 = x0 - 8 + j * 8;
                u16 tmp[8];
                if (xs0 >= 0 && xs0 <= FW - 8)
                    *(uint4*)tmp = *(const uint4*)(rp + xs0);
                else
                    for (int e = 0; e < 8; ++e) {
                        int gx = xs0 + e;
                        tmp[e] = (gx >= 0 && gx < FW) ? rp[gx] : (u16)0;
                    }
                for (int e = 0; e < 8; ++e) {
                    int xi = xs0 + e - x0 + 1;
                    if (xi >= 0 && xi < 66) u.a[rr][xi][ci] = tmp[e];
                }
            }
        } else {
            const float* rp = (const float*)feat + ((long)((b << 6) | ci) * FH + gy) * FW;
            for (int j = 0; j < 18; ++j) {
                int xs0 = x0 - 4 + j * 4;
                float tmp[4];
                if (xs0 >= 0 && xs0 <= FW - 4)
                    *(float4*)tmp = *(const float4*)(rp + xs0);
                else
                    for (int e = 0; e < 4; ++e) {
                        int gx = xs0 + e;
                        tmp[e] = (gx >= 0 && gx < FW) ? rp[gx] : 0.f;
                    }
                for (int e = 0; e < 4; ++e) {
                    int xi = xs0 + e - x0 + 1;
                    if (xi >= 0 && xi < 66) u.a[rr][xi][ci] = f2b(tmp[e]);
                }
            }
        }
    }
    __syncthreads();   // a_lds visible to all waves; no more barriers in K-loop

    f32x4 acc[4][4];
#pragma unroll
    for (int i = 0; i < 4; ++i)
#pragma unroll
        for (int t = 0; t < 4; ++t) acc[i][t] = (f32x4){0.f, 0.f, 0.f, 0.f};

    // ---- K-loop: 9 taps x 2 k-steps (32 ci each), barrier-free ----
#pragma unroll 1
    for (int tap = 0; tap < 9; ++tap) {
        const int ky = tap / 3, kx = tap % 3;
#pragma unroll
        for (int s = 0; s < 2; ++s) {
            const u16* wks = wpt + (tap * 2 + s) * 8192;
            short8 bfr[4];
#pragma unroll
            for (int t = 0; t < 4; ++t)
                bfr[t] = *(const short8*)(wks + (ng * 64 + t * 16 + n15) * 32 + q * 8);
            short8 afr[4];
#pragma unroll
            for (int i = 0; i < 4; ++i)
                afr[i] = *(const short8*)&u.a[mg + ky][i * 16 + n15 + kx][s * 32 + q * 8];
#pragma unroll
            for (int i = 0; i < 4; ++i)
#pragma unroll
                for (int t = 0; t < 4; ++t)
                    acc[i][t] = __builtin_amdgcn_mfma_f32_16x16x32_bf16(
                        afr[i], bfr[t], acc[i][t], 0, 0, 0);
        }
    }

    // ---- epilogue: b1 + relu + 1x1 partials (wave covers 64 m, 64 n) ----
    float b1v[4], w2v[3][4];
#pragma unroll
    for (int t = 0; t < 4; ++t) {
        int n = ng * 64 + t * 16 + n15;
        b1v[t] = bp[n];
#pragma unroll
        for (int k = 0; k < 3; ++k) w2v[k][t] = bp[256 + k * 256 + n];
    }
    __syncthreads();   // done reading u.a; reuse as red
#pragma unroll
    for (int i = 0; i < 4; ++i) {
#pragma unroll
        for (int r = 0; r < 4; ++r) {
            float pk[3];
#pragma unroll
            for (int k = 0; k < 3; ++k) pk[k] = 0.f;
#pragma unroll
            for (int t = 0; t < 4; ++t) {
                float h = fmaxf(acc[i][t][r] + b1v[t], 0.f);
#pragma unroll
                for (int k = 0; k < 3; ++k) pk[k] = fmaf(h, w2v[k][t], pk[k]);
            }
#pragma unroll
            for (int k = 0; k < 3; ++k) {
                pk[k] += __shfl_xor(pk[k], 1);
                pk[k] += __shfl_xor(pk[k], 2);
                pk[k] += __shfl_xor(pk[k], 4);
                pk[k] += __shfl_xor(pk[k], 8);
            }
            if (n15 == 0) {
                int ml = i * 16 + q * 4 + r;       // 0..63 within wave's M half
#pragma unroll
                for (int k = 0; k < 3; ++k) u.red[wave][ml][k] = pk[k];
            }
        }
    }
    __syncthreads();
    float* outf = wsbase + wfs[br];
    for (int t2 = tid; t2 < oc * 128; t2 += 512) {
        int k = t2 >> 7, m = t2 & 127;
        int row = m >> 6, x = m & 63;
        int mg2 = m >> 6, ml = m & 63;
        float s = bp[256 + oc * 256 + k];
#pragma unroll
        for (int w = 0; w < 4; ++w) s += u.red[mg2 * 4 + w][ml][k];
        long o = (((long)b * oc + k) * FH + (y0 + row)) * FW + x0 + x;
        gstore(outb, obase[br] + o, s, bfl);
        outf[o] = s;
    }
}

// =====================================================================
// Exact f32 strip (rows 0..2 of heat): selection decisions (NMS rows
// 0..1, first-50-zeros all in row 0) match the f32 reference path.
// 32-wide x-tiles halve per-block serial latency. Summation order per
// output is identical to prior rounds (bit-preserving).
// =====================================================================
union BrLds {
    float w[36 * 256];
    float part[32 * 3 * 32];
};

__global__ __launch_bounds__(256)
void kBranchX(const void* __restrict__ feat, const int* __restrict__ flag,
              const float* __restrict__ w1t, const float* __restrict__ bp,
              void* __restrict__ outb, long obase, float* __restrict__ outf) {
    __shared__ float in_lds[4][3][36];
    __shared__ BrLds u;
    const int bf = *flag;
    const int OC = 3;

    const int tid = threadIdx.x;
    const int xg = tid & 7, cg = tid >> 3;
    const int x0 = blockIdx.x * 32, y = blockIdx.y, b = blockIdx.z;
    const int c0 = cg * 8;

    float acc[8][4];
#pragma unroll
    for (int i = 0; i < 8; ++i)
#pragma unroll
        for (int j = 0; j < 4; ++j) acc[i][j] = 0.f;

    for (int chunk = 0; chunk < 16; ++chunk) {
        const int ci0 = chunk * 4;
        __syncthreads();
        for (int i = tid; i < 4 * 3 * 36; i += 256) {
            int xx = i % 36, t2 = i / 36;
            int r = t2 % 3, ci = t2 / 3;
            int gx = x0 - 1 + xx, gy = y - 1 + r;
            float v = 0.f;
            if (gx >= 0 && gx < FW && gy >= 0 && gy < FH)
                v = gload(feat, ((long)(b * CIN + ci0 + ci) * FH + gy) * FW + gx, bf);
            in_lds[ci][r][xx] = v;
        }
        {
            const float4* src = (const float4*)(w1t + (long)ci0 * 9 * 256);
            float4* dst = (float4*)u.w;
            for (int i = tid; i < 36 * 256 / 4; i += 256) dst[i] = src[i];
        }
        __syncthreads();
#pragma unroll
        for (int ci = 0; ci < 4; ++ci) {
#pragma unroll
            for (int ky = 0; ky < 3; ++ky) {
                const float* rowp = &in_lds[ci][ky][xg * 4];
                float inv[6];
                *(float4*)&inv[0] = *(const float4*)&rowp[0];
                *(float2*)&inv[4] = *(const float2*)&rowp[4];
#pragma unroll
                for (int kx = 0; kx < 3; ++kx) {
                    const float* wp = &u.w[(ci * 9 + ky * 3 + kx) * 256 + c0];
                    float wv[8];
                    *(float4*)&wv[0] = *(const float4*)&wp[0];
                    *(float4*)&wv[4] = *(const float4*)&wp[4];
#pragma unroll
                    for (int cc = 0; cc < 8; ++cc)
#pragma unroll
                        for (int xx = 0; xx < 4; ++xx)
                            acc[cc][xx] = fmaf(wv[cc], inv[xx + kx], acc[cc][xx]);
                }
            }
        }
    }

#pragma unroll
    for (int cc = 0; cc < 8; ++cc) {
        float b1v = bp[c0 + cc];
#pragma unroll
        for (int xx = 0; xx < 4; ++xx)
            acc[cc][xx] = fmaxf(acc[cc][xx] + b1v, 0.f);
    }

    __syncthreads();
#pragma unroll
    for (int k = 0; k < OC; ++k) {
        float p[4];
#pragma unroll
        for (int xx = 0; xx < 4; ++xx) p[xx] = 0.f;
#pragma unroll
        for (int cc = 0; cc < 8; ++cc) {
            float wv = bp[256 + k * 256 + c0 + cc];
#pragma unroll
            for (int xx = 0; xx < 4; ++xx) p[xx] = fmaf(acc[cc][xx], wv, p[xx]);
        }
#pragma unroll
        for (int xx = 0; xx < 4; ++xx)
            u.part[(cg * OC + k) * 32 + xg * 4 + xx] = p[xx];
    }
    __syncthreads();
    for (int t = tid; t < OC * 32; t += 256) {
        int k = t >> 5, xx = t & 31;
        float s = bp[256 + OC * 256 + k];
#pragma unroll 8
        for (int g = 0; g < 32; ++g) s += u.part[(g * OC + k) * 32 + xx];
        long o = (((long)b * OC + k) * FH + y) * FW + x0 + xx;
        gstore(outb, obase + o, s, bf);
        outf[o] = s;
    }
}

// =====================================================================
// NMS
// =====================================================================
__global__ void kNms(const float* __restrict__ heat, float* __restrict__ nh) {
    int idx = blockIdx.x * 256 + threadIdx.x;
    if (idx >= 737280) return;
    int x = idx % FW, t = idx / FW;
    int yy = t % FH, bc = t / FH;
    const float* p = heat + (long)bc * HW;
    float v = p[yy * FW + x];
    float m = v;
    for (int dy = -1; dy <= 1; ++dy) {
        int ny = yy + dy;
        if (ny < 0 || ny >= FH) continue;
        for (int dx = -1; dx <= 1; ++dx) {
            int nx = x + dx;
            if (nx < 0 || nx >= FW) continue;
            m = fmaxf(m, p[ny * FW + nx]);
        }
    }
    nh[idx] = (v == m) ? v : 0.f;
}

// =====================================================================
// top-k stage A: per (bc, chunk) local top-50 via single-wave extraction.
// =====================================================================
__global__ __launch_bounds__(256)
void kTopA(float* __restrict__ nh) {
    __shared__ u64 keys[CHUNK];
    const int bc = blockIdx.x, ch = blockIdx.y;
    const int tid = threadIdx.x;
    const long base = (long)bc * HW + (long)ch * CHUNK;
    for (int i = tid; i < CHUNK; i += 256)
        keys[i] = packKey(nh[base + i], ch * CHUNK + i);
    __syncthreads();
    if (tid < 64) {
        const int lane = tid;
        u64* outp = (u64*)(nh + base);
        for (int it = 0; it < KDET; ++it) {
            u64 bk = ~0ULL; int bp = 0;
            for (int i = lane; i < CHUNK; i += 64) {
                u64 k = keys[i];
                if (k < bk) { bk = k; bp = i; }
            }
#pragma unroll
            for (int s = 32; s > 0; s >>= 1) {
                u64 k2 = __shfl_down(bk, s);
                int p2 = __shfl_down(bp, s);
                if (k2 < bk) { bk = k2; bp = p2; }
            }
            bk = __shfl(bk, 0);
            bp = __shfl(bp, 0);
            if (lane == 0) {
                outp[it] = bk;
                keys[bp] = ~0ULL;
            }
        }
    }
}

// =====================================================================
// top-k stage B: merge 16x50 chunk keys -> sorted per-(b,c) top-50
// =====================================================================
__global__ __launch_bounds__(64)
void kTopB(const float* __restrict__ nh, float* __restrict__ s1s,
           int* __restrict__ s1i) {
    __shared__ u64 keys[NCHUNK * KDET];
    const int bc = blockIdx.x, lane = threadIdx.x;
    for (int ch = 0; ch < NCHUNK; ++ch) {
        const u64* src = (const u64*)(nh + (long)bc * HW + (long)ch * CHUNK);
        if (lane < KDET) keys[ch * KDET + lane] = src[lane];
    }
    __syncthreads();
    for (int it = 0; it < KDET; ++it) {
        u64 bk = ~0ULL; int bp = 0;
        for (int i = lane; i < NCHUNK * KDET; i += 64) {
            u64 k = keys[i];
            if (k < bk) { bk = k; bp = i; }
        }
#pragma unroll
        for (int s = 32; s > 0; s >>= 1) {
            u64 k2 = __shfl_down(bk, s);
            int p2 = __shfl_down(bp, s);
            if (k2 < bk) { bk = k2; bp = p2; }
        }
        bk = __shfl(bk, 0);
        bp = __shfl(bp, 0);
        if (lane == 0) {
            u32 hm = ~(u32)(bk >> 32);
            u32 u = (hm & 0x80000000u) ? (hm & 0x7fffffffu) : ~hm;
            s1s[bc * KDET + it] = __uint_as_float(u);
            s1i[bc * KDET + it] = (int)(bk & 0xFFFFFFFFu);
            keys[bp] = ~0ULL;
        }
    }
}

// =====================================================================
// top-50 stage 2 + boxes
// =====================================================================
__global__ void kTop2(const float* __restrict__ s1s, const int* __restrict__ s1i,
                      const float* __restrict__ off2, const float* __restrict__ siz2,
                      float* __restrict__ boxes, int* __restrict__ clsArr) {
    const int b = blockIdx.x, t = threadIdx.x;    // 64 threads
    __shared__ float sc[150];
    for (int i = t; i < 150; i += 64) sc[i] = s1s[b * 150 + i];
    __syncthreads();
    for (int r = 0; r < KDET; ++r) {
        float bv = -INFINITY; int bp = 0x7fffffff;
        for (int i = t; i < 150; i += 64) {
            float v = sc[i];
            if (v > bv) { bv = v; bp = i; }
        }
        for (int s = 32; s > 0; s >>= 1) {
            float v2 = __shfl_down(bv, s);
            int   p2 = __shfl_down(bp, s);
            if (v2 > bv || (v2 == bv && p2 < bp)) { bv = v2; bp = p2; }
        }
        if (t == 0) {
            int cls = bp / KDET;
            int ind = s1i[b * 150 + bp];
            int n = b * KDET + r;
            clsArr[n] = cls;
            int x = ind % FW, yy = ind / FW;
            float cx = (float)x  + off2[(((long)b * 2 + 0) * FH + yy) * FW + x];
            float cy = (float)yy + off2[(((long)b * 2 + 1) * FH + yy) * FW + x];
            float w  = siz2[(((long)b * 2 + 0) * FH + yy) * FW + x];
            float h  = siz2[(((long)b * 2 + 1) * FH + yy) * FW + x];
            boxes[n * 5 + 0] = (float)b;
            boxes[n * 5 + 1] = cx - w * 0.5f;
            boxes[n * 5 + 2] = cy - h * 0.5f;
            boxes[n * 5 + 3] = cx + w * 0.5f;
            boxes[n * 5 + 4] = cy + h * 0.5f;
            sc[bp] = -INFINITY;
        }
        __syncthreads();
    }
}

// =====================================================================
// ROI align 7x7 (sr=2) + coord maps + one-hot -> roi_in f32
// =====================================================================
__global__ __launch_bounds__(256)
void kRoi(const void* __restrict__ feat, const int* __restrict__ flag,
          const float* __restrict__ boxes, const int* __restrict__ clsArr,
          const float* __restrict__ par, float* __restrict__ roi_in) {
    const int n = blockIdx.x, tid = threadIdx.x;
    const int bf = *flag;
    __shared__ int   x0s[14], x1s[14], y0s[14], y1s[14], vxs[14], vys[14];
    __shared__ float lxs[14], lys[14], cxs[7], cys[7];

    const float bx1 = boxes[n * 5 + 1], by1 = boxes[n * 5 + 2];
    const float bx2 = boxes[n * 5 + 3], by2 = boxes[n * 5 + 4];
    const int b = (int)boxes[n * 5 + 0];

    if (tid < 14) {
        float roi_w = fmaxf(bx2 - bx1, 1.f);
        float X = bx1 + (roi_w / 7.f) * ((tid + 0.5f) * 0.5f);
        vxs[tid] = (X > -1.f) && (X < (float)FW);
        float Xc = fminf(fmaxf(X, 0.f), (float)(FW - 1));
        int xi = (int)floorf(Xc);
        x0s[tid] = xi; x1s[tid] = min(xi + 1, FW - 1); lxs[tid] = Xc - (float)xi;
    } else if (tid >= 16 && tid < 30) {
        int i = tid - 16;
        float roi_h = fmaxf(by2 - by1, 1.f);
        float Y = by1 + (roi_h / 7.f) * ((i + 0.5f) * 0.5f);
        vys[i] = (Y > -1.f) && (Y < (float)FH);
        float Yc = fminf(fmaxf(Y, 0.f), (float)(FH - 1));
        int yi = (int)floorf(Yc);
        y0s[i] = yi; y1s[i] = min(yi + 1, FH - 1); lys[i] = Yc - (float)yi;
    } else if (tid >= 32 && tid < 46) {
        int j = tid - 32;
        const float* cal = par + PB_CAL + b * 12;
        float f_u = cal[0], c_u = cal[2], t03 = cal[3];
        float f_v = cal[5], c_v = cal[6], t13 = cal[7];
        float bxc = t03 / (-f_u), byc = t13 / (-f_v);
        const float* cr = par + PB_CRN + b * 4;
        float crx0 = cr[0], cry0 = cr[1], crx1 = cr[2], cry1 = cr[3];
        float sx = crx1 - crx0, sy = cry1 - cry0;
        float u1 = bx1 / (float)FW * sx + crx0, v1 = by1 / (float)FH * sy + cry0;
        float u2 = bx2 / (float)FW * sx + crx0, v2 = by2 / (float)FH * sy + cry0;
        float p1x = (u1 - c_u) / f_u + bxc, p1y = (v1 - c_v) / f_v + byc;
        float p2x = (u2 - c_u) / f_u + bxc, p2y = (v2 - c_v) / f_v + byc;
        if (j < 7) cxs[j] = p1x + ((float)j / 6.f) * (p2x - p1x);
        else       cys[j - 7] = p1y + ((float)(j - 7) / 6.f) * (p2y - p1y);
    }
    __syncthreads();

    for (int t = tid; t < CIN * 49; t += 256) {
        int c = t / 49, p = t % 49, oy = p / 7, ox = p % 7;
        long fb = ((long)b * CIN + c) * HW;
        float acc = 0.f;
#pragma unroll
        for (int dy = 0; dy < 2; ++dy) {
            int sy = oy * 2 + dy;
            float ly = lys[sy]; int yA = y0s[sy], yB = y1s[sy], vy = vys[sy];
#pragma unroll
            for (int dx = 0; dx < 2; ++dx) {
                int sx = ox * 2 + dx;
                float lx = lxs[sx]; int xA = x0s[sx], xB = x1s[sx];
                float v = (1.f - ly) * (1.f - lx) * gload(feat, fb + yA * FW + xA, bf)
                        + (1.f - ly) * lx         * gload(feat, fb + yA * FW + xB, bf)
                        + ly * (1.f - lx)         * gload(feat, fb + yB * FW + xA, bf)
                        + ly * lx                 * gload(feat, fb + yB * FW + xB, bf);
                if (!(vy && vxs[sx])) v = 0.f;
                acc += v;
            }
        }
        roi_in[((long)n * CROI + c) * 49 + p] = acc * 0.25f;
    }
    int cls = clsArr[n];
    for (int t = tid; t < 5 * 49; t += 256) {
        int ch = t / 49, p = t % 49, i = p / 7, j = p % 7;
        float v;
        if (ch == 0)      v = cxs[j];
        else if (ch == 1) v = cys[i];
        else              v = (cls == ch - 2) ? 1.f : 0.f;
        roi_in[((long)n * CROI + 64 + ch) * 49 + p] = v;
    }
}

// =====================================================================
// MFMA ROI head: conv3x3(69->256,pad1) as 9 taps x 3 k-steps GEMM
// B-frags load directly from global; K-loop barrier-free; tap loop unroll 1.
// =====================================================================
__global__ __launch_bounds__(256, 4)
void kHeadM(const float* __restrict__ roi_in, const u16* __restrict__ whb,
            const float* __restrict__ par, float* __restrict__ head_out) {
    const int h = blockIdx.x, n = blockIdx.y, tid = threadIdx.x;
    const int wave = tid >> 6, lane = tid & 63;
    const int q = lane >> 4, n15 = lane & 15;
    const int ocArr[4] = {2, 2, 4, 24};
    const int offArr[4] = {0, 2, 4, 8};
    __shared__ __align__(16) u16 r_lds[9][9][104];   // padded roi, ci-contig
    __shared__ float means[256];

    for (int i = tid; i < 9 * 9 * 104 / 8; i += 256)
        ((uint4*)r_lds)[i] = (uint4){0, 0, 0, 0};
    __syncthreads();
    const float* rp = roi_in + (long)n * CROI * 49;
    for (int i = tid; i < CROI * 49; i += 256) {
        int c = i / 49, p = i % 49;
        r_lds[p / 7 + 1][p % 7 + 1][c] = f2b(rp[i]);
    }
    __syncthreads();

    int oyA[4], oxA[4];
#pragma unroll
    for (int i = 0; i < 4; ++i) {
        int pos = i * 16 + n15; if (pos > 48) pos = 48;
        oyA[i] = pos / 7; oxA[i] = pos % 7;
    }

    f32x4 acc[4][4];
#pragma unroll
    for (int i = 0; i < 4; ++i)
#pragma unroll
        for (int t = 0; t < 4; ++t) acc[i][t] = (f32x4){0.f, 0.f, 0.f, 0.f};

#pragma unroll 1
    for (int tap = 0; tap < 9; ++tap) {
        const int ky = tap / 3, kx = tap % 3;
        const u16* wt = whb + ((long)h * 9 + tap) * 24576;   // [3][256][32]
#pragma unroll
        for (int cs = 0; cs < 3; ++cs) {
            short8 afr[4], bfr[4];
#pragma unroll
            for (int i = 0; i < 4; ++i)
                afr[i] = *(const short8*)&r_lds[oyA[i] + ky][oxA[i] + kx][cs * 32 + q * 8];
#pragma unroll
            for (int t = 0; t < 4; ++t)
                bfr[t] = *(const short8*)(wt + ((cs << 8) + wave * 64 + t * 16 + n15) * 32 + q * 8);
#pragma unroll
            for (int i = 0; i < 4; ++i)
#pragma unroll
                for (int t = 0; t < 4; ++t)
                    acc[i][t] = __builtin_amdgcn_mfma_f32_16x16x32_bf16(
                        afr[i], bfr[t], acc[i][t], 0, 0, 0);
        }
    }

    const float* hb = par + PB_HD0 + h * 7456;
#pragma unroll
    for (int t = 0; t < 4; ++t) {
        int oc = wave * 64 + t * 16 + n15;
        float b1 = hb[oc], g = hb[256 + oc], be = hb[512 + oc];
        float m = hb[768 + oc], v = hb[1024 + oc];
        float scale = g / sqrtf(v + 1e-5f);
        float s = 0.f;
#pragma unroll
        for (int i = 0; i < 4; ++i)
#pragma unroll
            for (int r = 0; r < 4; ++r) {
                int pos = i * 16 + q * 4 + r;
                if (pos < 49)
                    s += fmaxf((acc[i][t][r] + b1 - m) * scale + be, 0.f);
            }
        s += __shfl_xor(s, 16);
        s += __shfl_xor(s, 32);
        if (q == 0) means[oc] = s / 49.f;
    }
    __syncthreads();

    int oc_out = ocArr[h];
    const float* w2 = hb + 1280;
    for (int k = wave; k < oc_out; k += 4) {
        float s = 0.f;
        for (int c = lane; c < 256; c += 64) s += means[c] * w2[k * 256 + c];
#pragma unroll
        for (int off = 32; off > 0; off >>= 1) s += __shfl_down(s, off);
        if (lane == 0)
            head_out[(long)n * 32 + offArr[h] + k] = s + w2[oc_out * 256 + k];
    }
}

// =====================================================================
// Final scalar math + small outputs
// =====================================================================
__global__ void kFinal(const float* __restrict__ head_out, const float* __restrict__ boxes,
                       const int* __restrict__ clsArr, const float* __restrict__ par,
                       void* __restrict__ out, const int* __restrict__ flag) {
    int n = blockIdx.x * 256 + threadIdx.x;
    if (n >= NROI) return;
    const int bf = *flag;
    const float* ho = head_out + (long)n * 32;
    float dep0 = ho[0], dep1 = ho[1];
    int b = (int)boxes[n * 5 + 0];
    int cls = clsArr[n];

    for (int j = 0; j < 24; ++j) gstore(out, O_HEAD + n * 24 + j, ho[8 + j], bf);
    gstore(out, O_OFF3 + n * 2 + 0, ho[2], bf);
    gstore(out, O_OFF3 + n * 2 + 1, ho[3], bf);
    gstore(out, O_S3D + n * 3 + 0, ho[4], bf);
    gstore(out, O_S3D + n * 3 + 1, ho[5], bf);
    gstore(out, O_S3D + n * 3 + 2, ho[6], bf);
    gstore(out, O_H3D + n, ho[7], bf);

    float cry0 = par[PB_CRN + b * 4 + 1], cry1 = par[PB_CRN + b * 4 + 3];
    float sy = cry1 - cry0;
    float bi2 = boxes[n * 5 + 2] / (float)FH * sy + cry0;
    float bi4 = boxes[n * 5 + 4] / (float)FH * sy + cry0;
    float box_h = fmaxf(bi4 - bi2, 1.f);
    float f_u = par[PB_CAL + b * 12 + 0];
    float size3d0 = par[PB_MSZ + cls * 3 + 0] + ho[4];
    float depth_geo = size3d0 / box_h * f_u;
    float sig = 1.f / (1.f + expf(-dep0));
    float d0 = 1.f / (sig + 1e-6f) - 1.f + depth_geo;
    float dgls = ho[7] + 2.f * (logf(f_u) - logf(box_h));
    float mx = fmaxf(dep1, dgls);
    float lse = mx + logf(expf(dep1 - mx) + expf(dgls - mx));
    gstore(out, O_DEP + n * 2 + 0, d0, bf);
    gstore(out, O_DEP + n * 2 + 1, lse, bf);
}

// =====================================================================
extern "C" void kernel_launch(void* const* d_in, const int* in_sizes, int n_in,
                              void* d_out, int out_size, void* d_ws, size_t ws_size,
                              hipStream_t stream) {
    (void)in_sizes; (void)n_in; (void)out_size; (void)ws_size;
    float* ws = (float*)d_ws;
    float* par = ws + WS_PAR;
    int* flag = (int*)(ws + WS_FLAG);
    u16* wb16 = (u16*)(ws + WS_WB16);
    u16* whb  = (u16*)(ws + WS_W1H);
    const void* feat = d_in[0];

    kDetect<<<1, 512, 0, stream>>>(feat, flag);

    WPtrs WP;
    WP.bw[0] = d_in[4]; WP.bw[1] = d_in[8]; WP.bw[2] = d_in[12];
    WP.hw[0] = d_in[16]; WP.hw[1] = d_in[24]; WP.hw[2] = d_in[32]; WP.hw[3] = d_in[40];
    kPrepW<<<5760, 256, 0, stream>>>(WP, flag, ws + WS_W1T, wb16, whb);

    Segs SG; int si = 0;
    auto add = [&](const void* s, int n, int dst) {
        SG.s[si].src = s; SG.s[si].n = n; SG.s[si].dst = dst; ++si;
    };
    add(d_in[1], 96, PB_CAL); add(d_in[2], 32, PB_CRN); add(d_in[3], 9, PB_MSZ);
    const int ocb[3] = {3, 2, 2};
    for (int b = 0; b < 3; ++b) {
        int base = PB_BR0 + b * 1040;
        int i0 = 4 + 4 * b;
        add(d_in[i0 + 1], 256, base);
        add(d_in[i0 + 2], ocb[b] * 256, base + 256);
        add(d_in[i0 + 3], ocb[b], base + 256 + ocb[b] * 256);
    }
    const int och[4] = {2, 2, 4, 24};
    for (int h = 0; h < 4; ++h) {
        int base = PB_HD0 + h * 7456;
        int i0 = 16 + 8 * h;
        add(d_in[i0 + 1], 256, base);
        add(d_in[i0 + 2], 256, base + 256);
        add(d_in[i0 + 3], 256, base + 512);
        add(d_in[i0 + 4], 256, base + 768);
        add(d_in[i0 + 5], 256, base + 1024);
        add(d_in[i0 + 6], och[h] * 256, base + 1280);
        add(d_in[i0 + 7], och[h], base + 1280 + och[h] * 256);
    }
    kPrepP<<<si, 256, 0, stream>>>(SG, flag, par);

    // merged MFMA branches (one dispatch, barrier-free K-loop, 64x64 wave tile)
    kBranch3<<<dim3(5, 48, 24), 512, 0, stream>>>(
        feat, flag, wb16, par + PB_BR0, d_out, ws);

    // exact f32 strip for NMS/topk decision region (rows 0..2 of heat)
    kBranchX<<<dim3(10, 3, 8), 256, 0, stream>>>(
        feat, flag, ws + WS_W1T, par + PB_BR0, d_out, O_HEAT, ws + WS_HEAT);

    kNms<<<2880, 256, 0, stream>>>(ws + WS_HEAT, ws + WS_NH);
    kTopA<<<dim3(24, NCHUNK), 256, 0, stream>>>(ws + WS_NH);
    kTopB<<<24, 64, 0, stream>>>(ws + WS_NH, ws + WS_S1S, (int*)(ws + WS_S1I));
    kTop2<<<8, 64, 0, stream>>>(ws + WS_S1S, (int*)(ws + WS_S1I), ws + WS_OFF2,
                                ws + WS_SIZ2, ws + WS_BOX, (int*)(ws + WS_CLS));
    kRoi<<<400, 256, 0, stream>>>(feat, flag, ws + WS_BOX, (int*)(ws + WS_CLS),
                                  par, ws + WS_ROI);
    kHeadM<<<dim3(4, NROI), 256, 0, stream>>>(ws + WS_ROI, whb, par, ws + WS_HOUT);
    kFinal<<<2, 256, 0, stream>>>(ws + WS_HOUT, ws + WS_BOX, (int*)(ws + WS_CLS),
                                  par, d_out, flag);
}

// Round 11
// 831.507 us; speedup vs baseline: 1.6613x; 1.0995x over previous
//
#include <hip/hip_runtime.h>
#include <math.h>

typedef unsigned short u16;
typedef unsigned int   u32;
typedef unsigned long long u64;
typedef __attribute__((ext_vector_type(8))) short short8;   // 8 bf16 (4 VGPR)
typedef __attribute__((ext_vector_type(4))) float f32x4;    // MFMA acc

// ---------- dtype helpers ----------
__device__ __forceinline__ float b2f(u16 v) { return __uint_as_float(((u32)v) << 16); }
__device__ __forceinline__ u16 f2b(float f) {
    u32 u = __float_as_uint(f);
    u32 r = (u + 0x7FFFu + ((u >> 16) & 1u)) >> 16;   // RNE
    return (u16)r;
}
__device__ __forceinline__ float gload(const void* p, long i, int bf) {
    return bf ? b2f(((const u16*)p)[i]) : ((const float*)p)[i];
}
__device__ __forceinline__ void gstore(void* p, long i, float v, int bf) {
    if (bf) ((u16*)p)[i] = f2b(v);
    else    ((float*)p)[i] = v;
}

// top-k key: smallest key = (largest value, then smallest index)
__device__ __forceinline__ u64 packKey(float v, int idx) {
    u32 u = __float_as_uint(v);
    u32 m = (u & 0x80000000u) ? ~u : (u | 0x80000000u);   // monotone float->uint
    return ((u64)(~m) << 32) | (u32)idx;
}

// per-block dtype-flag recompute (512 u16 probe of feat)
__device__ int blockFlag(const void* feat) {
    __shared__ int fcnt;
    if (threadIdx.x == 0) fcnt = 0;
    __syncthreads();
    int sane = 0;
    for (int i = threadIdx.x; i < 512; i += blockDim.x) {
        u16 v = ((const u16*)feat)[i];
        float f = b2f(v);
        u32 e = (v >> 7) & 0xFF;
        float a = fabsf(f);
        sane += (e != 0xFF) && (f == 0.f || (a >= 1e-8f && a <= 1e4f));
    }
    atomicAdd(&fcnt, sane);
    __syncthreads();
    return fcnt >= 480;
}

// ---------- problem constants ----------
#define BATCH 8
#define CIN   64
#define FH    96
#define FW    320
#define KDET  50
#define NROI  400
#define CROI  69
#define HW    (FH*FW)
#define CHUNK 1920
#define NCHUNK 16

// ---------- workspace layout (float offsets) ----------
#define WS_HEAT 0L
#define WS_OFF2 737280L
#define WS_SIZ2 1228800L
#define WS_NH   1720320L
#define WS_S1S  2457600L
#define WS_S1I  2458800L
#define WS_CLS  2460000L
#define WS_BOX  2460400L
#define WS_ROI  2462400L
#define WS_HOUT 3814800L
#define WS_W1T  3827600L     // 147456 f32: hm conv1 [k=576][c=256] (exact strip)
#define WS_WB16 3975056L     // u16: 3 branches * [9][2][256][32] bf16 (lane-coalesced)
#define WS_W1H  4269968L     // u16: 4 heads * [9][3][256][32] bf16
#define WS_PAR  4905872L     // packed f32 params
#define WS_FLAG 4938960L     // int dtype flag

// param block sub-offsets
#define PB_CAL 0
#define PB_CRN 96
#define PB_MSZ 128
#define PB_BR0 144          // stride 1040: b1@0, w2@256 ([k][n]), b2@256+OC*256
#define PB_HD0 3264         // stride 7456

// ---------- output layout (element offsets) ----------
#define O_HEAT 0L
#define O_OFF2 737280L
#define O_SIZ2 1228800L
#define O_HEAD 1720320L
#define O_DEP  1729920L
#define O_OFF3 1730720L
#define O_S3D  1731520L
#define O_H3D  1732720L

// =====================================================================
// Fused prep: weights + params + flag (block 0 writes flag for later kernels)
//  blocks [0,5760): weight repack; blocks [5760,5800): param segments
// =====================================================================
struct WPtrs { const void* bw[3]; const void* hw[4]; };
struct Seg { const void* src; int n; int dst; };
struct Segs { Seg s[40]; int cnt; };

__global__ void kPrepWP(WPtrs P, Segs S, const void* __restrict__ feat,
                        int* __restrict__ flag, float* __restrict__ w1t,
                        u16* __restrict__ wb16, u16* __restrict__ whb,
                        float* __restrict__ par) {
    const int bf = blockFlag(feat);
    if (blockIdx.x == 0 && threadIdx.x == 0) *flag = bf;
    if (blockIdx.x < 5760) {
        int idx = blockIdx.x * 256 + threadIdx.x;
        if (idx < 147456) {
            int k = idx >> 8, c = idx & 255;
            w1t[idx] = gload(P.bw[0], (long)c * 576 + k, bf);
        } else if (idx < 589824) {
            int j = idx - 147456;
            int br = j / 147456, rem = j % 147456;
            int tap = rem / 16384;
            int r2 = rem & 16383;
            int s = r2 >> 13;
            int n = (r2 >> 5) & 255;
            int c5 = r2 & 31;
            int ci = s * 32 + c5;
            wb16[j] = f2b(gload(P.bw[br], (long)n * 576 + ci * 9 + tap, bf));
        } else {
            int j = idx - 589824;               // < 884736
            int h = j / 221184, rem = j % 221184;
            int tap = rem / 24576, rem2 = rem % 24576;
            int cs = rem2 / 8192, rem3 = rem2 % 8192;
            int oc = rem3 >> 5, jj = rem3 & 31;
            int ci = cs * 32 + jj;
            u16 val = 0;
            if (ci < CROI) val = f2b(gload(P.hw[h], (long)oc * 621 + ci * 9 + tap, bf));
            whb[j] = val;
        }
    } else {
        int sidx = blockIdx.x - 5760;
        if (sidx < S.cnt) {
            Seg sg = S.s[sidx];
            for (int i = threadIdx.x; i < sg.n; i += 256)
                par[sg.dst + i] = gload(sg.src, i, bf);
        }
    }
}

// =====================================================================
// Merged MFMA branch conv: 512 thr, M=128 (2 rows x 64 x), wave 64x64.
// A staged ONCE per block; inner br-loop runs all 3 branches' K-loops.
// B direct from global; K-loop barrier-free; tap & br loops unroll 1.
// =====================================================================
__global__ __launch_bounds__(512, 4)
void kBranch3(const void* __restrict__ feat, const int* __restrict__ flag,
              const u16* __restrict__ wbAll,   // 3 * [9][2][256][32] bf16
              const float* __restrict__ bpAll, // par + PB_BR0, stride 1040
              void* __restrict__ outb, float* __restrict__ wsbase) {
    __shared__ __align__(16) u16 a_lds[4][68][72];   // rows y0-1..y0+2, pad 72
    __shared__ float red[8][64][3];                  // 1x1 partials per wave

    const long obase[3] = {O_HEAT, O_OFF2, O_SIZ2};
    const long wfs[3]   = {WS_HEAT, WS_OFF2, WS_SIZ2};

    const int bfl = *flag;
    const int tid = threadIdx.x;
    const int wave = tid >> 6, lane = tid & 63;
    const int q = lane >> 4, n15 = lane & 15;
    const int mg = wave >> 2, ng = wave & 3;
    const int x0 = blockIdx.x * 64, y0 = blockIdx.y * 2;
    const int b = blockIdx.z;

    // ---- stage input tile once: rows y0-1..y0+2, x0-1..x0+64, 64 ci ----
    if (tid < 256) {
        const int ci = tid & 63, rr = tid >> 6;
        const int gy = y0 - 1 + rr;
        if (gy < 0 || gy >= FH) {
            for (int xi = 0; xi < 66; ++xi) a_lds[rr][xi][ci] = 0;
        } else if (bfl) {
            const u16* rp = (const u16*)feat + ((long)((b << 6) | ci) * FH + gy) * FW;
            for (int j = 0; j < 10; ++j) {
                int xs0 = x0 - 8 + j * 8;
                u16 tmp[8];
                if (xs0 >= 0 && xs0 <= FW - 8)
                    *(uint4*)tmp = *(const uint4*)(rp + xs0);
                else
                    for (int e = 0; e < 8; ++e) {
                        int gx = xs0 + e;
                        tmp[e] = (gx >= 0 && gx < FW) ? rp[gx] : (u16)0;
                    }
                for (int e = 0; e < 8; ++e) {
                    int xi = xs0 + e - x0 + 1;
                    if (xi >= 0 && xi < 66) a_lds[rr][xi][ci] = tmp[e];
                }
            }
        } else {
            const float* rp = (const float*)feat + ((long)((b << 6) | ci) * FH + gy) * FW;
            for (int j = 0; j < 18; ++j) {
                int xs0 = x0 - 4 + j * 4;
                float tmp[4];
                if (xs0 >= 0 && xs0 <= FW - 4)
                    *(float4*)tmp = *(const float4*)(rp + xs0);
                else
                    for (int e = 0; e < 4; ++e) {
                        int gx = xs0 + e;
                        tmp[e] = (gx >= 0 && gx < FW) ? rp[gx] : 0.f;
                    }
                for (int e = 0; e < 4; ++e) {
                    int xi = xs0 + e - x0 + 1;
                    if (xi >= 0 && xi < 66) a_lds[rr][xi][ci] = f2b(tmp[e]);
                }
            }
        }
    }
    __syncthreads();   // a_lds visible; read-only from here on

#pragma unroll 1
    for (int br = 0; br < 3; ++br) {
        const int oc = (br == 0) ? 3 : 2;
        const u16* wpt = wbAll + br * 147456;
        const float* bp = bpAll + br * 1040;

        f32x4 acc[4][4];
#pragma unroll
        for (int i = 0; i < 4; ++i)
#pragma unroll
            for (int t = 0; t < 4; ++t) acc[i][t] = (f32x4){0.f, 0.f, 0.f, 0.f};

        // ---- K-loop: 9 taps x 2 k-steps, barrier-free ----
#pragma unroll 1
        for (int tap = 0; tap < 9; ++tap) {
            const int ky = tap / 3, kx = tap % 3;
#pragma unroll
            for (int s = 0; s < 2; ++s) {
                const u16* wks = wpt + (tap * 2 + s) * 8192;
                short8 bfr[4];
#pragma unroll
                for (int t = 0; t < 4; ++t)
                    bfr[t] = *(const short8*)(wks + (ng * 64 + t * 16 + n15) * 32 + q * 8);
                short8 afr[4];
#pragma unroll
                for (int i = 0; i < 4; ++i)
                    afr[i] = *(const short8*)&a_lds[mg + ky][i * 16 + n15 + kx][s * 32 + q * 8];
#pragma unroll
                for (int i = 0; i < 4; ++i)
#pragma unroll
                    for (int t = 0; t < 4; ++t)
                        acc[i][t] = __builtin_amdgcn_mfma_f32_16x16x32_bf16(
                            afr[i], bfr[t], acc[i][t], 0, 0, 0);
            }
        }

        // ---- epilogue: b1 + relu + 1x1 partials ----
        float b1v[4], w2v[3][4];
#pragma unroll
        for (int t = 0; t < 4; ++t) {
            int n = ng * 64 + t * 16 + n15;
            b1v[t] = bp[n];
#pragma unroll
            for (int k = 0; k < 3; ++k) w2v[k][t] = bp[256 + k * 256 + n];
        }
        __syncthreads();   // prior branch's store-loop reads of red complete
#pragma unroll
        for (int i = 0; i < 4; ++i) {
#pragma unroll
            for (int r = 0; r < 4; ++r) {
                float pk[3];
#pragma unroll
                for (int k = 0; k < 3; ++k) pk[k] = 0.f;
#pragma unroll
                for (int t = 0; t < 4; ++t) {
                    float h = fmaxf(acc[i][t][r] + b1v[t], 0.f);
#pragma unroll
                    for (int k = 0; k < 3; ++k) pk[k] = fmaf(h, w2v[k][t], pk[k]);
                }
#pragma unroll
                for (int k = 0; k < 3; ++k) {
                    pk[k] += __shfl_xor(pk[k], 1);
                    pk[k] += __shfl_xor(pk[k], 2);
                    pk[k] += __shfl_xor(pk[k], 4);
                    pk[k] += __shfl_xor(pk[k], 8);
                }
                if (n15 == 0) {
                    int ml = i * 16 + q * 4 + r;
#pragma unroll
                    for (int k = 0; k < 3; ++k) red[wave][ml][k] = pk[k];
                }
            }
        }
        __syncthreads();
        float* outf = wsbase + wfs[br];
        for (int t2 = tid; t2 < oc * 128; t2 += 512) {
            int k = t2 >> 7, m = t2 & 127;
            int row = m >> 6, x = m & 63;
            int mg2 = m >> 6, ml = m & 63;
            float s = bp[256 + oc * 256 + k];
#pragma unroll
            for (int w = 0; w < 4; ++w) s += red[mg2 * 4 + w][ml][k];
            long o = (((long)b * oc + k) * FH + (y0 + row)) * FW + x0 + x;
            gstore(outb, obase[br] + o, s, bfl);
            outf[o] = s;
        }
    }
}

// =====================================================================
// Exact f32 strip (rows 0..2 of heat): selection decisions bit-match f32
// =====================================================================
union BrLds {
    float w[36 * 256];
    float part[32 * 3 * 32];
};

__global__ __launch_bounds__(256)
void kBranchX(const void* __restrict__ feat, const int* __restrict__ flag,
              const float* __restrict__ w1t, const float* __restrict__ bp,
              void* __restrict__ outb, long obase, float* __restrict__ outf) {
    __shared__ float in_lds[4][3][36];
    __shared__ BrLds u;
    const int bf = *flag;
    const int OC = 3;

    const int tid = threadIdx.x;
    const int xg = tid & 7, cg = tid >> 3;
    const int x0 = blockIdx.x * 32, y = blockIdx.y, b = blockIdx.z;
    const int c0 = cg * 8;

    float acc[8][4];
#pragma unroll
    for (int i = 0; i < 8; ++i)
#pragma unroll
        for (int j = 0; j < 4; ++j) acc[i][j] = 0.f;

    for (int chunk = 0; chunk < 16; ++chunk) {
        const int ci0 = chunk * 4;
        __syncthreads();
        for (int i = tid; i < 4 * 3 * 36; i += 256) {
            int xx = i % 36, t2 = i / 36;
            int r = t2 % 3, ci = t2 / 3;
            int gx = x0 - 1 + xx, gy = y - 1 + r;
            float v = 0.f;
            if (gx >= 0 && gx < FW && gy >= 0 && gy < FH)
                v = gload(feat, ((long)(b * CIN + ci0 + ci) * FH + gy) * FW + gx, bf);
            in_lds[ci][r][xx] = v;
        }
        {
            const float4* src = (const float4*)(w1t + (long)ci0 * 9 * 256);
            float4* dst = (float4*)u.w;
            for (int i = tid; i < 36 * 256 / 4; i += 256) dst[i] = src[i];
        }
        __syncthreads();
#pragma unroll
        for (int ci = 0; ci < 4; ++ci) {
#pragma unroll
            for (int ky = 0; ky < 3; ++ky) {
                const float* rowp = &in_lds[ci][ky][xg * 4];
                float inv[6];
                *(float4*)&inv[0] = *(const float4*)&rowp[0];
                *(float2*)&inv[4] = *(const float2*)&rowp[4];
#pragma unroll
                for (int kx = 0; kx < 3; ++kx) {
                    const float* wp = &u.w[(ci * 9 + ky * 3 + kx) * 256 + c0];
                    float wv[8];
                    *(float4*)&wv[0] = *(const float4*)&wp[0];
                    *(float4*)&wv[4] = *(const float4*)&wp[4];
#pragma unroll
                    for (int cc = 0; cc < 8; ++cc)
#pragma unroll
                        for (int xx = 0; xx < 4; ++xx)
                            acc[cc][xx] = fmaf(wv[cc], inv[xx + kx], acc[cc][xx]);
                }
            }
        }
    }

#pragma unroll
    for (int cc = 0; cc < 8; ++cc) {
        float b1v = bp[c0 + cc];
#pragma unroll
        for (int xx = 0; xx < 4; ++xx)
            acc[cc][xx] = fmaxf(acc[cc][xx] + b1v, 0.f);
    }

    __syncthreads();
#pragma unroll
    for (int k = 0; k < OC; ++k) {
        float p[4];
#pragma unroll
        for (int xx = 0; xx < 4; ++xx) p[xx] = 0.f;
#pragma unroll
        for (int cc = 0; cc < 8; ++cc) {
            float wv = bp[256 + k * 256 + c0 + cc];
#pragma unroll
            for (int xx = 0; xx < 4; ++xx) p[xx] = fmaf(acc[cc][xx], wv, p[xx]);
        }
#pragma unroll
        for (int xx = 0; xx < 4; ++xx)
            u.part[(cg * OC + k) * 32 + xg * 4 + xx] = p[xx];
    }
    __syncthreads();
    for (int t = tid; t < OC * 32; t += 256) {
        int k = t >> 5, xx = t & 31;
        float s = bp[256 + OC * 256 + k];
#pragma unroll 8
        for (int g = 0; g < 32; ++g) s += u.part[(g * OC + k) * 32 + xx];
        long o = (((long)b * OC + k) * FH + y) * FW + x0 + xx;
        gstore(outb, obase + o, s, bf);
        outf[o] = s;
    }
}

// =====================================================================
// Fused NMS + top-k stage A: per (bc, chunk=6 rows) — NMS computed from
// an 8-row halo in LDS (-INF pad == clipped-window max), then local
// top-50 keys written in-place into the chunk's nh slice.
// =====================================================================
__global__ __launch_bounds__(256)
void kNmsTopA(const float* __restrict__ heat, float* __restrict__ nh) {
    __shared__ float hrow[8][320];
    __shared__ u64 keys[CHUNK];
    const int bc = blockIdx.x, ch = blockIdx.y;
    const int tid = threadIdx.x;
    const int r0 = ch * 6;
    const float* hp = heat + (long)bc * HW;

    for (int i = tid; i < 8 * 320; i += 256) {
        int rr = i / 320, x = i % 320;
        int gy = r0 - 1 + rr;
        hrow[rr][x] = (gy >= 0 && gy < FH) ? hp[(long)gy * FW + x] : -INFINITY;
    }
    __syncthreads();
    for (int i = tid; i < CHUNK; i += 256) {
        int ry = i / 320, x = i % 320;
        float v = hrow[ry + 1][x];
        float m = v;
        int xm = max(x - 1, 0), xp = min(x + 1, FW - 1);
#pragma unroll
        for (int dy = 0; dy < 3; ++dy) {
            m = fmaxf(m, hrow[ry + dy][xm]);
            m = fmaxf(m, hrow[ry + dy][x]);
            m = fmaxf(m, hrow[ry + dy][xp]);
        }
        float nv = (v == m) ? v : 0.f;
        keys[i] = packKey(nv, ch * CHUNK + i);
    }
    __syncthreads();
    if (tid < 64) {
        const int lane = tid;
        u64* outp = (u64*)(nh + (long)bc * HW + (long)ch * CHUNK);
        for (int it = 0; it < KDET; ++it) {
            u64 bk = ~0ULL; int bp = 0;
            for (int i = lane; i < CHUNK; i += 64) {
                u64 k = keys[i];
                if (k < bk) { bk = k; bp = i; }
            }
#pragma unroll
            for (int s = 32; s > 0; s >>= 1) {
                u64 k2 = __shfl_down(bk, s);
                int p2 = __shfl_down(bp, s);
                if (k2 < bk) { bk = k2; bp = p2; }
            }
            bk = __shfl(bk, 0);
            bp = __shfl(bp, 0);
            if (lane == 0) {
                outp[it] = bk;
                keys[bp] = ~0ULL;
            }
        }
    }
}

// =====================================================================
// Fused top-k stage B + stage 2 + boxes: 8 blocks (per batch), 192 thr.
// Wave c merges its class's 16x50 chunk keys -> sorted top-50 (LDS);
// wave 0 then runs the 150-way stage-2 with identical tie-break.
// =====================================================================
__global__ __launch_bounds__(192)
void kTopBC(const float* __restrict__ nh, const float* __restrict__ off2,
            const float* __restrict__ siz2, float* __restrict__ boxes,
            int* __restrict__ clsArr) {
    __shared__ u64 keys[3][NCHUNK * KDET];
    __shared__ float sc[150];
    __shared__ int   si[150];
    const int b = blockIdx.x, tid = threadIdx.x;
    const int wave = tid >> 6, lane = tid & 63;
    const int bc = b * 3 + wave;

    for (int ch = 0; ch < NCHUNK; ++ch) {
        const u64* src = (const u64*)(nh + (long)bc * HW + (long)ch * CHUNK);
        if (lane < KDET) keys[wave][ch * KDET + lane] = src[lane];
    }
    __syncthreads();
    for (int it = 0; it < KDET; ++it) {
        u64 bk = ~0ULL; int bp = 0;
        for (int i = lane; i < NCHUNK * KDET; i += 64) {
            u64 k = keys[wave][i];
            if (k < bk) { bk = k; bp = i; }
        }
#pragma unroll
        for (int s = 32; s > 0; s >>= 1) {
            u64 k2 = __shfl_down(bk, s);
            int p2 = __shfl_down(bp, s);
            if (k2 < bk) { bk = k2; bp = p2; }
        }
        bk = __shfl(bk, 0);
        bp = __shfl(bp, 0);
        if (lane == 0) {
            u32 hm = ~(u32)(bk >> 32);
            u32 u = (hm & 0x80000000u) ? (hm & 0x7fffffffu) : ~hm;
            sc[wave * KDET + it] = __uint_as_float(u);
            si[wave * KDET + it] = (int)(bk & 0xFFFFFFFFu);
            keys[wave][bp] = ~0ULL;
        }
    }
    __syncthreads();
    if (wave == 0) {
        const int t = lane;
        for (int r = 0; r < KDET; ++r) {
            float bv = -INFINITY; int bp = 0x7fffffff;
            for (int i = t; i < 150; i += 64) {
                float v = sc[i];
                if (v > bv) { bv = v; bp = i; }
            }
#pragma unroll
            for (int s = 32; s > 0; s >>= 1) {
                float v2 = __shfl_down(bv, s);
                int   p2 = __shfl_down(bp, s);
                if (v2 > bv || (v2 == bv && p2 < bp)) { bv = v2; bp = p2; }
            }
            bp = __shfl(bp, 0);
            if (t == 0) {
                int cls = bp / KDET;
                int ind = si[bp];
                int n = b * KDET + r;
                clsArr[n] = cls;
                int x = ind % FW, yy = ind / FW;
                float cx = (float)x  + off2[(((long)b * 2 + 0) * FH + yy) * FW + x];
                float cy = (float)yy + off2[(((long)b * 2 + 1) * FH + yy) * FW + x];
                float w  = siz2[(((long)b * 2 + 0) * FH + yy) * FW + x];
                float h  = siz2[(((long)b * 2 + 1) * FH + yy) * FW + x];
                boxes[n * 5 + 0] = (float)b;
                boxes[n * 5 + 1] = cx - w * 0.5f;
                boxes[n * 5 + 2] = cy - h * 0.5f;
                boxes[n * 5 + 3] = cx + w * 0.5f;
                boxes[n * 5 + 4] = cy + h * 0.5f;
                sc[bp] = -INFINITY;
            }
        }
    }
}

// =====================================================================
// ROI align 7x7 (sr=2) + coord maps + one-hot -> roi_in f32
// =====================================================================
__global__ __launch_bounds__(256)
void kRoi(const void* __restrict__ feat, const int* __restrict__ flag,
          const float* __restrict__ boxes, const int* __restrict__ clsArr,
          const float* __restrict__ par, float* __restrict__ roi_in) {
    const int n = blockIdx.x, tid = threadIdx.x;
    const int bf = *flag;
    __shared__ int   x0s[14], x1s[14], y0s[14], y1s[14], vxs[14], vys[14];
    __shared__ float lxs[14], lys[14], cxs[7], cys[7];

    const float bx1 = boxes[n * 5 + 1], by1 = boxes[n * 5 + 2];
    const float bx2 = boxes[n * 5 + 3], by2 = boxes[n * 5 + 4];
    const int b = (int)boxes[n * 5 + 0];

    if (tid < 14) {
        float roi_w = fmaxf(bx2 - bx1, 1.f);
        float X = bx1 + (roi_w / 7.f) * ((tid + 0.5f) * 0.5f);
        vxs[tid] = (X > -1.f) && (X < (float)FW);
        float Xc = fminf(fmaxf(X, 0.f), (float)(FW - 1));
        int xi = (int)floorf(Xc);
        x0s[tid] = xi; x1s[tid] = min(xi + 1, FW - 1); lxs[tid] = Xc - (float)xi;
    } else if (tid >= 16 && tid < 30) {
        int i = tid - 16;
        float roi_h = fmaxf(by2 - by1, 1.f);
        float Y = by1 + (roi_h / 7.f) * ((i + 0.5f) * 0.5f);
        vys[i] = (Y > -1.f) && (Y < (float)FH);
        float Yc = fminf(fmaxf(Y, 0.f), (float)(FH - 1));
        int yi = (int)floorf(Yc);
        y0s[i] = yi; y1s[i] = min(yi + 1, FH - 1); lys[i] = Yc - (float)yi;
    } else if (tid >= 32 && tid < 46) {
        int j = tid - 32;
        const float* cal = par + PB_CAL + b * 12;
        float f_u = cal[0], c_u = cal[2], t03 = cal[3];
        float f_v = cal[5], c_v = cal[6], t13 = cal[7];
        float bxc = t03 / (-f_u), byc = t13 / (-f_v);
        const float* cr = par + PB_CRN + b * 4;
        float crx0 = cr[0], cry0 = cr[1], crx1 = cr[2], cry1 = cr[3];
        float sx = crx1 - crx0, sy = cry1 - cry0;
        float u1 = bx1 / (float)FW * sx + crx0, v1 = by1 / (float)FH * sy + cry0;
        float u2 = bx2 / (float)FW * sx + crx0, v2 = by2 / (float)FH * sy + cry0;
        float p1x = (u1 - c_u) / f_u + bxc, p1y = (v1 - c_v) / f_v + byc;
        float p2x = (u2 - c_u) / f_u + bxc, p2y = (v2 - c_v) / f_v + byc;
        if (j < 7) cxs[j] = p1x + ((float)j / 6.f) * (p2x - p1x);
        else       cys[j - 7] = p1y + ((float)(j - 7) / 6.f) * (p2y - p1y);
    }
    __syncthreads();

    for (int t = tid; t < CIN * 49; t += 256) {
        int c = t / 49, p = t % 49, oy = p / 7, ox = p % 7;
        long fb = ((long)b * CIN + c) * HW;
        float acc = 0.f;
#pragma unroll
        for (int dy = 0; dy < 2; ++dy) {
            int sy = oy * 2 + dy;
            float ly = lys[sy]; int yA = y0s[sy], yB = y1s[sy], vy = vys[sy];
#pragma unroll
            for (int dx = 0; dx < 2; ++dx) {
                int sx = ox * 2 + dx;
                float lx = lxs[sx]; int xA = x0s[sx], xB = x1s[sx];
                float v = (1.f - ly) * (1.f - lx) * gload(feat, fb + yA * FW + xA, bf)
                        + (1.f - ly) * lx         * gload(feat, fb + yA * FW + xB, bf)
                        + ly * (1.f - lx)         * gload(feat, fb + yB * FW + xA, bf)
                        + ly * lx                 * gload(feat, fb + yB * FW + xB, bf);
                if (!(vy && vxs[sx])) v = 0.f;
                acc += v;
            }
        }
        roi_in[((long)n * CROI + c) * 49 + p] = acc * 0.25f;
    }
    int cls = clsArr[n];
    for (int t = tid; t < 5 * 49; t += 256) {
        int ch = t / 49, p = t % 49, i = p / 7, j = p % 7;
        float v;
        if (ch == 0)      v = cxs[j];
        else if (ch == 1) v = cys[i];
        else              v = (cls == ch - 2) ? 1.f : 0.f;
        roi_in[((long)n * CROI + 64 + ch) * 49 + p] = v;
    }
}

// =====================================================================
// MFMA ROI head: conv3x3(69->256,pad1) as 9 taps x 3 k-steps GEMM
// B-frags direct from global; K-loop barrier-free; tap loop unroll 1.
// =====================================================================
__global__ __launch_bounds__(256, 4)
void kHeadM(const float* __restrict__ roi_in, const u16* __restrict__ whb,
            const float* __restrict__ par, float* __restrict__ head_out) {
    const int h = blockIdx.x, n = blockIdx.y, tid = threadIdx.x;
    const int wave = tid >> 6, lane = tid & 63;
    const int q = lane >> 4, n15 = lane & 15;
    const int ocArr[4] = {2, 2, 4, 24};
    const int offArr[4] = {0, 2, 4, 8};
    __shared__ __align__(16) u16 r_lds[9][9][104];   // padded roi, ci-contig
    __shared__ float means[256];

    for (int i = tid; i < 9 * 9 * 104 / 8; i += 256)
        ((uint4*)r_lds)[i] = (uint4){0, 0, 0, 0};
    __syncthreads();
    const float* rp = roi_in + (long)n * CROI * 49;
    for (int i = tid; i < CROI * 49; i += 256) {
        int c = i / 49, p = i % 49;
        r_lds[p / 7 + 1][p % 7 + 1][c] = f2b(rp[i]);
    }
    __syncthreads();

    int oyA[4], oxA[4];
#pragma unroll
    for (int i = 0; i < 4; ++i) {
        int pos = i * 16 + n15; if (pos > 48) pos = 48;
        oyA[i] = pos / 7; oxA[i] = pos % 7;
    }

    f32x4 acc[4][4];
#pragma unroll
    for (int i = 0; i < 4; ++i)
#pragma unroll
        for (int t = 0; t < 4; ++t) acc[i][t] = (f32x4){0.f, 0.f, 0.f, 0.f};

#pragma unroll 1
    for (int tap = 0; tap < 9; ++tap) {
        const int ky = tap / 3, kx = tap % 3;
        const u16* wt = whb + ((long)h * 9 + tap) * 24576;   // [3][256][32]
#pragma unroll
        for (int cs = 0; cs < 3; ++cs) {
            short8 afr[4], bfr[4];
#pragma unroll
            for (int i = 0; i < 4; ++i)
                afr[i] = *(const short8*)&r_lds[oyA[i] + ky][oxA[i] + kx][cs * 32 + q * 8];
#pragma unroll
            for (int t = 0; t < 4; ++t)
                bfr[t] = *(const short8*)(wt + ((cs << 8) + wave * 64 + t * 16 + n15) * 32 + q * 8);
#pragma unroll
            for (int i = 0; i < 4; ++i)
#pragma unroll
                for (int t = 0; t < 4; ++t)
                    acc[i][t] = __builtin_amdgcn_mfma_f32_16x16x32_bf16(
                        afr[i], bfr[t], acc[i][t], 0, 0, 0);
        }
    }

    const float* hb = par + PB_HD0 + h * 7456;
#pragma unroll
    for (int t = 0; t < 4; ++t) {
        int oc = wave * 64 + t * 16 + n15;
        float b1 = hb[oc], g = hb[256 + oc], be = hb[512 + oc];
        float m = hb[768 + oc], v = hb[1024 + oc];
        float scale = g / sqrtf(v + 1e-5f);
        float s = 0.f;
#pragma unroll
        for (int i = 0; i < 4; ++i)
#pragma unroll
            for (int r = 0; r < 4; ++r) {
                int pos = i * 16 + q * 4 + r;
                if (pos < 49)
                    s += fmaxf((acc[i][t][r] + b1 - m) * scale + be, 0.f);
            }
        s += __shfl_xor(s, 16);
        s += __shfl_xor(s, 32);
        if (q == 0) means[oc] = s / 49.f;
    }
    __syncthreads();

    int oc_out = ocArr[h];
    const float* w2 = hb + 1280;
    for (int k = wave; k < oc_out; k += 4) {
        float s = 0.f;
        for (int c = lane; c < 256; c += 64) s += means[c] * w2[k * 256 + c];
#pragma unroll
        for (int off = 32; off > 0; off >>= 1) s += __shfl_down(s, off);
        if (lane == 0)
            head_out[(long)n * 32 + offArr[h] + k] = s + w2[oc_out * 256 + k];
    }
}

// =====================================================================
// Final scalar math + small outputs
// =====================================================================
__global__ void kFinal(const float* __restrict__ head_out, const float* __restrict__ boxes,
                       const int* __restrict__ clsArr, const float* __restrict__ par,
                       void* __restrict__ out, const int* __restrict__ flag) {
    int n = blockIdx.x * 256 + threadIdx.x;
    if (n >= NROI) return;
    const int bf = *flag;
    const float* ho = head_out + (long)n * 32;
    float dep0 = ho[0], dep1 = ho[1];
    int b = (int)boxes[n * 5 + 0];
    int cls = clsArr[n];

    for (int j = 0; j < 24; ++j) gstore(out, O_HEAD + n * 24 + j, ho[8 + j], bf);
    gstore(out, O_OFF3 + n * 2 + 0, ho[2], bf);
    gstore(out, O_OFF3 + n * 2 + 1, ho[3], bf);
    gstore(out, O_S3D + n * 3 + 0, ho[4], bf);
    gstore(out, O_S3D + n * 3 + 1, ho[5], bf);
    gstore(out, O_S3D + n * 3 + 2, ho[6], bf);
    gstore(out, O_H3D + n, ho[7], bf);

    float cry0 = par[PB_CRN + b * 4 + 1], cry1 = par[PB_CRN + b * 4 + 3];
    float sy = cry1 - cry0;
    float bi2 = boxes[n * 5 + 2] / (float)FH * sy + cry0;
    float bi4 = boxes[n * 5 + 4] / (float)FH * sy + cry0;
    float box_h = fmaxf(bi4 - bi2, 1.f);
    float f_u = par[PB_CAL + b * 12 + 0];
    float size3d0 = par[PB_MSZ + cls * 3 + 0] + ho[4];
    float depth_geo = size3d0 / box_h * f_u;
    float sig = 1.f / (1.f + expf(-dep0));
    float d0 = 1.f / (sig + 1e-6f) - 1.f + depth_geo;
    float dgls = ho[7] + 2.f * (logf(f_u) - logf(box_h));
    float mx = fmaxf(dep1, dgls);
    float lse = mx + logf(expf(dep1 - mx) + expf(dgls - mx));
    gstore(out, O_DEP + n * 2 + 0, d0, bf);
    gstore(out, O_DEP + n * 2 + 1, lse, bf);
}

// =====================================================================
extern "C" void kernel_launch(void* const* d_in, const int* in_sizes, int n_in,
                              void* d_out, int out_size, void* d_ws, size_t ws_size,
                              hipStream_t stream) {
    (void)in_sizes; (void)n_in; (void)out_size; (void)ws_size;
    float* ws = (float*)d_ws;
    float* par = ws + WS_PAR;
    int* flag = (int*)(ws + WS_FLAG);
    u16* wb16 = (u16*)(ws + WS_WB16);
    u16* whb  = (u16*)(ws + WS_W1H);
    const void* feat = d_in[0];

    WPtrs WP;
    WP.bw[0] = d_in[4]; WP.bw[1] = d_in[8]; WP.bw[2] = d_in[12];
    WP.hw[0] = d_in[16]; WP.hw[1] = d_in[24]; WP.hw[2] = d_in[32]; WP.hw[3] = d_in[40];

    Segs SG; int si = 0;
    auto add = [&](const void* s, int n, int dst) {
        SG.s[si].src = s; SG.s[si].n = n; SG.s[si].dst = dst; ++si;
    };
    add(d_in[1], 96, PB_CAL); add(d_in[2], 32, PB_CRN); add(d_in[3], 9, PB_MSZ);
    const int ocb[3] = {3, 2, 2};
    for (int b = 0; b < 3; ++b) {
        int base = PB_BR0 + b * 1040;
        int i0 = 4 + 4 * b;
        add(d_in[i0 + 1], 256, base);
        add(d_in[i0 + 2], ocb[b] * 256, base + 256);
        add(d_in[i0 + 3], ocb[b], base + 256 + ocb[b] * 256);
    }
    const int och[4] = {2, 2, 4, 24};
    for (int h = 0; h < 4; ++h) {
        int base = PB_HD0 + h * 7456;
        int i0 = 16 + 8 * h;
        add(d_in[i0 + 1], 256, base);
        add(d_in[i0 + 2], 256, base + 256);
        add(d_in[i0 + 3], 256, base + 512);
        add(d_in[i0 + 4], 256, base + 768);
        add(d_in[i0 + 5], 256, base + 1024);
        add(d_in[i0 + 6], och[h] * 256, base + 1280);
        add(d_in[i0 + 7], och[h], base + 1280 + och[h] * 256);
    }
    SG.cnt = si;

    kPrepWP<<<5760 + 40, 256, 0, stream>>>(WP, SG, feat, flag,
                                           ws + WS_W1T, wb16, whb, par);

    // merged MFMA branches: A staged once/block, inner br loop (z = batch)
    kBranch3<<<dim3(5, 48, 8), 512, 0, stream>>>(
        feat, flag, wb16, par + PB_BR0, d_out, ws);

    // exact f32 strip for NMS/topk decision region (rows 0..2 of heat)
    kBranchX<<<dim3(10, 3, 8), 256, 0, stream>>>(
        feat, flag, ws + WS_W1T, par + PB_BR0, d_out, O_HEAT, ws + WS_HEAT);

    kNmsTopA<<<dim3(24, NCHUNK), 256, 0, stream>>>(ws + WS_HEAT, ws + WS_NH);
    kTopBC<<<8, 192, 0, stream>>>(ws + WS_NH, ws + WS_OFF2, ws + WS_SIZ2,
                                  ws + WS_BOX, (int*)(ws + WS_CLS));
    kRoi<<<400, 256, 0, stream>>>(feat, flag, ws + WS_BOX, (int*)(ws + WS_CLS),
                                  par, ws + WS_ROI);
    kHeadM<<<dim3(4, NROI), 256, 0, stream>>>(ws + WS_ROI, whb, par, ws + WS_HOUT);
    kFinal<<<2, 256, 0, stream>>>(ws + WS_HOUT, ws + WS_BOX, (int*)(ws + WS_CLS),
                                  par, d_out, flag);
}

// Round 12
// 802.775 us; speedup vs baseline: 1.7207x; 1.0358x over previous
//
#include <hip/hip_runtime.h>
#include <math.h>

typedef unsigned short u16;
typedef unsigned int   u32;
typedef unsigned long long u64;
typedef __attribute__((ext_vector_type(8))) short short8;   // 8 bf16 (4 VGPR)
typedef __attribute__((ext_vector_type(4))) float f32x4;    // MFMA acc

// ---------- dtype helpers ----------
__device__ __forceinline__ float b2f(u16 v) { return __uint_as_float(((u32)v) << 16); }
__device__ __forceinline__ u16 f2b(float f) {
    u32 u = __float_as_uint(f);
    u32 r = (u + 0x7FFFu + ((u >> 16) & 1u)) >> 16;   // RNE
    return (u16)r;
}
__device__ __forceinline__ float gload(const void* p, long i, int bf) {
    return bf ? b2f(((const u16*)p)[i]) : ((const float*)p)[i];
}
__device__ __forceinline__ void gstore(void* p, long i, float v, int bf) {
    if (bf) ((u16*)p)[i] = f2b(v);
    else    ((float*)p)[i] = v;
}

// top-k key: smallest key = (largest value, then smallest index)
__device__ __forceinline__ u64 packKey(float v, int idx) {
    u32 u = __float_as_uint(v);
    u32 m = (u & 0x80000000u) ? ~u : (u | 0x80000000u);   // monotone float->uint
    return ((u64)(~m) << 32) | (u32)idx;
}

// per-block dtype-flag recompute (512 u16 probe of feat)
__device__ int blockFlag(const void* feat) {
    __shared__ int fcnt;
    if (threadIdx.x == 0) fcnt = 0;
    __syncthreads();
    int sane = 0;
    for (int i = threadIdx.x; i < 512; i += blockDim.x) {
        u16 v = ((const u16*)feat)[i];
        float f = b2f(v);
        u32 e = (v >> 7) & 0xFF;
        float a = fabsf(f);
        sane += (e != 0xFF) && (f == 0.f || (a >= 1e-8f && a <= 1e4f));
    }
    atomicAdd(&fcnt, sane);
    __syncthreads();
    return fcnt >= 480;
}

// ---------- problem constants ----------
#define BATCH 8
#define CIN   64
#define FH    96
#define FW    320
#define KDET  50
#define NROI  400
#define CROI  69
#define HW    (FH*FW)
#define CHUNK 1920
#define NCHUNK 16

// ---------- workspace layout (float offsets) ----------
#define WS_HEAT 0L
#define WS_OFF2 737280L
#define WS_SIZ2 1228800L
#define WS_NH   1720320L
#define WS_S1S  2457600L
#define WS_S1I  2458800L
#define WS_CLS  2460000L
#define WS_BOX  2460400L
#define WS_ROI  2462400L
#define WS_HOUT 3814800L
#define WS_W1T  3827600L     // 147456 f32: hm conv1 [k=576][c=256] (exact strip)
#define WS_WB16 3975056L     // u16: 3 branches * [9][2][256][32] bf16 (lane-coalesced)
#define WS_W1H  4269968L     // u16: 4 heads * [9][3][256][32] bf16
#define WS_PAR  4905872L     // packed f32 params
#define WS_FLAG 4938960L     // int dtype flag
#define WS_FEATT 4938964L    // u16: [8][96][320][64] bf16 transposed features
#define WS_END  (WS_FEATT + 7864320L)

// param block sub-offsets
#define PB_CAL 0
#define PB_CRN 96
#define PB_MSZ 128
#define PB_BR0 144          // stride 1040: b1@0, w2@256 ([k][n]), b2@256+OC*256
#define PB_HD0 3264         // stride 7456

// ---------- output layout (element offsets) ----------
#define O_HEAT 0L
#define O_OFF2 737280L
#define O_SIZ2 1228800L
#define O_HEAD 1720320L
#define O_DEP  1729920L
#define O_OFF3 1730720L
#define O_S3D  1731520L
#define O_H3D  1732720L

// =====================================================================
// Fused prep: weights + params + flag
// =====================================================================
struct WPtrs { const void* bw[3]; const void* hw[4]; };
struct Seg { const void* src; int n; int dst; };
struct Segs { Seg s[40]; int cnt; };

__global__ void kPrepWP(WPtrs P, Segs S, const void* __restrict__ feat,
                        int* __restrict__ flag, float* __restrict__ w1t,
                        u16* __restrict__ wb16, u16* __restrict__ whb,
                        float* __restrict__ par) {
    const int bf = blockFlag(feat);
    if (blockIdx.x == 0 && threadIdx.x == 0) *flag = bf;
    if (blockIdx.x < 5760) {
        int idx = blockIdx.x * 256 + threadIdx.x;
        if (idx < 147456) {
            int k = idx >> 8, c = idx & 255;
            w1t[idx] = gload(P.bw[0], (long)c * 576 + k, bf);
        } else if (idx < 589824) {
            int j = idx - 147456;
            int br = j / 147456, rem = j % 147456;
            int tap = rem / 16384;
            int r2 = rem & 16383;
            int s = r2 >> 13;
            int n = (r2 >> 5) & 255;
            int c5 = r2 & 31;
            int ci = s * 32 + c5;
            wb16[j] = f2b(gload(P.bw[br], (long)n * 576 + ci * 9 + tap, bf));
        } else {
            int j = idx - 589824;               // < 884736
            int h = j / 221184, rem = j % 221184;
            int tap = rem / 24576, rem2 = rem % 24576;
            int cs = rem2 / 8192, rem3 = rem2 % 8192;
            int oc = rem3 >> 5, jj = rem3 & 31;
            int ci = cs * 32 + jj;
            u16 val = 0;
            if (ci < CROI) val = f2b(gload(P.hw[h], (long)oc * 621 + ci * 9 + tap, bf));
            whb[j] = val;
        }
    } else {
        int sidx = blockIdx.x - 5760;
        if (sidx < S.cnt) {
            Seg sg = S.s[sidx];
            for (int i = threadIdx.x; i < sg.n; i += 256)
                par[sg.dst + i] = gload(sg.src, i, bf);
        }
    }
}

// =====================================================================
// Feature transpose: [b][c][h][w] -> [b][h][w][c] bf16 (for coalesced ROI)
// block = (xchunk, y, b); tile 64c x 64x via LDS
// =====================================================================
__global__ __launch_bounds__(256)
void kTrans(const void* __restrict__ feat, const int* __restrict__ flag,
            u16* __restrict__ featT) {
    __shared__ u16 t_lds[64][72];
    const int bf = *flag;
    const int x0 = blockIdx.x * 64, y = blockIdx.y, b = blockIdx.z;
    const int tid = threadIdx.x;
    for (int i = tid; i < 64 * 64; i += 256) {
        int c = i >> 6, x = i & 63;          // lanes: consecutive x (coalesced)
        t_lds[x][c] = f2b(gload(feat, ((long)(b * CIN + c) * FH + y) * FW + x0 + x, bf));
    }
    __syncthreads();
    u16* outp = featT + (((long)b * FH + y) * FW + x0) * 64;
    for (int i = tid; i < 64 * 64; i += 256) {
        int x = i >> 6, c = i & 63;          // lanes: consecutive c (coalesced)
        outp[(long)x * 64 + c] = t_lds[x][c];
    }
}

// =====================================================================
// Merged MFMA branch conv + exact f32 strip, one dispatch.
// grid (5, 48, 9): z<8 = conv role (b=z), z==8 = strip role.
// Conv: 512 thr, M=128 (2 rows x 64 x), wave 64x64; A staged once,
//   inner br-loop; heat stores SKIP rows 0..2 (strip owns them).
// Strip: rows 0..2 of heat, 32-wide x tiles, exact f32 path
//   (240 blocks = 48*5 exactly); runs concurrently with conv blocks.
// =====================================================================
union MLds {
    struct { u16 a[4][68][72]; float red[8][64][3]; } c;
    struct {
        float in[4][3][36];
        union { float w[36 * 256]; float part[32 * 3 * 32]; } u;
    } s;
};

__global__ __launch_bounds__(512, 4)
void kBranch3M(const void* __restrict__ feat, const int* __restrict__ flag,
               const u16* __restrict__ wbAll,   // 3 * [9][2][256][32] bf16
               const float* __restrict__ bpAll, // par + PB_BR0, stride 1040
               const float* __restrict__ w1t,   // strip weights f32
               void* __restrict__ outb, float* __restrict__ wsbase) {
    __shared__ __align__(16) MLds L;

    const long obase[3] = {O_HEAT, O_OFF2, O_SIZ2};
    const long wfs[3]   = {WS_HEAT, WS_OFF2, WS_SIZ2};

    const int bfl = *flag;
    const int tid = threadIdx.x;

    if (blockIdx.z == 8) {
        // ================= STRIP ROLE (exact f32, rows 0..2) ==========
        const int sidx = blockIdx.y * 5 + blockIdx.x;   // 0..239
        const int x0 = (sidx % 10) * 32;
        const int srem = sidx / 10;
        const int y = srem % 3;
        const int b = srem / 3;
        const float* bp = bpAll;                        // heat branch params
        const int OC = 3;
        const int xg = tid & 7, cg = tid >> 3;
        const int c0 = (cg & 31) * 8;

        float acc[8][4];
#pragma unroll
        for (int i = 0; i < 8; ++i)
#pragma unroll
            for (int j = 0; j < 4; ++j) acc[i][j] = 0.f;

        for (int chunk = 0; chunk < 16; ++chunk) {
            const int ci0 = chunk * 4;
            __syncthreads();
            for (int i = tid; i < 4 * 3 * 36; i += 512) {
                int xx = i % 36, t2 = i / 36;
                int r = t2 % 3, ci = t2 / 3;
                int gx = x0 - 1 + xx, gy = y - 1 + r;
                float v = 0.f;
                if (gx >= 0 && gx < FW && gy >= 0 && gy < FH)
                    v = gload(feat, ((long)(b * CIN + ci0 + ci) * FH + gy) * FW + gx, bfl);
                L.s.in[ci][r][xx] = v;
            }
            {
                const float4* src = (const float4*)(w1t + (long)ci0 * 9 * 256);
                float4* dst = (float4*)L.s.u.w;
                for (int i = tid; i < 36 * 256 / 4; i += 512) dst[i] = src[i];
            }
            __syncthreads();
            if (tid < 256) {
#pragma unroll
                for (int ci = 0; ci < 4; ++ci) {
#pragma unroll
                    for (int ky = 0; ky < 3; ++ky) {
                        const float* rowp = &L.s.in[ci][ky][xg * 4];
                        float inv[6];
                        *(float4*)&inv[0] = *(const float4*)&rowp[0];
                        *(float2*)&inv[4] = *(const float2*)&rowp[4];
#pragma unroll
                        for (int kx = 0; kx < 3; ++kx) {
                            const float* wp = &L.s.u.w[(ci * 9 + ky * 3 + kx) * 256 + c0];
                            float wv[8];
                            *(float4*)&wv[0] = *(const float4*)&wp[0];
                            *(float4*)&wv[4] = *(const float4*)&wp[4];
#pragma unroll
                            for (int cc = 0; cc < 8; ++cc)
#pragma unroll
                                for (int xx = 0; xx < 4; ++xx)
                                    acc[cc][xx] = fmaf(wv[cc], inv[xx + kx], acc[cc][xx]);
                        }
                    }
                }
            }
        }

        if (tid < 256) {
#pragma unroll
            for (int cc = 0; cc < 8; ++cc) {
                float b1v = bp[c0 + cc];
#pragma unroll
                for (int xx = 0; xx < 4; ++xx)
                    acc[cc][xx] = fmaxf(acc[cc][xx] + b1v, 0.f);
            }
        }
        __syncthreads();
        if (tid < 256) {
#pragma unroll
            for (int k = 0; k < OC; ++k) {
                float p[4];
#pragma unroll
                for (int xx = 0; xx < 4; ++xx) p[xx] = 0.f;
#pragma unroll
                for (int cc = 0; cc < 8; ++cc) {
                    float wv = bp[256 + k * 256 + c0 + cc];
#pragma unroll
                    for (int xx = 0; xx < 4; ++xx) p[xx] = fmaf(acc[cc][xx], wv, p[xx]);
                }
#pragma unroll
                for (int xx = 0; xx < 4; ++xx)
                    L.s.u.part[((cg & 31) * OC + k) * 32 + xg * 4 + xx] = p[xx];
            }
        }
        __syncthreads();
        float* outf = wsbase + WS_HEAT;
        for (int t = tid; t < OC * 32; t += 512) {
            int k = t >> 5, xx = t & 31;
            float s = bp[256 + OC * 256 + k];
#pragma unroll 8
            for (int g = 0; g < 32; ++g) s += L.s.u.part[(g * OC + k) * 32 + xx];
            long o = (((long)b * OC + k) * FH + y) * FW + x0 + xx;
            gstore(outb, O_HEAT + o, s, bfl);
            outf[o] = s;
        }
        return;
    }

    // ==================== CONV ROLE (MFMA) ============================
    const int wave = tid >> 6, lane = tid & 63;
    const int q = lane >> 4, n15 = lane & 15;
    const int mg = wave >> 2, ng = wave & 3;
    const int x0 = blockIdx.x * 64, y0 = blockIdx.y * 2;
    const int b = blockIdx.z;

    if (tid < 256) {
        const int ci = tid & 63, rr = tid >> 6;
        const int gy = y0 - 1 + rr;
        if (gy < 0 || gy >= FH) {
            for (int xi = 0; xi < 66; ++xi) L.c.a[rr][xi][ci] = 0;
        } else if (bfl) {
            const u16* rp = (const u16*)feat + ((long)((b << 6) | ci) * FH + gy) * FW;
            for (int j = 0; j < 10; ++j) {
                int xs0 = x0 - 8 + j * 8;
                u16 tmp[8];
                if (xs0 >= 0 && xs0 <= FW - 8)
                    *(uint4*)tmp = *(const uint4*)(rp + xs0);
                else
                    for (int e = 0; e < 8; ++e) {
                        int gx = xs0 + e;
                        tmp[e] = (gx >= 0 && gx < FW) ? rp[gx] : (u16)0;
                    }
                for (int e = 0; e < 8; ++e) {
                    int xi = xs0 + e - x0 + 1;
                    if (xi >= 0 && xi < 66) L.c.a[rr][xi][ci] = tmp[e];
                }
            }
        } else {
            const float* rp = (const float*)feat + ((long)((b << 6) | ci) * FH + gy) * FW;
            for (int j = 0; j < 18; ++j) {
                int xs0 = x0 - 4 + j * 4;
                float tmp[4];
                if (xs0 >= 0 && xs0 <= FW - 4)
                    *(float4*)tmp = *(const float4*)(rp + xs0);
                else
                    for (int e = 0; e < 4; ++e) {
                        int gx = xs0 + e;
                        tmp[e] = (gx >= 0 && gx < FW) ? rp[gx] : 0.f;
                    }
                for (int e = 0; e < 4; ++e) {
                    int xi = xs0 + e - x0 + 1;
                    if (xi >= 0 && xi < 66) L.c.a[rr][xi][ci] = f2b(tmp[e]);
                }
            }
        }
    }
    __syncthreads();   // a_lds visible; read-only from here on

#pragma unroll 1
    for (int br = 0; br < 3; ++br) {
        const int oc = (br == 0) ? 3 : 2;
        const u16* wpt = wbAll + br * 147456;
        const float* bp = bpAll + br * 1040;

        f32x4 acc[4][4];
#pragma unroll
        for (int i = 0; i < 4; ++i)
#pragma unroll
            for (int t = 0; t < 4; ++t) acc[i][t] = (f32x4){0.f, 0.f, 0.f, 0.f};

#pragma unroll 1
        for (int tap = 0; tap < 9; ++tap) {
            const int ky = tap / 3, kx = tap % 3;
#pragma unroll
            for (int s = 0; s < 2; ++s) {
                const u16* wks = wpt + (tap * 2 + s) * 8192;
                short8 bfr[4];
#pragma unroll
                for (int t = 0; t < 4; ++t)
                    bfr[t] = *(const short8*)(wks + (ng * 64 + t * 16 + n15) * 32 + q * 8);
                short8 afr[4];
#pragma unroll
                for (int i = 0; i < 4; ++i)
                    afr[i] = *(const short8*)&L.c.a[mg + ky][i * 16 + n15 + kx][s * 32 + q * 8];
#pragma unroll
                for (int i = 0; i < 4; ++i)
#pragma unroll
                    for (int t = 0; t < 4; ++t)
                        acc[i][t] = __builtin_amdgcn_mfma_f32_16x16x32_bf16(
                            afr[i], bfr[t], acc[i][t], 0, 0, 0);
            }
        }

        float b1v[4], w2v[3][4];
#pragma unroll
        for (int t = 0; t < 4; ++t) {
            int n = ng * 64 + t * 16 + n15;
            b1v[t] = bp[n];
#pragma unroll
            for (int k = 0; k < 3; ++k) w2v[k][t] = bp[256 + k * 256 + n];
        }
        __syncthreads();
#pragma unroll
        for (int i = 0; i < 4; ++i) {
#pragma unroll
            for (int r = 0; r < 4; ++r) {
                float pk[3];
#pragma unroll
                for (int k = 0; k < 3; ++k) pk[k] = 0.f;
#pragma unroll
                for (int t = 0; t < 4; ++t) {
                    float h = fmaxf(acc[i][t][r] + b1v[t], 0.f);
#pragma unroll
                    for (int k = 0; k < 3; ++k) pk[k] = fmaf(h, w2v[k][t], pk[k]);
                }
#pragma unroll
                for (int k = 0; k < 3; ++k) {
                    pk[k] += __shfl_xor(pk[k], 1);
                    pk[k] += __shfl_xor(pk[k], 2);
                    pk[k] += __shfl_xor(pk[k], 4);
                    pk[k] += __shfl_xor(pk[k], 8);
                }
                if (n15 == 0) {
                    int ml = i * 16 + q * 4 + r;
#pragma unroll
                    for (int k = 0; k < 3; ++k) L.c.red[wave][ml][k] = pk[k];
                }
            }
        }
        __syncthreads();
        float* outf = wsbase + wfs[br];
        for (int t2 = tid; t2 < oc * 128; t2 += 512) {
            int k = t2 >> 7, m = t2 & 127;
            int row = m >> 6, x = m & 63;
            int mg2 = m >> 6, ml = m & 63;
            float s = bp[256 + oc * 256 + k];
#pragma unroll
            for (int w = 0; w < 4; ++w) s += L.c.red[mg2 * 4 + w][ml][k];
            int grow = y0 + row;
            if (br == 0 && grow < 3) continue;    // strip role owns heat rows 0..2
            long o = (((long)b * oc + k) * FH + grow) * FW + x0 + x;
            gstore(outb, obase[br] + o, s, bfl);
            outf[o] = s;
        }
    }
}

// =====================================================================
// Fused NMS + top-k stage A
// =====================================================================
__global__ __launch_bounds__(256)
void kNmsTopA(const float* __restrict__ heat, float* __restrict__ nh) {
    __shared__ float hrow[8][320];
    __shared__ u64 keys[CHUNK];
    const int bc = blockIdx.x, ch = blockIdx.y;
    const int tid = threadIdx.x;
    const int r0 = ch * 6;
    const float* hp = heat + (long)bc * HW;

    for (int i = tid; i < 8 * 320; i += 256) {
        int rr = i / 320, x = i % 320;
        int gy = r0 - 1 + rr;
        hrow[rr][x] = (gy >= 0 && gy < FH) ? hp[(long)gy * FW + x] : -INFINITY;
    }
    __syncthreads();
    for (int i = tid; i < CHUNK; i += 256) {
        int ry = i / 320, x = i % 320;
        float v = hrow[ry + 1][x];
        float m = v;
        int xm = max(x - 1, 0), xp = min(x + 1, FW - 1);
#pragma unroll
        for (int dy = 0; dy < 3; ++dy) {
            m = fmaxf(m, hrow[ry + dy][xm]);
            m = fmaxf(m, hrow[ry + dy][x]);
            m = fmaxf(m, hrow[ry + dy][xp]);
        }
        float nv = (v == m) ? v : 0.f;
        keys[i] = packKey(nv, ch * CHUNK + i);
    }
    __syncthreads();
    if (tid < 64) {
        const int lane = tid;
        u64* outp = (u64*)(nh + (long)bc * HW + (long)ch * CHUNK);
        for (int it = 0; it < KDET; ++it) {
            u64 bk = ~0ULL; int bp = 0;
            for (int i = lane; i < CHUNK; i += 64) {
                u64 k = keys[i];
                if (k < bk) { bk = k; bp = i; }
            }
#pragma unroll
            for (int s = 32; s > 0; s >>= 1) {
                u64 k2 = __shfl_down(bk, s);
                int p2 = __shfl_down(bp, s);
                if (k2 < bk) { bk = k2; bp = p2; }
            }
            bk = __shfl(bk, 0);
            bp = __shfl(bp, 0);
            if (lane == 0) {
                outp[it] = bk;
                keys[bp] = ~0ULL;
            }
        }
    }
}

// =====================================================================
// Fused top-k stage B + stage 2 + boxes
// =====================================================================
__global__ __launch_bounds__(192)
void kTopBC(const float* __restrict__ nh, const float* __restrict__ off2,
            const float* __restrict__ siz2, float* __restrict__ boxes,
            int* __restrict__ clsArr) {
    __shared__ u64 keys[3][NCHUNK * KDET];
    __shared__ float sc[150];
    __shared__ int   si[150];
    const int b = blockIdx.x, tid = threadIdx.x;
    const int wave = tid >> 6, lane = tid & 63;
    const int bc = b * 3 + wave;

    for (int ch = 0; ch < NCHUNK; ++ch) {
        const u64* src = (const u64*)(nh + (long)bc * HW + (long)ch * CHUNK);
        if (lane < KDET) keys[wave][ch * KDET + lane] = src[lane];
    }
    __syncthreads();
    for (int it = 0; it < KDET; ++it) {
        u64 bk = ~0ULL; int bp = 0;
        for (int i = lane; i < NCHUNK * KDET; i += 64) {
            u64 k = keys[wave][i];
            if (k < bk) { bk = k; bp = i; }
        }
#pragma unroll
        for (int s = 32; s > 0; s >>= 1) {
            u64 k2 = __shfl_down(bk, s);
            int p2 = __shfl_down(bp, s);
            if (k2 < bk) { bk = k2; bp = p2; }
        }
        bk = __shfl(bk, 0);
        bp = __shfl(bp, 0);
        if (lane == 0) {
            u32 hm = ~(u32)(bk >> 32);
            u32 u = (hm & 0x80000000u) ? (hm & 0x7fffffffu) : ~hm;
            sc[wave * KDET + it] = __uint_as_float(u);
            si[wave * KDET + it] = (int)(bk & 0xFFFFFFFFu);
            keys[wave][bp] = ~0ULL;
        }
    }
    __syncthreads();
    if (wave == 0) {
        const int t = lane;
        for (int r = 0; r < KDET; ++r) {
            float bv = -INFINITY; int bp = 0x7fffffff;
            for (int i = t; i < 150; i += 64) {
                float v = sc[i];
                if (v > bv) { bv = v; bp = i; }
            }
#pragma unroll
            for (int s = 32; s > 0; s >>= 1) {
                float v2 = __shfl_down(bv, s);
                int   p2 = __shfl_down(bp, s);
                if (v2 > bv || (v2 == bv && p2 < bp)) { bv = v2; bp = p2; }
            }
            bp = __shfl(bp, 0);
            if (t == 0) {
                int cls = bp / KDET;
                int ind = si[bp];
                int n = b * KDET + r;
                clsArr[n] = cls;
                int x = ind % FW, yy = ind / FW;
                float cx = (float)x  + off2[(((long)b * 2 + 0) * FH + yy) * FW + x];
                float cy = (float)yy + off2[(((long)b * 2 + 1) * FH + yy) * FW + x];
                float w  = siz2[(((long)b * 2 + 0) * FH + yy) * FW + x];
                float h  = siz2[(((long)b * 2 + 1) * FH + yy) * FW + x];
                boxes[n * 5 + 0] = (float)b;
                boxes[n * 5 + 1] = cx - w * 0.5f;
                boxes[n * 5 + 2] = cy - h * 0.5f;
                boxes[n * 5 + 3] = cx + w * 0.5f;
                boxes[n * 5 + 4] = cy + h * 0.5f;
                sc[bp] = -INFINITY;
            }
        }
    }
}

// =====================================================================
// ROI metadata helper (shared by both kRoi variants)
// =====================================================================
#define ROI_META \
    if (tid < 14) { \
        float roi_w = fmaxf(bx2 - bx1, 1.f); \
        float X = bx1 + (roi_w / 7.f) * ((tid + 0.5f) * 0.5f); \
        vxs[tid] = (X > -1.f) && (X < (float)FW); \
        float Xc = fminf(fmaxf(X, 0.f), (float)(FW - 1)); \
        int xi = (int)floorf(Xc); \
        x0s[tid] = xi; x1s[tid] = min(xi + 1, FW - 1); lxs[tid] = Xc - (float)xi; \
    } else if (tid >= 16 && tid < 30) { \
        int i = tid - 16; \
        float roi_h = fmaxf(by2 - by1, 1.f); \
        float Y = by1 + (roi_h / 7.f) * ((i + 0.5f) * 0.5f); \
        vys[i] = (Y > -1.f) && (Y < (float)FH); \
        float Yc = fminf(fmaxf(Y, 0.f), (float)(FH - 1)); \
        int yi = (int)floorf(Yc); \
        y0s[i] = yi; y1s[i] = min(yi + 1, FH - 1); lys[i] = Yc - (float)yi; \
    } else if (tid >= 32 && tid < 46) { \
        int j = tid - 32; \
        const float* cal = par + PB_CAL + b * 12; \
        float f_u = cal[0], c_u = cal[2], t03 = cal[3]; \
        float f_v = cal[5], c_v = cal[6], t13 = cal[7]; \
        float bxc = t03 / (-f_u), byc = t13 / (-f_v); \
        const float* cr = par + PB_CRN + b * 4; \
        float crx0 = cr[0], cry0 = cr[1], crx1 = cr[2], cry1 = cr[3]; \
        float sx = crx1 - crx0, sy = cry1 - cry0; \
        float u1 = bx1 / (float)FW * sx + crx0, v1 = by1 / (float)FH * sy + cry0; \
        float u2 = bx2 / (float)FW * sx + crx0, v2 = by2 / (float)FH * sy + cry0; \
        float p1x = (u1 - c_u) / f_u + bxc, p1y = (v1 - c_v) / f_v + byc; \
        float p2x = (u2 - c_u) / f_u + bxc, p2y = (v2 - c_v) / f_v + byc; \
        if (j < 7) cxs[j] = p1x + ((float)j / 6.f) * (p2x - p1x); \
        else       cys[j - 7] = p1y + ((float)(j - 7) / 6.f) * (p2y - p1y); \
    }

// coalesced ROI align using transposed bf16 features
__global__ __launch_bounds__(256)
void kRoiT(const u16* __restrict__ featT, const float* __restrict__ boxes,
           const int* __restrict__ clsArr, const float* __restrict__ par,
           float* __restrict__ roi_in) {
    const int n = blockIdx.x, tid = threadIdx.x;
    __shared__ int   x0s[14], x1s[14], y0s[14], y1s[14], vxs[14], vys[14];
    __shared__ float lxs[14], lys[14], cxs[7], cys[7];

    const float bx1 = boxes[n * 5 + 1], by1 = boxes[n * 5 + 2];
    const float bx2 = boxes[n * 5 + 3], by2 = boxes[n * 5 + 4];
    const int b = (int)boxes[n * 5 + 0];

    ROI_META
    __syncthreads();

    const u16* fb = featT + (long)b * FH * FW * 64;
    for (int t = tid; t < CIN * 49; t += 256) {
        int c = t & 63, p = t >> 6;        // lanes: consecutive c (coalesced)
        int oy = p / 7, ox = p % 7;
        float acc = 0.f;
#pragma unroll
        for (int dy = 0; dy < 2; ++dy) {
            int sy = oy * 2 + dy;
            float ly = lys[sy]; int yA = y0s[sy], yB = y1s[sy], vy = vys[sy];
#pragma unroll
            for (int dx = 0; dx < 2; ++dx) {
                int sx = ox * 2 + dx;
                float lx = lxs[sx]; int xA = x0s[sx], xB = x1s[sx];
                float v = (1.f - ly) * (1.f - lx) * b2f(fb[((long)yA * FW + xA) * 64 + c])
                        + (1.f - ly) * lx         * b2f(fb[((long)yA * FW + xB) * 64 + c])
                        + ly * (1.f - lx)         * b2f(fb[((long)yB * FW + xA) * 64 + c])
                        + ly * lx                 * b2f(fb[((long)yB * FW + xB) * 64 + c]);
                if (!(vy && vxs[sx])) v = 0.f;
                acc += v;
            }
        }
        roi_in[((long)n * CROI + c) * 49 + p] = acc * 0.25f;
    }
    int cls = clsArr[n];
    for (int t = tid; t < 5 * 49; t += 256) {
        int ch = t / 49, p = t % 49, i = p / 7, j = p % 7;
        float v;
        if (ch == 0)      v = cxs[j];
        else if (ch == 1) v = cys[i];
        else              v = (cls == ch - 2) ? 1.f : 0.f;
        roi_in[((long)n * CROI + 64 + ch) * 49 + p] = v;
    }
}

// fallback ROI align (original layout) for small workspaces
__global__ __launch_bounds__(256)
void kRoi(const void* __restrict__ feat, const int* __restrict__ flag,
          const float* __restrict__ boxes, const int* __restrict__ clsArr,
          const float* __restrict__ par, float* __restrict__ roi_in) {
    const int n = blockIdx.x, tid = threadIdx.x;
    const int bf = *flag;
    __shared__ int   x0s[14], x1s[14], y0s[14], y1s[14], vxs[14], vys[14];
    __shared__ float lxs[14], lys[14], cxs[7], cys[7];

    const float bx1 = boxes[n * 5 + 1], by1 = boxes[n * 5 + 2];
    const float bx2 = boxes[n * 5 + 3], by2 = boxes[n * 5 + 4];
    const int b = (int)boxes[n * 5 + 0];

    ROI_META
    __syncthreads();

    for (int t = tid; t < CIN * 49; t += 256) {
        int c = t / 49, p = t % 49, oy = p / 7, ox = p % 7;
        long fb = ((long)b * CIN + c) * HW;
        float acc = 0.f;
#pragma unroll
        for (int dy = 0; dy < 2; ++dy) {
            int sy = oy * 2 + dy;
            float ly = lys[sy]; int yA = y0s[sy], yB = y1s[sy], vy = vys[sy];
#pragma unroll
            for (int dx = 0; dx < 2; ++dx) {
                int sx = ox * 2 + dx;
                float lx = lxs[sx]; int xA = x0s[sx], xB = x1s[sx];
                float v = (1.f - ly) * (1.f - lx) * gload(feat, fb + yA * FW + xA, bf)
                        + (1.f - ly) * lx         * gload(feat, fb + yA * FW + xB, bf)
                        + ly * (1.f - lx)         * gload(feat, fb + yB * FW + xA, bf)
                        + ly * lx                 * gload(feat, fb + yB * FW + xB, bf);
                if (!(vy && vxs[sx])) v = 0.f;
                acc += v;
            }
        }
        roi_in[((long)n * CROI + c) * 49 + p] = acc * 0.25f;
    }
    int cls = clsArr[n];
    for (int t = tid; t < 5 * 49; t += 256) {
        int ch = t / 49, p = t % 49, i = p / 7, j = p % 7;
        float v;
        if (ch == 0)      v = cxs[j];
        else if (ch == 1) v = cys[i];
        else              v = (cls == ch - 2) ? 1.f : 0.f;
        roi_in[((long)n * CROI + 64 + ch) * 49 + p] = v;
    }
}

// =====================================================================
// MFMA ROI head
// =====================================================================
__global__ __launch_bounds__(256, 4)
void kHeadM(const float* __restrict__ roi_in, const u16* __restrict__ whb,
            const float* __restrict__ par, float* __restrict__ head_out) {
    const int h = blockIdx.x, n = blockIdx.y, tid = threadIdx.x;
    const int wave = tid >> 6, lane = tid & 63;
    const int q = lane >> 4, n15 = lane & 15;
    const int ocArr[4] = {2, 2, 4, 24};
    const int offArr[4] = {0, 2, 4, 8};
    __shared__ __align__(16) u16 r_lds[9][9][104];
    __shared__ float means[256];

    for (int i = tid; i < 9 * 9 * 104 / 8; i += 256)
        ((uint4*)r_lds)[i] = (uint4){0, 0, 0, 0};
    __syncthreads();
    const float* rp = roi_in + (long)n * CROI * 49;
    for (int i = tid; i < CROI * 49; i += 256) {
        int c = i / 49, p = i % 49;
        r_lds[p / 7 + 1][p % 7 + 1][c] = f2b(rp[i]);
    }
    __syncthreads();

    int oyA[4], oxA[4];
#pragma unroll
    for (int i = 0; i < 4; ++i) {
        int pos = i * 16 + n15; if (pos > 48) pos = 48;
        oyA[i] = pos / 7; oxA[i] = pos % 7;
    }

    f32x4 acc[4][4];
#pragma unroll
    for (int i = 0; i < 4; ++i)
#pragma unroll
        for (int t = 0; t < 4; ++t) acc[i][t] = (f32x4){0.f, 0.f, 0.f, 0.f};

#pragma unroll 1
    for (int tap = 0; tap < 9; ++tap) {
        const int ky = tap / 3, kx = tap % 3;
        const u16* wt = whb + ((long)h * 9 + tap) * 24576;
#pragma unroll
        for (int cs = 0; cs < 3; ++cs) {
            short8 afr[4], bfr[4];
#pragma unroll
            for (int i = 0; i < 4; ++i)
                afr[i] = *(const short8*)&r_lds[oyA[i] + ky][oxA[i] + kx][cs * 32 + q * 8];
#pragma unroll
            for (int t = 0; t < 4; ++t)
                bfr[t] = *(const short8*)(wt + ((cs << 8) + wave * 64 + t * 16 + n15) * 32 + q * 8);
#pragma unroll
            for (int i = 0; i < 4; ++i)
#pragma unroll
                for (int t = 0; t < 4; ++t)
                    acc[i][t] = __builtin_amdgcn_mfma_f32_16x16x32_bf16(
                        afr[i], bfr[t], acc[i][t], 0, 0, 0);
        }
    }

    const float* hb = par + PB_HD0 + h * 7456;
#pragma unroll
    for (int t = 0; t < 4; ++t) {
        int oc = wave * 64 + t * 16 + n15;
        float b1 = hb[oc], g = hb[256 + oc], be = hb[512 + oc];
        float m = hb[768 + oc], v = hb[1024 + oc];
        float scale = g / sqrtf(v + 1e-5f);
        float s = 0.f;
#pragma unroll
        for (int i = 0; i < 4; ++i)
#pragma unroll
            for (int r = 0; r < 4; ++r) {
                int pos = i * 16 + q * 4 + r;
                if (pos < 49)
                    s += fmaxf((acc[i][t][r] + b1 - m) * scale + be, 0.f);
            }
        s += __shfl_xor(s, 16);
        s += __shfl_xor(s, 32);
        if (q == 0) means[oc] = s / 49.f;
    }
    __syncthreads();

    int oc_out = ocArr[h];
    const float* w2 = hb + 1280;
    for (int k = wave; k < oc_out; k += 4) {
        float s = 0.f;
        for (int c = lane; c < 256; c += 64) s += means[c] * w2[k * 256 + c];
#pragma unroll
        for (int off = 32; off > 0; off >>= 1) s += __shfl_down(s, off);
        if (lane == 0)
            head_out[(long)n * 32 + offArr[h] + k] = s + w2[oc_out * 256 + k];
    }
}

// =====================================================================
// Final scalar math + small outputs
// =====================================================================
__global__ void kFinal(const float* __restrict__ head_out, const float* __restrict__ boxes,
                       const int* __restrict__ clsArr, const float* __restrict__ par,
                       void* __restrict__ out, const int* __restrict__ flag) {
    int n = blockIdx.x * 256 + threadIdx.x;
    if (n >= NROI) return;
    const int bf = *flag;
    const float* ho = head_out + (long)n * 32;
    float dep0 = ho[0], dep1 = ho[1];
    int b = (int)boxes[n * 5 + 0];
    int cls = clsArr[n];

    for (int j = 0; j < 24; ++j) gstore(out, O_HEAD + n * 24 + j, ho[8 + j], bf);
    gstore(out, O_OFF3 + n * 2 + 0, ho[2], bf);
    gstore(out, O_OFF3 + n * 2 + 1, ho[3], bf);
    gstore(out, O_S3D + n * 3 + 0, ho[4], bf);
    gstore(out, O_S3D + n * 3 + 1, ho[5], bf);
    gstore(out, O_S3D + n * 3 + 2, ho[6], bf);
    gstore(out, O_H3D + n, ho[7], bf);

    float cry0 = par[PB_CRN + b * 4 + 1], cry1 = par[PB_CRN + b * 4 + 3];
    float sy = cry1 - cry0;
    float bi2 = boxes[n * 5 + 2] / (float)FH * sy + cry0;
    float bi4 = boxes[n * 5 + 4] / (float)FH * sy + cry0;
    float box_h = fmaxf(bi4 - bi2, 1.f);
    float f_u = par[PB_CAL + b * 12 + 0];
    float size3d0 = par[PB_MSZ + cls * 3 + 0] + ho[4];
    float depth_geo = size3d0 / box_h * f_u;
    float sig = 1.f / (1.f + expf(-dep0));
    float d0 = 1.f / (sig + 1e-6f) - 1.f + depth_geo;
    float dgls = ho[7] + 2.f * (logf(f_u) - logf(box_h));
    float mx = fmaxf(dep1, dgls);
    float lse = mx + logf(expf(dep1 - mx) + expf(dgls - mx));
    gstore(out, O_DEP + n * 2 + 0, d0, bf);
    gstore(out, O_DEP + n * 2 + 1, lse, bf);
}

// =====================================================================
extern "C" void kernel_launch(void* const* d_in, const int* in_sizes, int n_in,
                              void* d_out, int out_size, void* d_ws, size_t ws_size,
                              hipStream_t stream) {
    (void)in_sizes; (void)n_in; (void)out_size;
    float* ws = (float*)d_ws;
    float* par = ws + WS_PAR;
    int* flag = (int*)(ws + WS_FLAG);
    u16* wb16 = (u16*)(ws + WS_WB16);
    u16* whb  = (u16*)(ws + WS_W1H);
    u16* featT = (u16*)(ws + WS_FEATT);
    const void* feat = d_in[0];
    const bool bigws = ws_size >= (size_t)WS_END * 4;

    WPtrs WP;
    WP.bw[0] = d_in[4]; WP.bw[1] = d_in[8]; WP.bw[2] = d_in[12];
    WP.hw[0] = d_in[16]; WP.hw[1] = d_in[24]; WP.hw[2] = d_in[32]; WP.hw[3] = d_in[40];

    Segs SG; int si = 0;
    auto add = [&](const void* s, int n, int dst) {
        SG.s[si].src = s; SG.s[si].n = n; SG.s[si].dst = dst; ++si;
    };
    add(d_in[1], 96, PB_CAL); add(d_in[2], 32, PB_CRN); add(d_in[3], 9, PB_MSZ);
    const int ocb[3] = {3, 2, 2};
    for (int b = 0; b < 3; ++b) {
        int base = PB_BR0 + b * 1040;
        int i0 = 4 + 4 * b;
        add(d_in[i0 + 1], 256, base);
        add(d_in[i0 + 2], ocb[b] * 256, base + 256);
        add(d_in[i0 + 3], ocb[b], base + 256 + ocb[b] * 256);
    }
    const int och[4] = {2, 2, 4, 24};
    for (int h = 0; h < 4; ++h) {
        int base = PB_HD0 + h * 7456;
        int i0 = 16 + 8 * h;
        add(d_in[i0 + 1], 256, base);
        add(d_in[i0 + 2], 256, base + 256);
        add(d_in[i0 + 3], 256, base + 512);
        add(d_in[i0 + 4], 256, base + 768);
        add(d_in[i0 + 5], 256, base + 1024);
        add(d_in[i0 + 6], och[h] * 256, base + 1280);
        add(d_in[i0 + 7], och[h], base + 1280 + och[h] * 256);
    }
    SG.cnt = si;

    kPrepWP<<<5760 + 40, 256, 0, stream>>>(WP, SG, feat, flag,
                                           ws + WS_W1T, wb16, whb, par);
    if (bigws)
        kTrans<<<dim3(5, 96, 8), 256, 0, stream>>>(feat, flag, featT);

    // merged conv (z<8) + exact f32 strip (z==8) in one dispatch
    kBranch3M<<<dim3(5, 48, 9), 512, 0, stream>>>(
        feat, flag, wb16, par + PB_BR0, ws + WS_W1T, d_out, ws);

    kNmsTopA<<<dim3(24, NCHUNK), 256, 0, stream>>>(ws + WS_HEAT, ws + WS_NH);
    kTopBC<<<8, 192, 0, stream>>>(ws + WS_NH, ws + WS_OFF2, ws + WS_SIZ2,
                                  ws + WS_BOX, (int*)(ws + WS_CLS));
    if (bigws)
        kRoiT<<<400, 256, 0, stream>>>(featT, ws + WS_BOX, (int*)(ws + WS_CLS),
                                       par, ws + WS_ROI);
    else
        kRoi<<<400, 256, 0, stream>>>(feat, flag, ws + WS_BOX, (int*)(ws + WS_CLS),
                                      par, ws + WS_ROI);
    kHeadM<<<dim3(4, NROI), 256, 0, stream>>>(ws + WS_ROI, whb, par, ws + WS_HOUT);
    kFinal<<<2, 256, 0, stream>>>(ws + WS_HOUT, ws + WS_BOX, (int*)(ws + WS_CLS),
                                  par, d_out, flag);
}

// Round 13
// 747.304 us; speedup vs baseline: 1.8484x; 1.0742x over previous
//
#include <hip/hip_runtime.h>
#include <math.h>

typedef unsigned short u16;
typedef unsigned int   u32;
typedef unsigned long long u64;
typedef __attribute__((ext_vector_type(8))) short short8;   // 8 bf16 (4 VGPR)
typedef __attribute__((ext_vector_type(4))) float f32x4;    // MFMA acc

// ---------- dtype helpers ----------
__device__ __forceinline__ float b2f(u16 v) { return __uint_as_float(((u32)v) << 16); }
__device__ __forceinline__ u16 f2b(float f) {
    u32 u = __float_as_uint(f);
    u32 r = (u + 0x7FFFu + ((u >> 16) & 1u)) >> 16;   // RNE
    return (u16)r;
}
__device__ __forceinline__ float gload(const void* p, long i, int bf) {
    return bf ? b2f(((const u16*)p)[i]) : ((const float*)p)[i];
}
__device__ __forceinline__ void gstore(void* p, long i, float v, int bf) {
    if (bf) ((u16*)p)[i] = f2b(v);
    else    ((float*)p)[i] = v;
}

// top-k key: smallest key = (largest value, then smallest index)
__device__ __forceinline__ u64 packKey(float v, int idx) {
    u32 u = __float_as_uint(v);
    u32 m = (u & 0x80000000u) ? ~u : (u | 0x80000000u);   // monotone float->uint
    return ((u64)(~m) << 32) | (u32)idx;
}

// per-block dtype-flag recompute (512 u16 probe of feat)
__device__ int blockFlag(const void* feat) {
    __shared__ int fcnt;
    if (threadIdx.x == 0) fcnt = 0;
    __syncthreads();
    int sane = 0;
    for (int i = threadIdx.x; i < 512; i += blockDim.x) {
        u16 v = ((const u16*)feat)[i];
        float f = b2f(v);
        u32 e = (v >> 7) & 0xFF;
        float a = fabsf(f);
        sane += (e != 0xFF) && (f == 0.f || (a >= 1e-8f && a <= 1e4f));
    }
    atomicAdd(&fcnt, sane);
    __syncthreads();
    return fcnt >= 480;
}

// ---------- problem constants ----------
#define BATCH 8
#define CIN   64
#define FH    96
#define FW    320
#define KDET  50
#define NROI  400
#define CROI  69
#define HW    (FH*FW)
#define CHUNK 1920
#define NCHUNK 16

// ---------- workspace layout (float offsets) ----------
#define WS_HEAT 0L
#define WS_OFF2 737280L
#define WS_SIZ2 1228800L
#define WS_NH   1720320L
#define WS_CLS  2460000L
#define WS_BOX  2460400L
#define WS_ROI  2462400L
#define WS_HOUT 3814800L
#define WS_W1T  3827600L     // 147456 f32: hm conv1 [k=576][c=256] (exact strip)
#define WS_WB16 3975056L     // u16: 3 branches * [9][2][256][32] bf16 (lane-coalesced)
#define WS_W1H  4269968L     // u16: 4 heads * [9][3][256][32] bf16
#define WS_PAR  4905872L     // packed f32 params
#define WS_FLAG 4938960L     // int dtype flag
#define WS_FEATT 4938964L    // u16: [8][96][320][64] bf16 transposed features
#define WS_END  (WS_FEATT + 7864320L)

// param block sub-offsets
#define PB_CAL 0
#define PB_CRN 96
#define PB_MSZ 128
#define PB_BR0 144          // stride 1040: b1@0, w2@256 ([k][n]), b2@256+OC*256
#define PB_HD0 3264         // stride 7456

// ---------- output layout (element offsets) ----------
#define O_HEAT 0L
#define O_OFF2 737280L
#define O_SIZ2 1228800L
#define O_HEAD 1720320L
#define O_DEP  1729920L
#define O_OFF3 1730720L
#define O_S3D  1731520L
#define O_H3D  1732720L

// =====================================================================
// Fused prep: weights + params + flag
// =====================================================================
struct WPtrs { const void* bw[3]; const void* hw[4]; };
struct Seg { const void* src; int n; int dst; };
struct Segs { Seg s[40]; int cnt; };

__global__ void kPrepWP(WPtrs P, Segs S, const void* __restrict__ feat,
                        int* __restrict__ flag, float* __restrict__ w1t,
                        u16* __restrict__ wb16, u16* __restrict__ whb,
                        float* __restrict__ par) {
    const int bf = blockFlag(feat);
    if (blockIdx.x == 0 && threadIdx.x == 0) *flag = bf;
    if (blockIdx.x < 5760) {
        int idx = blockIdx.x * 256 + threadIdx.x;
        if (idx < 147456) {
            int k = idx >> 8, c = idx & 255;
            w1t[idx] = gload(P.bw[0], (long)c * 576 + k, bf);
        } else if (idx < 589824) {
            int j = idx - 147456;
            int br = j / 147456, rem = j % 147456;
            int tap = rem / 16384;
            int r2 = rem & 16383;
            int s = r2 >> 13;
            int n = (r2 >> 5) & 255;
            int c5 = r2 & 31;
            int ci = s * 32 + c5;
            wb16[j] = f2b(gload(P.bw[br], (long)n * 576 + ci * 9 + tap, bf));
        } else {
            int j = idx - 589824;               // < 884736
            int h = j / 221184, rem = j % 221184;
            int tap = rem / 24576, rem2 = rem % 24576;
            int cs = rem2 / 8192, rem3 = rem2 % 8192;
            int oc = rem3 >> 5, jj = rem3 & 31;
            int ci = cs * 32 + jj;
            u16 val = 0;
            if (ci < CROI) val = f2b(gload(P.hw[h], (long)oc * 621 + ci * 9 + tap, bf));
            whb[j] = val;
        }
    } else {
        int sidx = blockIdx.x - 5760;
        if (sidx < S.cnt) {
            Seg sg = S.s[sidx];
            for (int i = threadIdx.x; i < sg.n; i += 256)
                par[sg.dst + i] = gload(sg.src, i, bf);
        }
    }
}

// =====================================================================
// Mega branch dispatch: grid (5, 48, 8/9/10)
//   z<8  : MFMA conv role (b=z); heat stores skip rows 0..2
//   z==8 : exact f32 strip role (heat rows 0..2)
//   z==9 : feature transpose role (only launched when bigws)
// =====================================================================
union MLds {
    struct { u16 a[4][68][72]; float red[8][64][3]; } c;
    struct {
        float in[4][3][36];
        union { float w[36 * 256]; float part[32 * 3 * 32]; } u;
    } s;
    u16 t[64][72];
};

__global__ __launch_bounds__(512, 4)
void kBranch3M(const void* __restrict__ feat, const int* __restrict__ flag,
               const u16* __restrict__ wbAll,   // 3 * [9][2][256][32] bf16
               const float* __restrict__ bpAll, // par + PB_BR0, stride 1040
               const float* __restrict__ w1t,   // strip weights f32
               void* __restrict__ outb, float* __restrict__ wsbase) {
    __shared__ __align__(16) MLds L;

    const long obase[3] = {O_HEAT, O_OFF2, O_SIZ2};
    const long wfs[3]   = {WS_HEAT, WS_OFF2, WS_SIZ2};

    const int bfl = *flag;
    const int tid = threadIdx.x;

    if (blockIdx.z == 9) {
        // ================= TRANSPOSE ROLE: [b][c][h][w]->[b][h][w][c] ==
        u16* featT = (u16*)(wsbase + WS_FEATT);
        const int x0 = blockIdx.x * 64;
        const int y0 = blockIdx.y * 2;
        for (int sub = 0; sub < 16; ++sub) {       // 8 b x 2 rows
            const int b = sub >> 1, y = y0 + (sub & 1);
            __syncthreads();
            for (int i = tid; i < 64 * 64; i += 512) {
                int c = i >> 6, x = i & 63;        // lanes: consecutive x
                L.t[x][c] = f2b(gload(feat, ((long)(b * CIN + c) * FH + y) * FW + x0 + x, bfl));
            }
            __syncthreads();
            u16* outp = featT + (((long)b * FH + y) * FW + x0) * 64;
            for (int i = tid; i < 64 * 64; i += 512) {
                int x = i >> 6, c = i & 63;        // lanes: consecutive c
                outp[(long)x * 64 + c] = L.t[x][c];
            }
        }
        return;
    }

    if (blockIdx.z == 8) {
        // ================= STRIP ROLE (exact f32, rows 0..2) ==========
        const int sidx = blockIdx.y * 5 + blockIdx.x;   // 0..239
        const int x0 = (sidx % 10) * 32;
        const int srem = sidx / 10;
        const int y = srem % 3;
        const int b = srem / 3;
        const float* bp = bpAll;                        // heat branch params
        const int OC = 3;
        const int xg = tid & 7, cg = tid >> 3;
        const int c0 = (cg & 31) * 8;

        float acc[8][4];
#pragma unroll
        for (int i = 0; i < 8; ++i)
#pragma unroll
            for (int j = 0; j < 4; ++j) acc[i][j] = 0.f;

        for (int chunk = 0; chunk < 16; ++chunk) {
            const int ci0 = chunk * 4;
            __syncthreads();
            for (int i = tid; i < 4 * 3 * 36; i += 512) {
                int xx = i % 36, t2 = i / 36;
                int r = t2 % 3, ci = t2 / 3;
                int gx = x0 - 1 + xx, gy = y - 1 + r;
                float v = 0.f;
                if (gx >= 0 && gx < FW && gy >= 0 && gy < FH)
                    v = gload(feat, ((long)(b * CIN + ci0 + ci) * FH + gy) * FW + gx, bfl);
                L.s.in[ci][r][xx] = v;
            }
            {
                const float4* src = (const float4*)(w1t + (long)ci0 * 9 * 256);
                float4* dst = (float4*)L.s.u.w;
                for (int i = tid; i < 36 * 256 / 4; i += 512) dst[i] = src[i];
            }
            __syncthreads();
            if (tid < 256) {
#pragma unroll
                for (int ci = 0; ci < 4; ++ci) {
#pragma unroll
                    for (int ky = 0; ky < 3; ++ky) {
                        const float* rowp = &L.s.in[ci][ky][xg * 4];
                        float inv[6];
                        *(float4*)&inv[0] = *(const float4*)&rowp[0];
                        *(float2*)&inv[4] = *(const float2*)&rowp[4];
#pragma unroll
                        for (int kx = 0; kx < 3; ++kx) {
                            const float* wp = &L.s.u.w[(ci * 9 + ky * 3 + kx) * 256 + c0];
                            float wv[8];
                            *(float4*)&wv[0] = *(const float4*)&wp[0];
                            *(float4*)&wv[4] = *(const float4*)&wp[4];
#pragma unroll
                            for (int cc = 0; cc < 8; ++cc)
#pragma unroll
                                for (int xx = 0; xx < 4; ++xx)
                                    acc[cc][xx] = fmaf(wv[cc], inv[xx + kx], acc[cc][xx]);
                        }
                    }
                }
            }
        }

        if (tid < 256) {
#pragma unroll
            for (int cc = 0; cc < 8; ++cc) {
                float b1v = bp[c0 + cc];
#pragma unroll
                for (int xx = 0; xx < 4; ++xx)
                    acc[cc][xx] = fmaxf(acc[cc][xx] + b1v, 0.f);
            }
        }
        __syncthreads();
        if (tid < 256) {
#pragma unroll
            for (int k = 0; k < OC; ++k) {
                float p[4];
#pragma unroll
                for (int xx = 0; xx < 4; ++xx) p[xx] = 0.f;
#pragma unroll
                for (int cc = 0; cc < 8; ++cc) {
                    float wv = bp[256 + k * 256 + c0 + cc];
#pragma unroll
                    for (int xx = 0; xx < 4; ++xx) p[xx] = fmaf(acc[cc][xx], wv, p[xx]);
                }
#pragma unroll
                for (int xx = 0; xx < 4; ++xx)
                    L.s.u.part[((cg & 31) * OC + k) * 32 + xg * 4 + xx] = p[xx];
            }
        }
        __syncthreads();
        float* outf = wsbase + WS_HEAT;
        for (int t = tid; t < OC * 32; t += 512) {
            int k = t >> 5, xx = t & 31;
            float s = bp[256 + OC * 256 + k];
#pragma unroll 8
            for (int g = 0; g < 32; ++g) s += L.s.u.part[(g * OC + k) * 32 + xx];
            long o = (((long)b * OC + k) * FH + y) * FW + x0 + xx;
            gstore(outb, O_HEAT + o, s, bfl);
            outf[o] = s;
        }
        return;
    }

    // ==================== CONV ROLE (MFMA) ============================
    const int wave = tid >> 6, lane = tid & 63;
    const int q = lane >> 4, n15 = lane & 15;
    const int mg = wave >> 2, ng = wave & 3;
    const int x0 = blockIdx.x * 64, y0 = blockIdx.y * 2;
    const int b = blockIdx.z;

    if (tid < 256) {
        const int ci = tid & 63, rr = tid >> 6;
        const int gy = y0 - 1 + rr;
        if (gy < 0 || gy >= FH) {
            for (int xi = 0; xi < 66; ++xi) L.c.a[rr][xi][ci] = 0;
        } else if (bfl) {
            const u16* rp = (const u16*)feat + ((long)((b << 6) | ci) * FH + gy) * FW;
            for (int j = 0; j < 10; ++j) {
                int xs0 = x0 - 8 + j * 8;
                u16 tmp[8];
                if (xs0 >= 0 && xs0 <= FW - 8)
                    *(uint4*)tmp = *(const uint4*)(rp + xs0);
                else
                    for (int e = 0; e < 8; ++e) {
                        int gx = xs0 + e;
                        tmp[e] = (gx >= 0 && gx < FW) ? rp[gx] : (u16)0;
                    }
                for (int e = 0; e < 8; ++e) {
                    int xi = xs0 + e - x0 + 1;
                    if (xi >= 0 && xi < 66) L.c.a[rr][xi][ci] = tmp[e];
                }
            }
        } else {
            const float* rp = (const float*)feat + ((long)((b << 6) | ci) * FH + gy) * FW;
            for (int j = 0; j < 18; ++j) {
                int xs0 = x0 - 4 + j * 4;
                float tmp[4];
                if (xs0 >= 0 && xs0 <= FW - 4)
                    *(float4*)tmp = *(const float4*)(rp + xs0);
                else
                    for (int e = 0; e < 4; ++e) {
                        int gx = xs0 + e;
                        tmp[e] = (gx >= 0 && gx < FW) ? rp[gx] : 0.f;
                    }
                for (int e = 0; e < 4; ++e) {
                    int xi = xs0 + e - x0 + 1;
                    if (xi >= 0 && xi < 66) L.c.a[rr][xi][ci] = f2b(tmp[e]);
                }
            }
        }
    }
    __syncthreads();   // a_lds visible; read-only from here on

#pragma unroll 1
    for (int br = 0; br < 3; ++br) {
        const int oc = (br == 0) ? 3 : 2;
        const u16* wpt = wbAll + br * 147456;
        const float* bp = bpAll + br * 1040;

        f32x4 acc[4][4];
#pragma unroll
        for (int i = 0; i < 4; ++i)
#pragma unroll
            for (int t = 0; t < 4; ++t) acc[i][t] = (f32x4){0.f, 0.f, 0.f, 0.f};

#pragma unroll 1
        for (int tap = 0; tap < 9; ++tap) {
            const int ky = tap / 3, kx = tap % 3;
#pragma unroll
            for (int s = 0; s < 2; ++s) {
                const u16* wks = wpt + (tap * 2 + s) * 8192;
                short8 bfr[4];
#pragma unroll
                for (int t = 0; t < 4; ++t)
                    bfr[t] = *(const short8*)(wks + (ng * 64 + t * 16 + n15) * 32 + q * 8);
                short8 afr[4];
#pragma unroll
                for (int i = 0; i < 4; ++i)
                    afr[i] = *(const short8*)&L.c.a[mg + ky][i * 16 + n15 + kx][s * 32 + q * 8];
#pragma unroll
                for (int i = 0; i < 4; ++i)
#pragma unroll
                    for (int t = 0; t < 4; ++t)
                        acc[i][t] = __builtin_amdgcn_mfma_f32_16x16x32_bf16(
                            afr[i], bfr[t], acc[i][t], 0, 0, 0);
            }
        }

        float b1v[4], w2v[3][4];
#pragma unroll
        for (int t = 0; t < 4; ++t) {
            int n = ng * 64 + t * 16 + n15;
            b1v[t] = bp[n];
#pragma unroll
            for (int k = 0; k < 3; ++k) w2v[k][t] = bp[256 + k * 256 + n];
        }
        __syncthreads();
#pragma unroll
        for (int i = 0; i < 4; ++i) {
#pragma unroll
            for (int r = 0; r < 4; ++r) {
                float pk[3];
#pragma unroll
                for (int k = 0; k < 3; ++k) pk[k] = 0.f;
#pragma unroll
                for (int t = 0; t < 4; ++t) {
                    float h = fmaxf(acc[i][t][r] + b1v[t], 0.f);
#pragma unroll
                    for (int k = 0; k < 3; ++k) pk[k] = fmaf(h, w2v[k][t], pk[k]);
                }
#pragma unroll
                for (int k = 0; k < 3; ++k) {
                    pk[k] += __shfl_xor(pk[k], 1);
                    pk[k] += __shfl_xor(pk[k], 2);
                    pk[k] += __shfl_xor(pk[k], 4);
                    pk[k] += __shfl_xor(pk[k], 8);
                }
                if (n15 == 0) {
                    int ml = i * 16 + q * 4 + r;
#pragma unroll
                    for (int k = 0; k < 3; ++k) L.c.red[wave][ml][k] = pk[k];
                }
            }
        }
        __syncthreads();
        float* outf = wsbase + wfs[br];
        for (int t2 = tid; t2 < oc * 128; t2 += 512) {
            int k = t2 >> 7, m = t2 & 127;
            int row = m >> 6, x = m & 63;
            int mg2 = m >> 6, ml = m & 63;
            float s = bp[256 + oc * 256 + k];
#pragma unroll
            for (int w = 0; w < 4; ++w) s += L.c.red[mg2 * 4 + w][ml][k];
            int grow = y0 + row;
            if (br == 0 && grow < 3) continue;    // strip role owns heat rows 0..2
            long o = (((long)b * oc + k) * FH + grow) * FW + x0 + x;
            gstore(outb, obase[br] + o, s, bfl);
            outf[o] = s;
        }
    }
}

// =====================================================================
// Fused NMS + top-k stage A (4-wave hierarchical extraction)
// =====================================================================
__global__ __launch_bounds__(256)
void kNmsTopA(const float* __restrict__ heat, float* __restrict__ nh) {
    __shared__ float hrow[8][320];
    __shared__ u64 keys[CHUNK];
    __shared__ u64 sub[4][KDET];
    const int bc = blockIdx.x, ch = blockIdx.y;
    const int tid = threadIdx.x;
    const int wave = tid >> 6, lane = tid & 63;
    const int r0 = ch * 6;
    const float* hp = heat + (long)bc * HW;

    for (int i = tid; i < 8 * 320; i += 256) {
        int rr = i / 320, x = i % 320;
        int gy = r0 - 1 + rr;
        hrow[rr][x] = (gy >= 0 && gy < FH) ? hp[(long)gy * FW + x] : -INFINITY;
    }
    __syncthreads();
    for (int i = tid; i < CHUNK; i += 256) {
        int ry = i / 320, x = i % 320;
        float v = hrow[ry + 1][x];
        float m = v;
        int xm = max(x - 1, 0), xp = min(x + 1, FW - 1);
#pragma unroll
        for (int dy = 0; dy < 3; ++dy) {
            m = fmaxf(m, hrow[ry + dy][xm]);
            m = fmaxf(m, hrow[ry + dy][x]);
            m = fmaxf(m, hrow[ry + dy][xp]);
        }
        float nv = (v == m) ? v : 0.f;
        keys[i] = packKey(nv, ch * CHUNK + i);
    }
    __syncthreads();
    // each wave: top-50 of its 480-element sub-chunk
    {
        u64* kw = keys + wave * 480;
        for (int it = 0; it < KDET; ++it) {
            u64 bk = ~0ULL; int bp = 0;
            for (int i = lane; i < 480; i += 64) {
                u64 k = kw[i];
                if (k < bk) { bk = k; bp = i; }
            }
#pragma unroll
            for (int s = 32; s > 0; s >>= 1) {
                u64 k2 = __shfl_down(bk, s);
                int p2 = __shfl_down(bp, s);
                if (k2 < bk) { bk = k2; bp = p2; }
            }
            bk = __shfl(bk, 0);
            bp = __shfl(bp, 0);
            if (lane == 0) {
                sub[wave][it] = bk;
                kw[bp] = ~0ULL;
            }
        }
    }
    __syncthreads();
    // wave 0: merge 4x50 -> chunk top-50
    if (wave == 0) {
        u64* outp = (u64*)(nh + (long)bc * HW + (long)ch * CHUNK);
        u64* sp = &sub[0][0];
        for (int it = 0; it < KDET; ++it) {
            u64 bk = ~0ULL; int bp = 0;
            for (int i = lane; i < 4 * KDET; i += 64) {
                u64 k = sp[i];
                if (k < bk) { bk = k; bp = i; }
            }
#pragma unroll
            for (int s = 32; s > 0; s >>= 1) {
                u64 k2 = __shfl_down(bk, s);
                int p2 = __shfl_down(bp, s);
                if (k2 < bk) { bk = k2; bp = p2; }
            }
            bk = __shfl(bk, 0);
            bp = __shfl(bp, 0);
            if (lane == 0) {
                outp[it] = bk;
                sp[bp] = ~0ULL;
            }
        }
    }
}

// =====================================================================
// Fused top-k stage B + stage 2 + boxes
// =====================================================================
__global__ __launch_bounds__(192)
void kTopBC(const float* __restrict__ nh, const float* __restrict__ off2,
            const float* __restrict__ siz2, float* __restrict__ boxes,
            int* __restrict__ clsArr) {
    __shared__ u64 keys[3][NCHUNK * KDET];
    __shared__ float sc[150];
    __shared__ int   si[150];
    const int b = blockIdx.x, tid = threadIdx.x;
    const int wave = tid >> 6, lane = tid & 63;
    const int bc = b * 3 + wave;

    for (int ch = 0; ch < NCHUNK; ++ch) {
        const u64* src = (const u64*)(nh + (long)bc * HW + (long)ch * CHUNK);
        if (lane < KDET) keys[wave][ch * KDET + lane] = src[lane];
    }
    __syncthreads();
    for (int it = 0; it < KDET; ++it) {
        u64 bk = ~0ULL; int bp = 0;
        for (int i = lane; i < NCHUNK * KDET; i += 64) {
            u64 k = keys[wave][i];
            if (k < bk) { bk = k; bp = i; }
        }
#pragma unroll
        for (int s = 32; s > 0; s >>= 1) {
            u64 k2 = __shfl_down(bk, s);
            int p2 = __shfl_down(bp, s);
            if (k2 < bk) { bk = k2; bp = p2; }
        }
        bk = __shfl(bk, 0);
        bp = __shfl(bp, 0);
        if (lane == 0) {
            u32 hm = ~(u32)(bk >> 32);
            u32 u = (hm & 0x80000000u) ? (hm & 0x7fffffffu) : ~hm;
            sc[wave * KDET + it] = __uint_as_float(u);
            si[wave * KDET + it] = (int)(bk & 0xFFFFFFFFu);
            keys[wave][bp] = ~0ULL;
        }
    }
    __syncthreads();
    if (wave == 0) {
        const int t = lane;
        for (int r = 0; r < KDET; ++r) {
            float bv = -INFINITY; int bp = 0x7fffffff;
            for (int i = t; i < 150; i += 64) {
                float v = sc[i];
                if (v > bv) { bv = v; bp = i; }
            }
#pragma unroll
            for (int s = 32; s > 0; s >>= 1) {
                float v2 = __shfl_down(bv, s);
                int   p2 = __shfl_down(bp, s);
                if (v2 > bv || (v2 == bv && p2 < bp)) { bv = v2; bp = p2; }
            }
            bp = __shfl(bp, 0);
            if (t == 0) {
                int cls = bp / KDET;
                int ind = si[bp];
                int n = b * KDET + r;
                clsArr[n] = cls;
                int x = ind % FW, yy = ind / FW;
                float cx = (float)x  + off2[(((long)b * 2 + 0) * FH + yy) * FW + x];
                float cy = (float)yy + off2[(((long)b * 2 + 1) * FH + yy) * FW + x];
                float w  = siz2[(((long)b * 2 + 0) * FH + yy) * FW + x];
                float h  = siz2[(((long)b * 2 + 1) * FH + yy) * FW + x];
                boxes[n * 5 + 0] = (float)b;
                boxes[n * 5 + 1] = cx - w * 0.5f;
                boxes[n * 5 + 2] = cy - h * 0.5f;
                boxes[n * 5 + 3] = cx + w * 0.5f;
                boxes[n * 5 + 4] = cy + h * 0.5f;
                sc[bp] = -INFINITY;
            }
        }
    }
}

// =====================================================================
// ROI metadata helper
// =====================================================================
#define ROI_META \
    if (tid < 14) { \
        float roi_w = fmaxf(bx2 - bx1, 1.f); \
        float X = bx1 + (roi_w / 7.f) * ((tid + 0.5f) * 0.5f); \
        vxs[tid] = (X > -1.f) && (X < (float)FW); \
        float Xc = fminf(fmaxf(X, 0.f), (float)(FW - 1)); \
        int xi = (int)floorf(Xc); \
        x0s[tid] = xi; x1s[tid] = min(xi + 1, FW - 1); lxs[tid] = Xc - (float)xi; \
    } else if (tid >= 16 && tid < 30) { \
        int i = tid - 16; \
        float roi_h = fmaxf(by2 - by1, 1.f); \
        float Y = by1 + (roi_h / 7.f) * ((i + 0.5f) * 0.5f); \
        vys[i] = (Y > -1.f) && (Y < (float)FH); \
        float Yc = fminf(fmaxf(Y, 0.f), (float)(FH - 1)); \
        int yi = (int)floorf(Yc); \
        y0s[i] = yi; y1s[i] = min(yi + 1, FH - 1); lys[i] = Yc - (float)yi; \
    } else if (tid >= 32 && tid < 46) { \
        int j = tid - 32; \
        const float* cal = par + PB_CAL + b * 12; \
        float f_u = cal[0], c_u = cal[2], t03 = cal[3]; \
        float f_v = cal[5], c_v = cal[6], t13 = cal[7]; \
        float bxc = t03 / (-f_u), byc = t13 / (-f_v); \
        const float* cr = par + PB_CRN + b * 4; \
        float crx0 = cr[0], cry0 = cr[1], crx1 = cr[2], cry1 = cr[3]; \
        float sx = crx1 - crx0, sy = cry1 - cry0; \
        float u1 = bx1 / (float)FW * sx + crx0, v1 = by1 / (float)FH * sy + cry0; \
        float u2 = bx2 / (float)FW * sx + crx0, v2 = by2 / (float)FH * sy + cry0; \
        float p1x = (u1 - c_u) / f_u + bxc, p1y = (v1 - c_v) / f_v + byc; \
        float p2x = (u2 - c_u) / f_u + bxc, p2y = (v2 - c_v) / f_v + byc; \
        if (j < 7) cxs[j] = p1x + ((float)j / 6.f) * (p2x - p1x); \
        else       cys[j - 7] = p1y + ((float)(j - 7) / 6.f) * (p2y - p1y); \
    }

// =====================================================================
// Fused ROI-align + MFMA head (bigws path): stages r_lds directly from
// transposed features (coalesced corners), then conv+BN+mean+1x1.
// =====================================================================
__global__ __launch_bounds__(256, 4)
void kHeadM2(const u16* __restrict__ featT, const float* __restrict__ boxes,
             const int* __restrict__ clsArr, const u16* __restrict__ whb,
             const float* __restrict__ par, float* __restrict__ head_out) {
    const int h = blockIdx.x, n = blockIdx.y, tid = threadIdx.x;
    const int wave = tid >> 6, lane = tid & 63;
    const int q = lane >> 4, n15 = lane & 15;
    const int ocArr[4] = {2, 2, 4, 24};
    const int offArr[4] = {0, 2, 4, 8};
    __shared__ __align__(16) u16 r_lds[9][9][104];
    __shared__ float means[256];
    __shared__ int   x0s[14], x1s[14], y0s[14], y1s[14], vxs[14], vys[14];
    __shared__ float lxs[14], lys[14], cxs[7], cys[7];

    const float bx1 = boxes[n * 5 + 1], by1 = boxes[n * 5 + 2];
    const float bx2 = boxes[n * 5 + 3], by2 = boxes[n * 5 + 4];
    const int b = (int)boxes[n * 5 + 0];
    ROI_META

    for (int i = tid; i < 9 * 9 * 104 / 8; i += 256)
        ((uint4*)r_lds)[i] = (uint4){0, 0, 0, 0};
    __syncthreads();

    const u16* fb = featT + (long)b * FH * FW * 64;
    for (int t = tid; t < CIN * 49; t += 256) {
        int c = t & 63, p = t >> 6;        // lanes: consecutive c (coalesced)
        int oy = p / 7, ox = p % 7;
        float acc = 0.f;
#pragma unroll
        for (int dy = 0; dy < 2; ++dy) {
            int sy = oy * 2 + dy;
            float ly = lys[sy]; int yA = y0s[sy], yB = y1s[sy], vy = vys[sy];
#pragma unroll
            for (int dx = 0; dx < 2; ++dx) {
                int sx = ox * 2 + dx;
                float lx = lxs[sx]; int xA = x0s[sx], xB = x1s[sx];
                float v = (1.f - ly) * (1.f - lx) * b2f(fb[((long)yA * FW + xA) * 64 + c])
                        + (1.f - ly) * lx         * b2f(fb[((long)yA * FW + xB) * 64 + c])
                        + ly * (1.f - lx)         * b2f(fb[((long)yB * FW + xA) * 64 + c])
                        + ly * lx                 * b2f(fb[((long)yB * FW + xB) * 64 + c]);
                if (!(vy && vxs[sx])) v = 0.f;
                acc += v;
            }
        }
        r_lds[oy + 1][ox + 1][c] = f2b(acc * 0.25f);
    }
    {
        int cls = clsArr[n];
        for (int t = tid; t < 5 * 49; t += 256) {
            int ch = t / 49, p = t % 49, i = p / 7, j = p % 7;
            float v;
            if (ch == 0)      v = cxs[j];
            else if (ch == 1) v = cys[i];
            else              v = (cls == ch - 2) ? 1.f : 0.f;
            r_lds[i + 1][j + 1][64 + ch] = f2b(v);
        }
    }
    __syncthreads();

    int oyA[4], oxA[4];
#pragma unroll
    for (int i = 0; i < 4; ++i) {
        int pos = i * 16 + n15; if (pos > 48) pos = 48;
        oyA[i] = pos / 7; oxA[i] = pos % 7;
    }

    f32x4 acc[4][4];
#pragma unroll
    for (int i = 0; i < 4; ++i)
#pragma unroll
        for (int t = 0; t < 4; ++t) acc[i][t] = (f32x4){0.f, 0.f, 0.f, 0.f};

#pragma unroll 1
    for (int tap = 0; tap < 9; ++tap) {
        const int ky = tap / 3, kx = tap % 3;
        const u16* wt = whb + ((long)h * 9 + tap) * 24576;
#pragma unroll
        for (int cs = 0; cs < 3; ++cs) {
            short8 afr[4], bfr[4];
#pragma unroll
            for (int i = 0; i < 4; ++i)
                afr[i] = *(const short8*)&r_lds[oyA[i] + ky][oxA[i] + kx][cs * 32 + q * 8];
#pragma unroll
            for (int t = 0; t < 4; ++t)
                bfr[t] = *(const short8*)(wt + ((cs << 8) + wave * 64 + t * 16 + n15) * 32 + q * 8);
#pragma unroll
            for (int i = 0; i < 4; ++i)
#pragma unroll
                for (int t = 0; t < 4; ++t)
                    acc[i][t] = __builtin_amdgcn_mfma_f32_16x16x32_bf16(
                        afr[i], bfr[t], acc[i][t], 0, 0, 0);
        }
    }

    const float* hb = par + PB_HD0 + h * 7456;
#pragma unroll
    for (int t = 0; t < 4; ++t) {
        int oc = wave * 64 + t * 16 + n15;
        float b1 = hb[oc], g = hb[256 + oc], be = hb[512 + oc];
        float m = hb[768 + oc], v = hb[1024 + oc];
        float scale = g / sqrtf(v + 1e-5f);
        float s = 0.f;
#pragma unroll
        for (int i = 0; i < 4; ++i)
#pragma unroll
            for (int r = 0; r < 4; ++r) {
                int pos = i * 16 + q * 4 + r;
                if (pos < 49)
                    s += fmaxf((acc[i][t][r] + b1 - m) * scale + be, 0.f);
            }
        s += __shfl_xor(s, 16);
        s += __shfl_xor(s, 32);
        if (q == 0) means[oc] = s / 49.f;
    }
    __syncthreads();

    int oc_out = ocArr[h];
    const float* w2 = hb + 1280;
    for (int k = wave; k < oc_out; k += 4) {
        float s = 0.f;
        for (int c = lane; c < 256; c += 64) s += means[c] * w2[k * 256 + c];
#pragma unroll
        for (int off = 32; off > 0; off >>= 1) s += __shfl_down(s, off);
        if (lane == 0)
            head_out[(long)n * 32 + offArr[h] + k] = s + w2[oc_out * 256 + k];
    }
}

// =====================================================================
// Fallback path (small ws): separate ROI-align + head reading roi_in
// =====================================================================
__global__ __launch_bounds__(256)
void kRoi(const void* __restrict__ feat, const int* __restrict__ flag,
          const float* __restrict__ boxes, const int* __restrict__ clsArr,
          const float* __restrict__ par, float* __restrict__ roi_in) {
    const int n = blockIdx.x, tid = threadIdx.x;
    const int bf = *flag;
    __shared__ int   x0s[14], x1s[14], y0s[14], y1s[14], vxs[14], vys[14];
    __shared__ float lxs[14], lys[14], cxs[7], cys[7];

    const float bx1 = boxes[n * 5 + 1], by1 = boxes[n * 5 + 2];
    const float bx2 = boxes[n * 5 + 3], by2 = boxes[n * 5 + 4];
    const int b = (int)boxes[n * 5 + 0];

    ROI_META
    __syncthreads();

    for (int t = tid; t < CIN * 49; t += 256) {
        int c = t / 49, p = t % 49, oy = p / 7, ox = p % 7;
        long fb = ((long)b * CIN + c) * HW;
        float acc = 0.f;
#pragma unroll
        for (int dy = 0; dy < 2; ++dy) {
            int sy = oy * 2 + dy;
            float ly = lys[sy]; int yA = y0s[sy], yB = y1s[sy], vy = vys[sy];
#pragma unroll
            for (int dx = 0; dx < 2; ++dx) {
                int sx = ox * 2 + dx;
                float lx = lxs[sx]; int xA = x0s[sx], xB = x1s[sx];
                float v = (1.f - ly) * (1.f - lx) * gload(feat, fb + yA * FW + xA, bf)
                        + (1.f - ly) * lx         * gload(feat, fb + yA * FW + xB, bf)
                        + ly * (1.f - lx)         * gload(feat, fb + yB * FW + xA, bf)
                        + ly * lx                 * gload(feat, fb + yB * FW + xB, bf);
                if (!(vy && vxs[sx])) v = 0.f;
                acc += v;
            }
        }
        roi_in[((long)n * CROI + c) * 49 + p] = acc * 0.25f;
    }
    int cls = clsArr[n];
    for (int t = tid; t < 5 * 49; t += 256) {
        int ch = t / 49, p = t % 49, i = p / 7, j = p % 7;
        float v;
        if (ch == 0)      v = cxs[j];
        else if (ch == 1) v = cys[i];
        else              v = (cls == ch - 2) ? 1.f : 0.f;
        roi_in[((long)n * CROI + 64 + ch) * 49 + p] = v;
    }
}

__global__ __launch_bounds__(256, 4)
void kHeadM(const float* __restrict__ roi_in, const u16* __restrict__ whb,
            const float* __restrict__ par, float* __restrict__ head_out) {
    const int h = blockIdx.x, n = blockIdx.y, tid = threadIdx.x;
    const int wave = tid >> 6, lane = tid & 63;
    const int q = lane >> 4, n15 = lane & 15;
    const int ocArr[4] = {2, 2, 4, 24};
    const int offArr[4] = {0, 2, 4, 8};
    __shared__ __align__(16) u16 r_lds[9][9][104];
    __shared__ float means[256];

    for (int i = tid; i < 9 * 9 * 104 / 8; i += 256)
        ((uint4*)r_lds)[i] = (uint4){0, 0, 0, 0};
    __syncthreads();
    const float* rp = roi_in + (long)n * CROI * 49;
    for (int i = tid; i < CROI * 49; i += 256) {
        int c = i / 49, p = i % 49;
        r_lds[p / 7 + 1][p % 7 + 1][c] = f2b(rp[i]);
    }
    __syncthreads();

    int oyA[4], oxA[4];
#pragma unroll
    for (int i = 0; i < 4; ++i) {
        int pos = i * 16 + n15; if (pos > 48) pos = 48;
        oyA[i] = pos / 7; oxA[i] = pos % 7;
    }

    f32x4 acc[4][4];
#pragma unroll
    for (int i = 0; i < 4; ++i)
#pragma unroll
        for (int t = 0; t < 4; ++t) acc[i][t] = (f32x4){0.f, 0.f, 0.f, 0.f};

#pragma unroll 1
    for (int tap = 0; tap < 9; ++tap) {
        const int ky = tap / 3, kx = tap % 3;
        const u16* wt = whb + ((long)h * 9 + tap) * 24576;
#pragma unroll
        for (int cs = 0; cs < 3; ++cs) {
            short8 afr[4], bfr[4];
#pragma unroll
            for (int i = 0; i < 4; ++i)
                afr[i] = *(const short8*)&r_lds[oyA[i] + ky][oxA[i] + kx][cs * 32 + q * 8];
#pragma unroll
            for (int t = 0; t < 4; ++t)
                bfr[t] = *(const short8*)(wt + ((cs << 8) + wave * 64 + t * 16 + n15) * 32 + q * 8);
#pragma unroll
            for (int i = 0; i < 4; ++i)
#pragma unroll
                for (int t = 0; t < 4; ++t)
                    acc[i][t] = __builtin_amdgcn_mfma_f32_16x16x32_bf16(
                        afr[i], bfr[t], acc[i][t], 0, 0, 0);
        }
    }

    const float* hb = par + PB_HD0 + h * 7456;
#pragma unroll
    for (int t = 0; t < 4; ++t) {
        int oc = wave * 64 + t * 16 + n15;
        float b1 = hb[oc], g = hb[256 + oc], be = hb[512 + oc];
        float m = hb[768 + oc], v = hb[1024 + oc];
        float scale = g / sqrtf(v + 1e-5f);
        float s = 0.f;
#pragma unroll
        for (int i = 0; i < 4; ++i)
#pragma unroll
            for (int r = 0; r < 4; ++r) {
                int pos = i * 16 + q * 4 + r;
                if (pos < 49)
                    s += fmaxf((acc[i][t][r] + b1 - m) * scale + be, 0.f);
            }
        s += __shfl_xor(s, 16);
        s += __shfl_xor(s, 32);
        if (q == 0) means[oc] = s / 49.f;
    }
    __syncthreads();

    int oc_out = ocArr[h];
    const float* w2 = hb + 1280;
    for (int k = wave; k < oc_out; k += 4) {
        float s = 0.f;
        for (int c = lane; c < 256; c += 64) s += means[c] * w2[k * 256 + c];
#pragma unroll
        for (int off = 32; off > 0; off >>= 1) s += __shfl_down(s, off);
        if (lane == 0)
            head_out[(long)n * 32 + offArr[h] + k] = s + w2[oc_out * 256 + k];
    }
}

// =====================================================================
// Final scalar math + small outputs
// =====================================================================
__global__ void kFinal(const float* __restrict__ head_out, const float* __restrict__ boxes,
                       const int* __restrict__ clsArr, const float* __restrict__ par,
                       void* __restrict__ out, const int* __restrict__ flag) {
    int n = blockIdx.x * 256 + threadIdx.x;
    if (n >= NROI) return;
    const int bf = *flag;
    const float* ho = head_out + (long)n * 32;
    float dep0 = ho[0], dep1 = ho[1];
    int b = (int)boxes[n * 5 + 0];
    int cls = clsArr[n];

    for (int j = 0; j < 24; ++j) gstore(out, O_HEAD + n * 24 + j, ho[8 + j], bf);
    gstore(out, O_OFF3 + n * 2 + 0, ho[2], bf);
    gstore(out, O_OFF3 + n * 2 + 1, ho[3], bf);
    gstore(out, O_S3D + n * 3 + 0, ho[4], bf);
    gstore(out, O_S3D + n * 3 + 1, ho[5], bf);
    gstore(out, O_S3D + n * 3 + 2, ho[6], bf);
    gstore(out, O_H3D + n, ho[7], bf);

    float cry0 = par[PB_CRN + b * 4 + 1], cry1 = par[PB_CRN + b * 4 + 3];
    float sy = cry1 - cry0;
    float bi2 = boxes[n * 5 + 2] / (float)FH * sy + cry0;
    float bi4 = boxes[n * 5 + 4] / (float)FH * sy + cry0;
    float box_h = fmaxf(bi4 - bi2, 1.f);
    float f_u = par[PB_CAL + b * 12 + 0];
    float size3d0 = par[PB_MSZ + cls * 3 + 0] + ho[4];
    float depth_geo = size3d0 / box_h * f_u;
    float sig = 1.f / (1.f + expf(-dep0));
    float d0 = 1.f / (sig + 1e-6f) - 1.f + depth_geo;
    float dgls = ho[7] + 2.f * (logf(f_u) - logf(box_h));
    float mx = fmaxf(dep1, dgls);
    float lse = mx + logf(expf(dep1 - mx) + expf(dgls - mx));
    gstore(out, O_DEP + n * 2 + 0, d0, bf);
    gstore(out, O_DEP + n * 2 + 1, lse, bf);
}

// =====================================================================
extern "C" void kernel_launch(void* const* d_in, const int* in_sizes, int n_in,
                              void* d_out, int out_size, void* d_ws, size_t ws_size,
                              hipStream_t stream) {
    (void)in_sizes; (void)n_in; (void)out_size;
    float* ws = (float*)d_ws;
    float* par = ws + WS_PAR;
    int* flag = (int*)(ws + WS_FLAG);
    u16* wb16 = (u16*)(ws + WS_WB16);
    u16* whb  = (u16*)(ws + WS_W1H);
    u16* featT = (u16*)(ws + WS_FEATT);
    const void* feat = d_in[0];
    const bool bigws = ws_size >= (size_t)WS_END * 4;

    WPtrs WP;
    WP.bw[0] = d_in[4]; WP.bw[1] = d_in[8]; WP.bw[2] = d_in[12];
    WP.hw[0] = d_in[16]; WP.hw[1] = d_in[24]; WP.hw[2] = d_in[32]; WP.hw[3] = d_in[40];

    Segs SG; int si = 0;
    auto add = [&](const void* s, int n, int dst) {
        SG.s[si].src = s; SG.s[si].n = n; SG.s[si].dst = dst; ++si;
    };
    add(d_in[1], 96, PB_CAL); add(d_in[2], 32, PB_CRN); add(d_in[3], 9, PB_MSZ);
    const int ocb[3] = {3, 2, 2};
    for (int b = 0; b < 3; ++b) {
        int base = PB_BR0 + b * 1040;
        int i0 = 4 + 4 * b;
        add(d_in[i0 + 1], 256, base);
        add(d_in[i0 + 2], ocb[b] * 256, base + 256);
        add(d_in[i0 + 3], ocb[b], base + 256 + ocb[b] * 256);
    }
    const int och[4] = {2, 2, 4, 24};
    for (int h = 0; h < 4; ++h) {
        int base = PB_HD0 + h * 7456;
        int i0 = 16 + 8 * h;
        add(d_in[i0 + 1], 256, base);
        add(d_in[i0 + 2], 256, base + 256);
        add(d_in[i0 + 3], 256, base + 512);
        add(d_in[i0 + 4], 256, base + 768);
        add(d_in[i0 + 5], 256, base + 1024);
        add(d_in[i0 + 6], och[h] * 256, base + 1280);
        add(d_in[i0 + 7], och[h], base + 1280 + och[h] * 256);
    }
    SG.cnt = si;

    kPrepWP<<<5760 + 40, 256, 0, stream>>>(WP, SG, feat, flag,
                                           ws + WS_W1T, wb16, whb, par);

    // mega dispatch: conv (z<8) + f32 strip (z==8) + transpose (z==9 if bigws)
    kBranch3M<<<dim3(5, 48, bigws ? 10 : 9), 512, 0, stream>>>(
        feat, flag, wb16, par + PB_BR0, ws + WS_W1T, d_out, ws);

    kNmsTopA<<<dim3(24, NCHUNK), 256, 0, stream>>>(ws + WS_HEAT, ws + WS_NH);
    kTopBC<<<8, 192, 0, stream>>>(ws + WS_NH, ws + WS_OFF2, ws + WS_SIZ2,
                                  ws + WS_BOX, (int*)(ws + WS_CLS));
    if (bigws) {
        kHeadM2<<<dim3(4, NROI), 256, 0, stream>>>(featT, ws + WS_BOX,
                                                   (int*)(ws + WS_CLS), whb, par,
                                                   ws + WS_HOUT);
    } else {
        kRoi<<<400, 256, 0, stream>>>(feat, flag, ws + WS_BOX, (int*)(ws + WS_CLS),
                                      par, ws + WS_ROI);
        kHeadM<<<dim3(4, NROI), 256, 0, stream>>>(ws + WS_ROI, whb, par, ws + WS_HOUT);
    }
    kFinal<<<2, 256, 0, stream>>>(ws + WS_HOUT, ws + WS_BOX, (int*)(ws + WS_CLS),
                                  par, d_out, flag);
}